// Round 1
// baseline (6498.743 us; speedup 1.0000x reference)
//
#include <hip/hip_runtime.h>
#include <hip/hip_bf16.h>
#include <math.h>

#define B_    4
#define GRID_ 12
#define DM_   384
#define DEPTH_ 8
#define L_    1728      // 12^3
#define DI_   768
#define NS_   16
#define DC_   4
#define DTR_  24
#define KEEP_ 432
#define XPR_  56        // DTR + 2*NS

// ---------------------------------------------------------------- utilities
__device__ __forceinline__ float silu_f(float x) {
    return x / (1.0f + __expf(-x));
}
__device__ __forceinline__ float softplus_f(float x) {
    return (x > 20.0f) ? x : log1pf(expf(x));
}
__device__ __forceinline__ float gelu_exact_f(float x) {
    return 0.5f * x * (1.0f + erff(x * 0.7071067811865476f));
}

// ---------------------------------------------------------------- ids / rank
// One thread per batch: stable-argsort semantics -> active positions in
// ascending order get ranks 0..KEEP-1; inactive get -1.
__global__ void compute_ids_k(const int* __restrict__ active,
                              int* __restrict__ RANK, int* __restrict__ IDS) {
    int b = threadIdx.x;
    if (b >= B_) return;
    int cnt = 0;
    for (int l = 0; l < L_; ++l) {
        if (active[b * L_ + l]) {
            IDS[b * KEEP_ + cnt] = l;
            RANK[b * L_ + l] = cnt;
            ++cnt;
        } else {
            RANK[b * L_ + l] = -1;
        }
    }
}

// X[b,i,c] = imgs[b,c,ids[b,i]] + pos[ids[b,i], c]
__global__ void gather_embed_k(const float* __restrict__ imgs,
                               const float* __restrict__ pos,
                               const int* __restrict__ IDS,
                               float* __restrict__ X) {
    int tid = blockIdx.x * 256 + threadIdx.x;
    if (tid >= B_ * KEEP_ * DM_) return;
    int c = tid % DM_;
    int i = (tid / DM_) % KEEP_;
    int b = tid / (DM_ * KEEP_);
    int l = IDS[b * KEEP_ + i];
    X[tid] = imgs[((size_t)b * DM_ + c) * L_ + l] + pos[(size_t)l * DM_ + c];
}

// out[b,c,l] = active ? X[b, rank, c] : mask_token[c]
__global__ void final_scatter_k(const float* __restrict__ X,
                                const float* __restrict__ mask_token,
                                const int* __restrict__ RANK,
                                float* __restrict__ out) {
    int tid = blockIdx.x * 256 + threadIdx.x;
    if (tid >= B_ * DM_ * L_) return;
    int l = tid % L_;
    int c = (tid / L_) % DM_;
    int b = tid / (L_ * DM_);
    int r = RANK[b * L_ + l];
    out[tid] = (r >= 0) ? X[((size_t)b * KEEP_ + r) * DM_ + c] : mask_token[c];
}

// ---------------------------------------------------------------- layernorm
// rows = B*KEEP, cols = DM (384). One wave per row, 4 rows per block.
__global__ void layernorm_k(const float* __restrict__ X,
                            const float* __restrict__ w,
                            const float* __restrict__ bia,
                            float* __restrict__ H, int rows) {
    int row = blockIdx.x * 4 + (threadIdx.x >> 6);
    int lane = threadIdx.x & 63;
    if (row >= rows) return;
    const float* x = X + (size_t)row * DM_;
    float v[6];
    float s = 0.0f;
#pragma unroll
    for (int j = 0; j < 6; ++j) { v[j] = x[lane + 64 * j]; s += v[j]; }
#pragma unroll
    for (int m = 1; m < 64; m <<= 1) s += __shfl_xor(s, m);
    float mu = s * (1.0f / DM_);
    float s2 = 0.0f;
#pragma unroll
    for (int j = 0; j < 6; ++j) { float d = v[j] - mu; s2 += d * d; }
#pragma unroll
    for (int m = 1; m < 64; m <<= 1) s2 += __shfl_xor(s2, m);
    float rs = rsqrtf(s2 * (1.0f / DM_) + 1e-5f);
    float* h = H + (size_t)row * DM_;
#pragma unroll
    for (int j = 0; j < 6; ++j) {
        int c = lane + 64 * j;
        h[c] = (v[j] - mu) * rs * w[c] + bia[c];
    }
}

// ---------------------------------------------------------------- GEMM
// C[m,n] = sum_k A[m,k] * W[n,k]   (W row-major N x K)
// modes: 0 none, 1 bias, 2 bias+softplus, 3 bias+gelu, 4 residual (C+=),
//        5 bias+residual
#define BM_ 64
#define BN_ 64
#define BKK_ 16
__global__ __launch_bounds__(256) void gemm_k(
    const float* __restrict__ A, int lda,
    const float* __restrict__ W,
    const float* __restrict__ bias,
    float* __restrict__ C, int ldc,
    int M, int N, int K, int mode) {
    __shared__ float As[BKK_][BM_ + 1];
    __shared__ float Bs[BKK_][BN_ + 1];
    int t = threadIdx.x;
    int m0 = blockIdx.y * BM_;
    int n0 = blockIdx.x * BN_;
    float acc[4][4] = {{0.f}};
    for (int k0 = 0; k0 < K; k0 += BKK_) {
#pragma unroll
        for (int i = 0; i < 4; ++i) {
            int idx = t + i * 256;
            int mm = idx >> 4;
            int kk = idx & 15;
            float av = 0.0f, wv = 0.0f;
            if (m0 + mm < M && k0 + kk < K)
                av = A[(size_t)(m0 + mm) * lda + k0 + kk];
            if (n0 + mm < N && k0 + kk < K)
                wv = W[(size_t)(n0 + mm) * K + k0 + kk];
            As[kk][mm] = av;
            Bs[kk][mm] = wv;
        }
        __syncthreads();
        int tn4 = (t & 15) * 4, tm4 = (t >> 4) * 4;
#pragma unroll
        for (int kk = 0; kk < BKK_; ++kk) {
            float a[4], bb[4];
#pragma unroll
            for (int i = 0; i < 4; ++i) a[i] = As[kk][tm4 + i];
#pragma unroll
            for (int j = 0; j < 4; ++j) bb[j] = Bs[kk][tn4 + j];
#pragma unroll
            for (int i = 0; i < 4; ++i)
#pragma unroll
                for (int j = 0; j < 4; ++j) acc[i][j] += a[i] * bb[j];
        }
        __syncthreads();
    }
    int tn = n0 + (t & 15) * 4;
    int tm = m0 + (t >> 4) * 4;
#pragma unroll
    for (int i = 0; i < 4; ++i) {
        int m = tm + i;
        if (m >= M) continue;
#pragma unroll
        for (int j = 0; j < 4; ++j) {
            int n = tn + j;
            if (n >= N) continue;
            float v = acc[i][j];
            size_t ci = (size_t)m * ldc + n;
            if (mode == 1) {
                v += bias[n];
            } else if (mode == 2) {
                v = softplus_f(v + bias[n]);
            } else if (mode == 3) {
                v = gelu_exact_f(v + bias[n]);
            } else if (mode == 4) {
                v += C[ci];
            } else if (mode == 5) {
                v += C[ci] + bias[n];
            }
            C[ci] = v;
        }
    }
}

// ---------------------------------------------------------------- conv+silu
// XCONV[dir,b,s,d] = silu( sum_k cw[d,k]*xr_seq[s-3+k] + cb[d] )
// dir 0: xr_seq[j] = XZ[b, j, d];  dir 1: xr_seq[j] = XZ[b, K-1-j, d]
__global__ void conv_silu_k(const float* __restrict__ XZ,
                            const float* __restrict__ cw,
                            const float* __restrict__ cb,
                            float* __restrict__ XCONV) {
    int tid = blockIdx.x * 256 + threadIdx.x;
    if (tid >= 2 * B_ * KEEP_ * DI_) return;
    int d = tid % DI_;
    int s = (tid / DI_) % KEEP_;
    int b = (tid / (DI_ * KEEP_)) % B_;
    int dir = tid / (DI_ * KEEP_ * B_);
    float v = cb[d];
#pragma unroll
    for (int k = 0; k < DC_; ++k) {
        int j = s - (DC_ - 1) + k;
        if (j >= 0) {
            int la = dir ? (KEEP_ - 1 - j) : j;
            v += cw[d * DC_ + k] * XZ[((size_t)b * KEEP_ + la) * (2 * DI_) + d];
        }
    }
    XCONV[tid] = silu_f(v);
}

// ---------------------------------------------------------------- SSM scan
// one thread per (dir, b, d, n); 16-lane butterfly reduces over n.
__global__ void ssm_scan_k(const float* __restrict__ DELTA,
                           const float* __restrict__ XCONV,
                           const float* __restrict__ XDB,
                           const float* __restrict__ XZ,
                           const float* __restrict__ Alog,
                           const float* __restrict__ Ablog,
                           const float* __restrict__ dskip,
                           float* __restrict__ YOUT) {
    int gid = blockIdx.x * 256 + threadIdx.x;
    int n = gid & 15;
    int d = (gid >> 4) % DI_;
    int b = (gid / (16 * DI_)) % B_;
    int dir = gid / (16 * DI_ * B_);
    const float* alog = dir ? Ablog : Alog;
    float Aval = -__expf(alog[d * NS_ + n]);
    float dsk = dskip[d];
    size_t base = (size_t)(dir * B_ + b) * KEEP_;
    float h = 0.0f;
    for (int s = 0; s < KEEP_; ++s) {
        size_t row = base + s;
        float delta = DELTA[row * DI_ + d];
        float xv = XCONV[row * DI_ + d];
        float bm = XDB[row * XPR_ + DTR_ + n];
        float cm = XDB[row * XPR_ + DTR_ + NS_ + n];
        float dA = __expf(delta * Aval);
        h = dA * h + (delta * bm) * xv;
        float contrib = h * cm;
        contrib += __shfl_xor(contrib, 1);
        contrib += __shfl_xor(contrib, 2);
        contrib += __shfl_xor(contrib, 4);
        contrib += __shfl_xor(contrib, 8);
        if (n == 0) {
            int la = dir ? (KEEP_ - 1 - s) : s;
            float z = XZ[((size_t)b * KEEP_ + la) * (2 * DI_) + DI_ + d];
            float y = contrib + dsk * xv;
            YOUT[((size_t)(dir * B_ + b) * KEEP_ + la) * DI_ + d] = y * silu_f(z);
        }
    }
}

// YSUM = YOUT[0] + YOUT[1]
__global__ void add2_k(const float* __restrict__ YOUT, float* __restrict__ YSUM) {
    int tid = blockIdx.x * 256 + threadIdx.x;
    if (tid >= B_ * KEEP_ * DI_) return;
    YSUM[tid] = YOUT[tid] + YOUT[tid + (size_t)B_ * KEEP_ * DI_];
}

// ---------------------------------------------------------------- launcher
extern "C" void kernel_launch(void* const* d_in, const int* in_sizes, int n_in,
                              void* d_out, int out_size, void* d_ws, size_t ws_size,
                              hipStream_t stream) {
    const float* imgs      = (const float*)d_in[0];
    const float* pos       = (const float*)d_in[1];
    const float* mask_tok  = (const float*)d_in[2];
    const float* n1w       = (const float*)d_in[3];
    const float* n1b       = (const float*)d_in[4];
    const float* inW       = (const float*)d_in[5];
    const float* cw        = (const float*)d_in[6];
    const float* cb        = (const float*)d_in[7];
    const float* xpw       = (const float*)d_in[8];
    const float* dtw       = (const float*)d_in[9];
    const float* dtb       = (const float*)d_in[10];
    const float* Alog      = (const float*)d_in[11];
    const float* Ablog     = (const float*)d_in[12];
    const float* dskip     = (const float*)d_in[13];
    const float* ow        = (const float*)d_in[14];
    const float* n2w       = (const float*)d_in[15];
    const float* n2b       = (const float*)d_in[16];
    const float* f1w       = (const float*)d_in[17];
    const float* f1b       = (const float*)d_in[18];
    const float* f2w       = (const float*)d_in[19];
    const float* f2b       = (const float*)d_in[20];
    const int*   active    = (const int*)d_in[21];
    float* out = (float*)d_out;

    // workspace carve
    char* w = (char*)d_ws;
    auto alloc = [&](size_t bytes) {
        void* p = (void*)w;
        w += (bytes + 255) & ~(size_t)255;
        return p;
    };
    int*   RANK  = (int*)  alloc((size_t)B_ * L_ * 4);
    int*   IDS   = (int*)  alloc((size_t)B_ * KEEP_ * 4);
    float* X     = (float*)alloc((size_t)B_ * KEEP_ * DM_ * 4);
    float* H     = (float*)alloc((size_t)B_ * KEEP_ * DM_ * 4);
    float* XZ    = (float*)alloc((size_t)B_ * KEEP_ * 2 * DI_ * 4);
    float* XCONV = (float*)alloc((size_t)2 * B_ * KEEP_ * DI_ * 4);
    float* XDB   = (float*)alloc((size_t)2 * B_ * KEEP_ * XPR_ * 4);
    float* DELTA = (float*)alloc((size_t)2 * B_ * KEEP_ * DI_ * 4);
    float* YOUT  = (float*)alloc((size_t)2 * B_ * KEEP_ * DI_ * 4);
    float* YSUM  = (float*)alloc((size_t)B_ * KEEP_ * DI_ * 4);
    float* G     = (float*)alloc((size_t)B_ * KEEP_ * DI_ * 4);

    const int ROWS = B_ * KEEP_;       // 1728
    const int ROWS2 = 2 * B_ * KEEP_;  // 3456

    compute_ids_k<<<1, 64, 0, stream>>>(active, RANK, IDS);
    gather_embed_k<<<(B_ * KEEP_ * DM_ + 255) / 256, 256, 0, stream>>>(imgs, pos, IDS, X);

    for (int layer = 0; layer < DEPTH_; ++layer) {
        const float* L_inW = inW + (size_t)layer * 2 * DI_ * DM_;
        const float* L_cw  = cw  + (size_t)layer * DI_ * DC_;
        const float* L_cb  = cb  + (size_t)layer * DI_;
        const float* L_xpw = xpw + (size_t)layer * XPR_ * DI_;
        const float* L_dtw = dtw + (size_t)layer * DI_ * DTR_;
        const float* L_dtb = dtb + (size_t)layer * DI_;
        const float* L_Al  = Alog  + (size_t)layer * DI_ * NS_;
        const float* L_Abl = Ablog + (size_t)layer * DI_ * NS_;
        const float* L_dsk = dskip + (size_t)layer * DI_;
        const float* L_ow  = ow  + (size_t)layer * DM_ * DI_;
        const float* L_f1w = f1w + (size_t)layer * 2 * DM_ * DM_;
        const float* L_f1b = f1b + (size_t)layer * 2 * DM_;
        const float* L_f2w = f2w + (size_t)layer * DM_ * 2 * DM_;
        const float* L_f2b = f2b + (size_t)layer * DM_;

        // LN1
        layernorm_k<<<(ROWS + 3) / 4, 256, 0, stream>>>(
            X, n1w + layer * DM_, n1b + layer * DM_, H, ROWS);
        // in_proj: (1728 x 384) x (1536 x 384)^T -> XZ (1728 x 1536)
        gemm_k<<<dim3((2 * DI_) / BN_, ROWS / BM_), 256, 0, stream>>>(
            H, DM_, L_inW, nullptr, XZ, 2 * DI_, ROWS, 2 * DI_, DM_, 0);
        // conv + silu (both directions)
        conv_silu_k<<<(2 * B_ * KEEP_ * DI_ + 255) / 256, 256, 0, stream>>>(
            XZ, L_cw, L_cb, XCONV);
        // x_proj: (3456 x 768) x (56 x 768)^T -> XDB (3456 x 56)
        gemm_k<<<dim3((XPR_ + BN_ - 1) / BN_, ROWS2 / BM_), 256, 0, stream>>>(
            XCONV, DI_, L_xpw, nullptr, XDB, XPR_, ROWS2, XPR_, DI_, 0);
        // dt: (3456 x 24 view of XDB) x (768 x 24)^T + dtb, softplus -> DELTA
        gemm_k<<<dim3(DI_ / BN_, ROWS2 / BM_), 256, 0, stream>>>(
            XDB, XPR_, L_dtw, L_dtb, DELTA, DI_, ROWS2, DI_, DTR_, 2);
        // scan
        ssm_scan_k<<<(2 * B_ * DI_ * NS_) / 256, 256, 0, stream>>>(
            DELTA, XCONV, XDB, XZ, L_Al, L_Abl, L_dsk, YOUT);
        // yf + yb
        add2_k<<<(B_ * KEEP_ * DI_ + 255) / 256, 256, 0, stream>>>(YOUT, YSUM);
        // out_proj + residual: X += YSUM (1728x768) x (384x768)^T
        gemm_k<<<dim3(DM_ / BN_, ROWS / BM_), 256, 0, stream>>>(
            YSUM, DI_, L_ow, nullptr, X, DM_, ROWS, DM_, DI_, 4);
        // LN2
        layernorm_k<<<(ROWS + 3) / 4, 256, 0, stream>>>(
            X, n2w + layer * DM_, n2b + layer * DM_, H, ROWS);
        // fc1 + bias + gelu: (1728x384) x (768x384)^T -> G
        gemm_k<<<dim3((2 * DM_) / BN_, ROWS / BM_), 256, 0, stream>>>(
            H, DM_, L_f1w, L_f1b, G, 2 * DM_, ROWS, 2 * DM_, DM_, 3);
        // fc2 + bias + residual: X += G (1728x768) x (384x768)^T + f2b
        gemm_k<<<dim3(DM_ / BN_, ROWS / BM_), 256, 0, stream>>>(
            G, 2 * DM_, L_f2w, L_f2b, X, DM_, ROWS, DM_, 2 * DM_, 5);
    }

    final_scatter_k<<<(B_ * DM_ * L_ + 255) / 256, 256, 0, stream>>>(
        X, mask_tok, RANK, out);
}

// Round 2
// 4740.012 us; speedup vs baseline: 1.3710x; 1.3710x over previous
//
#include <hip/hip_runtime.h>
#include <hip/hip_bf16.h>
#include <math.h>

#define B_    4
#define GRID_ 12
#define DM_   384
#define DEPTH_ 8
#define L_    1728      // 12^3
#define DI_   768
#define NS_   16
#define DC_   4
#define DTR_  24
#define KEEP_ 432
#define XPR_  56        // DTR + 2*NS

// ---------------------------------------------------------------- utilities
__device__ __forceinline__ float silu_f(float x) {
    return x / (1.0f + __expf(-x));
}
__device__ __forceinline__ float softplus_f(float x) {
    return (x > 20.0f) ? x : log1pf(expf(x));
}
__device__ __forceinline__ float gelu_exact_f(float x) {
    return 0.5f * x * (1.0f + erff(x * 0.7071067811865476f));
}

// ---------------------------------------------------------------- ids / rank
// One block per batch: parallel stable-rank via 256-thread prefix scan.
// Active positions in ascending order get ranks 0..KEEP-1; inactive -1.
__global__ __launch_bounds__(256) void compute_ids_k(
        const int* __restrict__ active,
        int* __restrict__ RANK, int* __restrict__ IDS) {
    __shared__ int cnt[256];
    int b = blockIdx.x;
    int t = threadIdx.x;
    const int PER = (L_ + 255) / 256;   // 7
    int base = t * PER;
    int c = 0;
    for (int j = 0; j < PER; ++j) {
        int l = base + j;
        if (l < L_ && active[b * L_ + l]) ++c;
    }
    cnt[t] = c;
    __syncthreads();
    for (int off = 1; off < 256; off <<= 1) {
        int v = (t >= off) ? cnt[t - off] : 0;
        __syncthreads();
        cnt[t] += v;
        __syncthreads();
    }
    int r = cnt[t] - c;   // exclusive prefix
    for (int j = 0; j < PER; ++j) {
        int l = base + j;
        if (l >= L_) break;
        if (active[b * L_ + l]) {
            RANK[b * L_ + l] = r;
            IDS[b * KEEP_ + r] = l;
            ++r;
        } else {
            RANK[b * L_ + l] = -1;
        }
    }
}

// X[b,i,c] = imgs[b,c,ids[b,i]] + pos[ids[b,i], c]
__global__ void gather_embed_k(const float* __restrict__ imgs,
                               const float* __restrict__ pos,
                               const int* __restrict__ IDS,
                               float* __restrict__ X) {
    int tid = blockIdx.x * 256 + threadIdx.x;
    if (tid >= B_ * KEEP_ * DM_) return;
    int c = tid % DM_;
    int i = (tid / DM_) % KEEP_;
    int b = tid / (DM_ * KEEP_);
    int l = IDS[b * KEEP_ + i];
    X[tid] = imgs[((size_t)b * DM_ + c) * L_ + l] + pos[(size_t)l * DM_ + c];
}

// out[b,c,l] = active ? X[b, rank, c] : mask_token[c]
__global__ void final_scatter_k(const float* __restrict__ X,
                                const float* __restrict__ mask_token,
                                const int* __restrict__ RANK,
                                float* __restrict__ out) {
    int tid = blockIdx.x * 256 + threadIdx.x;
    if (tid >= B_ * DM_ * L_) return;
    int l = tid % L_;
    int c = (tid / L_) % DM_;
    int b = tid / (L_ * DM_);
    int r = RANK[b * L_ + l];
    out[tid] = (r >= 0) ? X[((size_t)b * KEEP_ + r) * DM_ + c] : mask_token[c];
}

// ---------------------------------------------------------------- layernorm
// rows = B*KEEP, cols = DM (384). One wave per row, 4 rows per block.
__global__ void layernorm_k(const float* __restrict__ X,
                            const float* __restrict__ w,
                            const float* __restrict__ bia,
                            float* __restrict__ H, int rows) {
    int row = blockIdx.x * 4 + (threadIdx.x >> 6);
    int lane = threadIdx.x & 63;
    if (row >= rows) return;
    const float* x = X + (size_t)row * DM_;
    float v[6];
    float s = 0.0f;
#pragma unroll
    for (int j = 0; j < 6; ++j) { v[j] = x[lane + 64 * j]; s += v[j]; }
#pragma unroll
    for (int m = 1; m < 64; m <<= 1) s += __shfl_xor(s, m);
    float mu = s * (1.0f / DM_);
    float s2 = 0.0f;
#pragma unroll
    for (int j = 0; j < 6; ++j) { float d = v[j] - mu; s2 += d * d; }
#pragma unroll
    for (int m = 1; m < 64; m <<= 1) s2 += __shfl_xor(s2, m);
    float rs = rsqrtf(s2 * (1.0f / DM_) + 1e-5f);
    float* h = H + (size_t)row * DM_;
#pragma unroll
    for (int j = 0; j < 6; ++j) {
        int c = lane + 64 * j;
        h[c] = (v[j] - mu) * rs * w[c] + bia[c];
    }
}

// ---------------------------------------------------------------- GEMM
// C[m,n] = sum_k A[m,k] * W[n,k]   (W row-major N x K)
// modes: 0 none, 1 bias, 2 bias+softplus, 3 bias+gelu, 4 residual (C+=),
//        5 bias+residual
#define BM_ 64
#define BN_ 64
#define BKK_ 16
__global__ __launch_bounds__(256) void gemm_k(
    const float* __restrict__ A, int lda,
    const float* __restrict__ W,
    const float* __restrict__ bias,
    float* __restrict__ C, int ldc,
    int M, int N, int K, int mode) {
    __shared__ float As[BKK_][BM_ + 1];
    __shared__ float Bs[BKK_][BN_ + 1];
    int t = threadIdx.x;
    int m0 = blockIdx.y * BM_;
    int n0 = blockIdx.x * BN_;
    float acc[4][4] = {{0.f}};
    for (int k0 = 0; k0 < K; k0 += BKK_) {
#pragma unroll
        for (int i = 0; i < 4; ++i) {
            int idx = t + i * 256;
            int mm = idx >> 4;
            int kk = idx & 15;
            float av = 0.0f, wv = 0.0f;
            if (m0 + mm < M && k0 + kk < K)
                av = A[(size_t)(m0 + mm) * lda + k0 + kk];
            if (n0 + mm < N && k0 + kk < K)
                wv = W[(size_t)(n0 + mm) * K + k0 + kk];
            As[kk][mm] = av;
            Bs[kk][mm] = wv;
        }
        __syncthreads();
        int tn4 = (t & 15) * 4, tm4 = (t >> 4) * 4;
#pragma unroll
        for (int kk = 0; kk < BKK_; ++kk) {
            float a[4], bb[4];
#pragma unroll
            for (int i = 0; i < 4; ++i) a[i] = As[kk][tm4 + i];
#pragma unroll
            for (int j = 0; j < 4; ++j) bb[j] = Bs[kk][tn4 + j];
#pragma unroll
            for (int i = 0; i < 4; ++i)
#pragma unroll
                for (int j = 0; j < 4; ++j) acc[i][j] += a[i] * bb[j];
        }
        __syncthreads();
    }
    int tn = n0 + (t & 15) * 4;
    int tm = m0 + (t >> 4) * 4;
#pragma unroll
    for (int i = 0; i < 4; ++i) {
        int m = tm + i;
        if (m >= M) continue;
#pragma unroll
        for (int j = 0; j < 4; ++j) {
            int n = tn + j;
            if (n >= N) continue;
            float v = acc[i][j];
            size_t ci = (size_t)m * ldc + n;
            if (mode == 1) {
                v += bias[n];
            } else if (mode == 2) {
                v = softplus_f(v + bias[n]);
            } else if (mode == 3) {
                v = gelu_exact_f(v + bias[n]);
            } else if (mode == 4) {
                v += C[ci];
            } else if (mode == 5) {
                v += C[ci] + bias[n];
            }
            C[ci] = v;
        }
    }
}

// ---------------------------------------------------------------- conv+silu
// XCONV[dir,b,s,d] = silu( sum_k cw[d,k]*xr_seq[s-3+k] + cb[d] )
// dir 0: xr_seq[j] = XZ[b, j, d];  dir 1: xr_seq[j] = XZ[b, K-1-j, d]
__global__ void conv_silu_k(const float* __restrict__ XZ,
                            const float* __restrict__ cw,
                            const float* __restrict__ cb,
                            float* __restrict__ XCONV) {
    int tid = blockIdx.x * 256 + threadIdx.x;
    if (tid >= 2 * B_ * KEEP_ * DI_) return;
    int d = tid % DI_;
    int s = (tid / DI_) % KEEP_;
    int b = (tid / (DI_ * KEEP_)) % B_;
    int dir = tid / (DI_ * KEEP_ * B_);
    float v = cb[d];
#pragma unroll
    for (int k = 0; k < DC_; ++k) {
        int j = s - (DC_ - 1) + k;
        if (j >= 0) {
            int la = dir ? (KEEP_ - 1 - j) : j;
            v += cw[d * DC_ + k] * XZ[((size_t)b * KEEP_ + la) * (2 * DI_) + d];
        }
    }
    XCONV[tid] = silu_f(v);
}

// ---------------------------------------------------------------- SSM scan
// Cooperative version: one block per (dir, b, 16-d slice). 256 threads =
// 16 d x 16 n. Sequence is processed in LDS-staged chunks of SCS_ steps so
// the recurrence's dependent chain never touches global memory.
#define SCS_ 72   // 432 = 6 * 72
__global__ __launch_bounds__(256) void ssm_scan_k(
        const float* __restrict__ DELTA,
        const float* __restrict__ XCONV,
        const float* __restrict__ XDB,
        const float* __restrict__ XZ,
        const float* __restrict__ Alog,
        const float* __restrict__ Ablog,
        const float* __restrict__ dskip,
        float* __restrict__ YOUT) {
    __shared__ float sD[SCS_][16];   // delta  [step][d-local]
    __shared__ float sX[SCS_][16];   // xconv  [step][d-local]
    __shared__ float sB[SCS_][16];   // B      [step][n]
    __shared__ float sC[SCS_][16];   // C      [step][n]
    __shared__ float sZ[SCS_][16];   // z-gate [step][d-local]

    const int NDB = DI_ / 16;        // 48 d-slices
    int blk = blockIdx.x;
    int d0  = (blk % NDB) * 16;
    int b   = (blk / NDB) % B_;
    int dir = blk / (NDB * B_);

    int t  = threadIdx.x;
    int n  = t & 15;                 // state index
    int dl = t >> 4;                 // d-local 0..15
    int d  = d0 + dl;

    const float* alog = dir ? Ablog : Alog;
    float Aval = -__expf(alog[d * NS_ + n]);
    float dsk  = dskip[d];
    size_t base = (size_t)(dir * B_ + b) * KEEP_;

    float h = 0.0f;
    for (int c0 = 0; c0 < KEEP_; c0 += SCS_) {
        // cooperative staging: coalesced 64B segments per 16 threads
        for (int i = t; i < SCS_ * 16; i += 256) {
            int s   = i >> 4;
            int col = i & 15;
            size_t row = base + c0 + s;
            sD[s][col] = DELTA[row * DI_ + d0 + col];
            sX[s][col] = XCONV[row * DI_ + d0 + col];
            sB[s][col] = XDB[row * XPR_ + DTR_ + col];
            sC[s][col] = XDB[row * XPR_ + DTR_ + NS_ + col];
            int la = dir ? (KEEP_ - 1 - (c0 + s)) : (c0 + s);
            sZ[s][col] = XZ[((size_t)b * KEEP_ + la) * (2 * DI_) + DI_ + d0 + col];
        }
        __syncthreads();
        for (int s = 0; s < SCS_; ++s) {
            float delta = sD[s][dl];
            float xv    = sX[s][dl];
            float bm    = sB[s][n];
            float cm    = sC[s][n];
            float dA = __expf(delta * Aval);
            h = dA * h + (delta * bm) * xv;
            float contrib = h * cm;
            contrib += __shfl_xor(contrib, 1);
            contrib += __shfl_xor(contrib, 2);
            contrib += __shfl_xor(contrib, 4);
            contrib += __shfl_xor(contrib, 8);
            if (n == 0) {
                int la = dir ? (KEEP_ - 1 - (c0 + s)) : (c0 + s);
                float y = contrib + dsk * xv;
                YOUT[((size_t)(dir * B_ + b) * KEEP_ + la) * DI_ + d] =
                    y * silu_f(sZ[s][dl]);
            }
        }
        __syncthreads();
    }
}

// YSUM = YOUT[0] + YOUT[1]
__global__ void add2_k(const float* __restrict__ YOUT, float* __restrict__ YSUM) {
    int tid = blockIdx.x * 256 + threadIdx.x;
    if (tid >= B_ * KEEP_ * DI_) return;
    YSUM[tid] = YOUT[tid] + YOUT[tid + (size_t)B_ * KEEP_ * DI_];
}

// ---------------------------------------------------------------- launcher
extern "C" void kernel_launch(void* const* d_in, const int* in_sizes, int n_in,
                              void* d_out, int out_size, void* d_ws, size_t ws_size,
                              hipStream_t stream) {
    const float* imgs      = (const float*)d_in[0];
    const float* pos       = (const float*)d_in[1];
    const float* mask_tok  = (const float*)d_in[2];
    const float* n1w       = (const float*)d_in[3];
    const float* n1b       = (const float*)d_in[4];
    const float* inW       = (const float*)d_in[5];
    const float* cw        = (const float*)d_in[6];
    const float* cb        = (const float*)d_in[7];
    const float* xpw       = (const float*)d_in[8];
    const float* dtw       = (const float*)d_in[9];
    const float* dtb       = (const float*)d_in[10];
    const float* Alog      = (const float*)d_in[11];
    const float* Ablog     = (const float*)d_in[12];
    const float* dskip     = (const float*)d_in[13];
    const float* ow        = (const float*)d_in[14];
    const float* n2w       = (const float*)d_in[15];
    const float* n2b       = (const float*)d_in[16];
    const float* f1w       = (const float*)d_in[17];
    const float* f1b       = (const float*)d_in[18];
    const float* f2w       = (const float*)d_in[19];
    const float* f2b       = (const float*)d_in[20];
    const int*   active    = (const int*)d_in[21];
    float* out = (float*)d_out;

    // workspace carve
    char* w = (char*)d_ws;
    auto alloc = [&](size_t bytes) {
        void* p = (void*)w;
        w += (bytes + 255) & ~(size_t)255;
        return p;
    };
    int*   RANK  = (int*)  alloc((size_t)B_ * L_ * 4);
    int*   IDS   = (int*)  alloc((size_t)B_ * KEEP_ * 4);
    float* X     = (float*)alloc((size_t)B_ * KEEP_ * DM_ * 4);
    float* H     = (float*)alloc((size_t)B_ * KEEP_ * DM_ * 4);
    float* XZ    = (float*)alloc((size_t)B_ * KEEP_ * 2 * DI_ * 4);
    float* XCONV = (float*)alloc((size_t)2 * B_ * KEEP_ * DI_ * 4);
    float* XDB   = (float*)alloc((size_t)2 * B_ * KEEP_ * XPR_ * 4);
    float* DELTA = (float*)alloc((size_t)2 * B_ * KEEP_ * DI_ * 4);
    float* YOUT  = (float*)alloc((size_t)2 * B_ * KEEP_ * DI_ * 4);
    float* YSUM  = (float*)alloc((size_t)B_ * KEEP_ * DI_ * 4);
    float* G     = (float*)alloc((size_t)B_ * KEEP_ * DI_ * 4);

    const int ROWS = B_ * KEEP_;       // 1728
    const int ROWS2 = 2 * B_ * KEEP_;  // 3456

    compute_ids_k<<<B_, 256, 0, stream>>>(active, RANK, IDS);
    gather_embed_k<<<(B_ * KEEP_ * DM_ + 255) / 256, 256, 0, stream>>>(imgs, pos, IDS, X);

    for (int layer = 0; layer < DEPTH_; ++layer) {
        const float* L_inW = inW + (size_t)layer * 2 * DI_ * DM_;
        const float* L_cw  = cw  + (size_t)layer * DI_ * DC_;
        const float* L_cb  = cb  + (size_t)layer * DI_;
        const float* L_xpw = xpw + (size_t)layer * XPR_ * DI_;
        const float* L_dtw = dtw + (size_t)layer * DI_ * DTR_;
        const float* L_dtb = dtb + (size_t)layer * DI_;
        const float* L_Al  = Alog  + (size_t)layer * DI_ * NS_;
        const float* L_Abl = Ablog + (size_t)layer * DI_ * NS_;
        const float* L_dsk = dskip + (size_t)layer * DI_;
        const float* L_ow  = ow  + (size_t)layer * DM_ * DI_;
        const float* L_f1w = f1w + (size_t)layer * 2 * DM_ * DM_;
        const float* L_f1b = f1b + (size_t)layer * 2 * DM_;
        const float* L_f2w = f2w + (size_t)layer * DM_ * 2 * DM_;
        const float* L_f2b = f2b + (size_t)layer * DM_;

        // LN1
        layernorm_k<<<(ROWS + 3) / 4, 256, 0, stream>>>(
            X, n1w + layer * DM_, n1b + layer * DM_, H, ROWS);
        // in_proj: (1728 x 384) x (1536 x 384)^T -> XZ (1728 x 1536)
        gemm_k<<<dim3((2 * DI_) / BN_, ROWS / BM_), 256, 0, stream>>>(
            H, DM_, L_inW, nullptr, XZ, 2 * DI_, ROWS, 2 * DI_, DM_, 0);
        // conv + silu (both directions)
        conv_silu_k<<<(2 * B_ * KEEP_ * DI_ + 255) / 256, 256, 0, stream>>>(
            XZ, L_cw, L_cb, XCONV);
        // x_proj: (3456 x 768) x (56 x 768)^T -> XDB (3456 x 56)
        gemm_k<<<dim3((XPR_ + BN_ - 1) / BN_, ROWS2 / BM_), 256, 0, stream>>>(
            XCONV, DI_, L_xpw, nullptr, XDB, XPR_, ROWS2, XPR_, DI_, 0);
        // dt: (3456 x 24 view of XDB) x (768 x 24)^T + dtb, softplus -> DELTA
        gemm_k<<<dim3(DI_ / BN_, ROWS2 / BM_), 256, 0, stream>>>(
            XDB, XPR_, L_dtw, L_dtb, DELTA, DI_, ROWS2, DI_, DTR_, 2);
        // scan (cooperative, LDS-staged)
        ssm_scan_k<<<2 * B_ * (DI_ / 16), 256, 0, stream>>>(
            DELTA, XCONV, XDB, XZ, L_Al, L_Abl, L_dsk, YOUT);
        // yf + yb
        add2_k<<<(B_ * KEEP_ * DI_ + 255) / 256, 256, 0, stream>>>(YOUT, YSUM);
        // out_proj + residual: X += YSUM (1728x768) x (384x768)^T
        gemm_k<<<dim3(DM_ / BN_, ROWS / BM_), 256, 0, stream>>>(
            YSUM, DI_, L_ow, nullptr, X, DM_, ROWS, DM_, DI_, 4);
        // LN2
        layernorm_k<<<(ROWS + 3) / 4, 256, 0, stream>>>(
            X, n2w + layer * DM_, n2b + layer * DM_, H, ROWS);
        // fc1 + bias + gelu: (1728x384) x (768x384)^T -> G
        gemm_k<<<dim3((2 * DM_) / BN_, ROWS / BM_), 256, 0, stream>>>(
            H, DM_, L_f1w, L_f1b, G, 2 * DM_, ROWS, 2 * DM_, DM_, 3);
        // fc2 + bias + residual: X += G (1728x768) x (384x768)^T + f2b
        gemm_k<<<dim3(DM_ / BN_, ROWS / BM_), 256, 0, stream>>>(
            G, 2 * DM_, L_f2w, L_f2b, X, DM_, ROWS, DM_, 2 * DM_, 5);
    }

    final_scatter_k<<<(B_ * DM_ * L_ + 255) / 256, 256, 0, stream>>>(
        X, mask_tok, RANK, out);
}

// Round 3
// 3748.388 us; speedup vs baseline: 1.7337x; 1.2645x over previous
//
#include <hip/hip_runtime.h>
#include <hip/hip_bf16.h>
#include <math.h>

#define B_    4
#define GRID_ 12
#define DM_   384
#define DEPTH_ 8
#define L_    1728      // 12^3
#define DI_   768
#define NS_   16
#define DC_   4
#define DTR_  24
#define KEEP_ 432
#define XPR_  56        // DTR + 2*NS
#define NC_   16        // scan chunks
#define CL_   27        // steps per chunk (16*27 = 432)

// ---------------------------------------------------------------- utilities
__device__ __forceinline__ float silu_f(float x) {
    return x / (1.0f + __expf(-x));
}
__device__ __forceinline__ float softplus_f(float x) {
    return (x > 20.0f) ? x : log1pf(expf(x));
}
__device__ __forceinline__ float gelu_exact_f(float x) {
    return 0.5f * x * (1.0f + erff(x * 0.7071067811865476f));
}

// ---------------------------------------------------------------- ids / rank
__global__ __launch_bounds__(256) void compute_ids_k(
        const int* __restrict__ active,
        int* __restrict__ RANK, int* __restrict__ IDS) {
    __shared__ int cnt[256];
    int b = blockIdx.x;
    int t = threadIdx.x;
    const int PER = (L_ + 255) / 256;   // 7
    int base = t * PER;
    int c = 0;
    for (int j = 0; j < PER; ++j) {
        int l = base + j;
        if (l < L_ && active[b * L_ + l]) ++c;
    }
    cnt[t] = c;
    __syncthreads();
    for (int off = 1; off < 256; off <<= 1) {
        int v = (t >= off) ? cnt[t - off] : 0;
        __syncthreads();
        cnt[t] += v;
        __syncthreads();
    }
    int r = cnt[t] - c;   // exclusive prefix
    for (int j = 0; j < PER; ++j) {
        int l = base + j;
        if (l >= L_) break;
        if (active[b * L_ + l]) {
            RANK[b * L_ + l] = r;
            IDS[b * KEEP_ + r] = l;
            ++r;
        } else {
            RANK[b * L_ + l] = -1;
        }
    }
}

// X[b,i,c] = imgs[b,c,ids[b,i]] + pos[ids[b,i], c]
__global__ void gather_embed_k(const float* __restrict__ imgs,
                               const float* __restrict__ pos,
                               const int* __restrict__ IDS,
                               float* __restrict__ X) {
    int tid = blockIdx.x * 256 + threadIdx.x;
    if (tid >= B_ * KEEP_ * DM_) return;
    int c = tid % DM_;
    int i = (tid / DM_) % KEEP_;
    int b = tid / (DM_ * KEEP_);
    int l = IDS[b * KEEP_ + i];
    X[tid] = imgs[((size_t)b * DM_ + c) * L_ + l] + pos[(size_t)l * DM_ + c];
}

// out[b,c,l] = active ? X[b, rank, c] : mask_token[c]
__global__ void final_scatter_k(const float* __restrict__ X,
                                const float* __restrict__ mask_token,
                                const int* __restrict__ RANK,
                                float* __restrict__ out) {
    int tid = blockIdx.x * 256 + threadIdx.x;
    if (tid >= B_ * DM_ * L_) return;
    int l = tid % L_;
    int c = (tid / L_) % DM_;
    int b = tid / (L_ * DM_);
    int r = RANK[b * L_ + l];
    out[tid] = (r >= 0) ? X[((size_t)b * KEEP_ + r) * DM_ + c] : mask_token[c];
}

// ---------------------------------------------------------------- layernorm
__global__ void layernorm_k(const float* __restrict__ X,
                            const float* __restrict__ w,
                            const float* __restrict__ bia,
                            float* __restrict__ H, int rows) {
    int row = blockIdx.x * 4 + (threadIdx.x >> 6);
    int lane = threadIdx.x & 63;
    if (row >= rows) return;
    const float* x = X + (size_t)row * DM_;
    float v[6];
    float s = 0.0f;
#pragma unroll
    for (int j = 0; j < 6; ++j) { v[j] = x[lane + 64 * j]; s += v[j]; }
#pragma unroll
    for (int m = 1; m < 64; m <<= 1) s += __shfl_xor(s, m);
    float mu = s * (1.0f / DM_);
    float s2 = 0.0f;
#pragma unroll
    for (int j = 0; j < 6; ++j) { float d = v[j] - mu; s2 += d * d; }
#pragma unroll
    for (int m = 1; m < 64; m <<= 1) s2 += __shfl_xor(s2, m);
    float rs = rsqrtf(s2 * (1.0f / DM_) + 1e-5f);
    float* h = H + (size_t)row * DM_;
#pragma unroll
    for (int j = 0; j < 6; ++j) {
        int c = lane + 64 * j;
        h[c] = (v[j] - mu) * rs * w[c] + bia[c];
    }
}

// ---------------------------------------------------------------- GEMM
// C[m,n] = sum_k (A[m,k] (+ A2[m,k])) * W[n,k]   (W row-major N x K)
// modes: 0 none, 1 bias, 2 bias+softplus, 3 bias+gelu, 4 residual (C+=),
//        5 bias+residual
#define BM_ 64
#define BN_ 64
#define BKK_ 16
#define PAD_ 68   // 16B-aligned rows -> ds_read_b128; stride-68 <=2-way conflict (free)
__global__ __launch_bounds__(256) void gemm_k(
    const float* __restrict__ A, const float* __restrict__ A2, int lda,
    const float* __restrict__ W,
    const float* __restrict__ bias,
    float* __restrict__ C, int ldc,
    int M, int N, int K, int mode) {
    __shared__ float As[BKK_][PAD_];
    __shared__ float Bs[BKK_][PAD_];
    int t = threadIdx.x;
    int m0 = blockIdx.y * BM_;
    int n0 = blockIdx.x * BN_;
    float acc[4][4] = {{0.f}};
    for (int k0 = 0; k0 < K; k0 += BKK_) {
#pragma unroll
        for (int i = 0; i < 4; ++i) {
            int idx = t + i * 256;
            int mm = idx >> 4;
            int kk = idx & 15;
            float av = 0.0f, wv = 0.0f;
            if (m0 + mm < M && k0 + kk < K) {
                size_t ai = (size_t)(m0 + mm) * lda + k0 + kk;
                av = A[ai];
                if (A2) av += A2[ai];
            }
            if (n0 + mm < N && k0 + kk < K)
                wv = W[(size_t)(n0 + mm) * K + k0 + kk];
            As[kk][mm] = av;
            Bs[kk][mm] = wv;
        }
        __syncthreads();
        int tn4 = (t & 15) * 4, tm4 = (t >> 4) * 4;
#pragma unroll
        for (int kk = 0; kk < BKK_; ++kk) {
            float a[4], bb[4];
#pragma unroll
            for (int i = 0; i < 4; ++i) a[i] = As[kk][tm4 + i];
#pragma unroll
            for (int j = 0; j < 4; ++j) bb[j] = Bs[kk][tn4 + j];
#pragma unroll
            for (int i = 0; i < 4; ++i)
#pragma unroll
                for (int j = 0; j < 4; ++j) acc[i][j] += a[i] * bb[j];
        }
        __syncthreads();
    }
    int tn = n0 + (t & 15) * 4;
    int tm = m0 + (t >> 4) * 4;
#pragma unroll
    for (int i = 0; i < 4; ++i) {
        int m = tm + i;
        if (m >= M) continue;
#pragma unroll
        for (int j = 0; j < 4; ++j) {
            int n = tn + j;
            if (n >= N) continue;
            float v = acc[i][j];
            size_t ci = (size_t)m * ldc + n;
            if (mode == 1) {
                v += bias[n];
            } else if (mode == 2) {
                v = softplus_f(v + bias[n]);
            } else if (mode == 3) {
                v = gelu_exact_f(v + bias[n]);
            } else if (mode == 4) {
                v += C[ci];
            } else if (mode == 5) {
                v += C[ci] + bias[n];
            }
            C[ci] = v;
        }
    }
}

// ---------------------------------------------------------------- conv+silu
__global__ void conv_silu_k(const float* __restrict__ XZ,
                            const float* __restrict__ cw,
                            const float* __restrict__ cb,
                            float* __restrict__ XCONV) {
    int tid = blockIdx.x * 256 + threadIdx.x;
    if (tid >= 2 * B_ * KEEP_ * DI_) return;
    int d = tid % DI_;
    int s = (tid / DI_) % KEEP_;
    int b = (tid / (DI_ * KEEP_)) % B_;
    int dir = tid / (DI_ * KEEP_ * B_);
    float v = cb[d];
#pragma unroll
    for (int k = 0; k < DC_; ++k) {
        int j = s - (DC_ - 1) + k;
        if (j >= 0) {
            int la = dir ? (KEEP_ - 1 - j) : j;
            v += cw[d * DC_ + k] * XZ[((size_t)b * KEEP_ + la) * (2 * DI_) + d];
        }
    }
    XCONV[tid] = silu_f(v);
}

// ---------------------------------------------------------------- SSM scan
// Chunked parallel scan, 3 phases. State per (d) thread lives in registers
// (h[16]); no cross-lane ops. Linear recurrence h=a*h+b is associative:
// chunk-local scans (A), cross-chunk combine (B), replay with h_init (C).
// Decay product over a chunk = exp(A[n] * sum(delta)).

// Phase A: thread = (dir,b,d,chunk). Block = 256 d's; grid covers 3 d-groups.
__global__ __launch_bounds__(256) void scan_partial_k(
        const float* __restrict__ DELTA,
        const float* __restrict__ XCONV,
        const float* __restrict__ XDB,
        const float* __restrict__ Alog,
        const float* __restrict__ Ablog,
        float* __restrict__ HFIN,
        float* __restrict__ SDELT) {
    __shared__ float sB[CL_][NS_];
    int blk = blockIdx.x;
    int g   = blk % 3;
    int c   = (blk / 3) % NC_;
    int b   = (blk / (3 * NC_)) % B_;
    int dir = blk / (3 * NC_ * B_);
    int t = threadIdx.x;
    int d = g * 256 + t;
    size_t base = (size_t)(dir * B_ + b) * KEEP_ + c * CL_;

    for (int i = t; i < CL_ * NS_; i += 256) {
        int s = i >> 4, n = i & 15;
        sB[s][n] = XDB[(base + s) * XPR_ + DTR_ + n];
    }
    __syncthreads();

    const float* alog = dir ? Ablog : Alog;
    float Av[NS_];
#pragma unroll
    for (int n = 0; n < NS_; ++n) Av[n] = -__expf(alog[d * NS_ + n]);
    float h[NS_];
#pragma unroll
    for (int n = 0; n < NS_; ++n) h[n] = 0.0f;
    float sdel = 0.0f;

    float nd = DELTA[base * DI_ + d];
    float nx = XCONV[base * DI_ + d];
    for (int s = 0; s < CL_; ++s) {
        float delta = nd, xv = nx;
        if (s + 1 < CL_) {
            nd = DELTA[(base + s + 1) * DI_ + d];
            nx = XCONV[(base + s + 1) * DI_ + d];
        }
        sdel += delta;
        float dx = delta * xv;
#pragma unroll
        for (int n = 0; n < NS_; ++n)
            h[n] = __expf(delta * Av[n]) * h[n] + dx * sB[s][n];
    }
    size_t o = ((size_t)(dir * B_ + b) * NC_ + c) * DI_ + d;
    SDELT[o] = sdel;
#pragma unroll
    for (int n = 0; n < NS_; ++n) HFIN[o * NS_ + n] = h[n];
}

// Phase B: thread = (dir,b,d,n); 16-step serial combine across chunks.
__global__ __launch_bounds__(256) void scan_combine_k(
        const float* __restrict__ HFIN,
        const float* __restrict__ SDELT,
        const float* __restrict__ Alog,
        const float* __restrict__ Ablog,
        float* __restrict__ HINIT) {
    int gid = blockIdx.x * 256 + threadIdx.x;
    int n = gid & 15;
    int d = (gid >> 4) % DI_;
    int b = (gid / (16 * DI_)) % B_;
    int dir = gid / (16 * DI_ * B_);
    const float* alog = dir ? Ablog : Alog;
    float Av = -__expf(alog[d * NS_ + n]);
    float hi = 0.0f;
#pragma unroll
    for (int c = 0; c < NC_; ++c) {
        size_t o = ((size_t)(dir * B_ + b) * NC_ + c) * DI_ + d;
        HINIT[o * NS_ + n] = hi;
        hi = __expf(Av * SDELT[o]) * hi + HFIN[o * NS_ + n];
    }
}

// Phase C: replay chunk with h_init; y = sum_n h*C in-register; gate; write.
__global__ __launch_bounds__(256) void scan_final_k(
        const float* __restrict__ DELTA,
        const float* __restrict__ XCONV,
        const float* __restrict__ XDB,
        const float* __restrict__ XZ,
        const float* __restrict__ Alog,
        const float* __restrict__ Ablog,
        const float* __restrict__ dskip,
        const float* __restrict__ HINIT,
        float* __restrict__ YOUT) {
    __shared__ float sB[CL_][NS_];
    __shared__ float sC[CL_][NS_];
    int blk = blockIdx.x;
    int g   = blk % 3;
    int c   = (blk / 3) % NC_;
    int b   = (blk / (3 * NC_)) % B_;
    int dir = blk / (3 * NC_ * B_);
    int t = threadIdx.x;
    int d = g * 256 + t;
    size_t base = (size_t)(dir * B_ + b) * KEEP_ + c * CL_;

    for (int i = t; i < CL_ * NS_; i += 256) {
        int s = i >> 4, n = i & 15;
        sB[s][n] = XDB[(base + s) * XPR_ + DTR_ + n];
        sC[s][n] = XDB[(base + s) * XPR_ + DTR_ + NS_ + n];
    }
    __syncthreads();

    const float* alog = dir ? Ablog : Alog;
    float Av[NS_];
#pragma unroll
    for (int n = 0; n < NS_; ++n) Av[n] = -__expf(alog[d * NS_ + n]);
    float dsk = dskip[d];
    size_t o = ((size_t)(dir * B_ + b) * NC_ + c) * DI_ + d;
    float h[NS_];
#pragma unroll
    for (int n = 0; n < NS_; ++n) h[n] = HINIT[o * NS_ + n];

    float nd = DELTA[base * DI_ + d];
    float nx = XCONV[base * DI_ + d];
    for (int s = 0; s < CL_; ++s) {
        float delta = nd, xv = nx;
        if (s + 1 < CL_) {
            nd = DELTA[(base + s + 1) * DI_ + d];
            nx = XCONV[(base + s + 1) * DI_ + d];
        }
        float dx = delta * xv;
        float y = 0.0f;
#pragma unroll
        for (int n = 0; n < NS_; ++n) {
            h[n] = __expf(delta * Av[n]) * h[n] + dx * sB[s][n];
            y += h[n] * sC[s][n];
        }
        int pos = c * CL_ + s;
        int la = dir ? (KEEP_ - 1 - pos) : pos;
        float z = XZ[((size_t)b * KEEP_ + la) * (2 * DI_) + DI_ + d];
        YOUT[((size_t)(dir * B_ + b) * KEEP_ + la) * DI_ + d] =
            (y + dsk * xv) * silu_f(z);
    }
}

// ---------------------------------------------------------------- launcher
extern "C" void kernel_launch(void* const* d_in, const int* in_sizes, int n_in,
                              void* d_out, int out_size, void* d_ws, size_t ws_size,
                              hipStream_t stream) {
    const float* imgs      = (const float*)d_in[0];
    const float* pos       = (const float*)d_in[1];
    const float* mask_tok  = (const float*)d_in[2];
    const float* n1w       = (const float*)d_in[3];
    const float* n1b       = (const float*)d_in[4];
    const float* inW       = (const float*)d_in[5];
    const float* cw        = (const float*)d_in[6];
    const float* cb        = (const float*)d_in[7];
    const float* xpw       = (const float*)d_in[8];
    const float* dtw       = (const float*)d_in[9];
    const float* dtb       = (const float*)d_in[10];
    const float* Alog      = (const float*)d_in[11];
    const float* Ablog     = (const float*)d_in[12];
    const float* dskip     = (const float*)d_in[13];
    const float* ow        = (const float*)d_in[14];
    const float* n2w       = (const float*)d_in[15];
    const float* n2b       = (const float*)d_in[16];
    const float* f1w       = (const float*)d_in[17];
    const float* f1b       = (const float*)d_in[18];
    const float* f2w       = (const float*)d_in[19];
    const float* f2b       = (const float*)d_in[20];
    const int*   active    = (const int*)d_in[21];
    float* out = (float*)d_out;

    // workspace carve
    char* w = (char*)d_ws;
    auto alloc = [&](size_t bytes) {
        void* p = (void*)w;
        w += (bytes + 255) & ~(size_t)255;
        return p;
    };
    int*   RANK  = (int*)  alloc((size_t)B_ * L_ * 4);
    int*   IDS   = (int*)  alloc((size_t)B_ * KEEP_ * 4);
    float* X     = (float*)alloc((size_t)B_ * KEEP_ * DM_ * 4);
    float* H     = (float*)alloc((size_t)B_ * KEEP_ * DM_ * 4);
    float* XZ    = (float*)alloc((size_t)B_ * KEEP_ * 2 * DI_ * 4);
    float* XCONV = (float*)alloc((size_t)2 * B_ * KEEP_ * DI_ * 4);
    float* XDB   = (float*)alloc((size_t)2 * B_ * KEEP_ * XPR_ * 4);
    float* DELTA = (float*)alloc((size_t)2 * B_ * KEEP_ * DI_ * 4);
    float* YOUT  = (float*)alloc((size_t)2 * B_ * KEEP_ * DI_ * 4);
    float* G     = (float*)alloc((size_t)B_ * KEEP_ * DI_ * 4);
    float* HFIN  = (float*)alloc((size_t)2 * B_ * NC_ * DI_ * NS_ * 4);
    float* HINIT = (float*)alloc((size_t)2 * B_ * NC_ * DI_ * NS_ * 4);
    float* SDELT = (float*)alloc((size_t)2 * B_ * NC_ * DI_ * 4);

    const int ROWS = B_ * KEEP_;       // 1728
    const int ROWS2 = 2 * B_ * KEEP_;  // 3456
    const int SCAN_BLOCKS = 2 * B_ * NC_ * 3;   // 384

    compute_ids_k<<<B_, 256, 0, stream>>>(active, RANK, IDS);
    gather_embed_k<<<(B_ * KEEP_ * DM_ + 255) / 256, 256, 0, stream>>>(imgs, pos, IDS, X);

    for (int layer = 0; layer < DEPTH_; ++layer) {
        const float* L_inW = inW + (size_t)layer * 2 * DI_ * DM_;
        const float* L_cw  = cw  + (size_t)layer * DI_ * DC_;
        const float* L_cb  = cb  + (size_t)layer * DI_;
        const float* L_xpw = xpw + (size_t)layer * XPR_ * DI_;
        const float* L_dtw = dtw + (size_t)layer * DI_ * DTR_;
        const float* L_dtb = dtb + (size_t)layer * DI_;
        const float* L_Al  = Alog  + (size_t)layer * DI_ * NS_;
        const float* L_Abl = Ablog + (size_t)layer * DI_ * NS_;
        const float* L_dsk = dskip + (size_t)layer * DI_;
        const float* L_ow  = ow  + (size_t)layer * DM_ * DI_;
        const float* L_f1w = f1w + (size_t)layer * 2 * DM_ * DM_;
        const float* L_f1b = f1b + (size_t)layer * 2 * DM_;
        const float* L_f2w = f2w + (size_t)layer * DM_ * 2 * DM_;
        const float* L_f2b = f2b + (size_t)layer * DM_;

        // LN1
        layernorm_k<<<(ROWS + 3) / 4, 256, 0, stream>>>(
            X, n1w + layer * DM_, n1b + layer * DM_, H, ROWS);
        // in_proj: (1728 x 384) x (1536 x 384)^T -> XZ (1728 x 1536)
        gemm_k<<<dim3((2 * DI_) / BN_, ROWS / BM_), 256, 0, stream>>>(
            H, nullptr, DM_, L_inW, nullptr, XZ, 2 * DI_, ROWS, 2 * DI_, DM_, 0);
        // conv + silu (both directions)
        conv_silu_k<<<(2 * B_ * KEEP_ * DI_ + 255) / 256, 256, 0, stream>>>(
            XZ, L_cw, L_cb, XCONV);
        // x_proj: (3456 x 768) x (56 x 768)^T -> XDB (3456 x 56)
        gemm_k<<<dim3((XPR_ + BN_ - 1) / BN_, ROWS2 / BM_), 256, 0, stream>>>(
            XCONV, nullptr, DI_, L_xpw, nullptr, XDB, XPR_, ROWS2, XPR_, DI_, 0);
        // dt: (3456 x 24 view of XDB) x (768 x 24)^T + dtb, softplus -> DELTA
        gemm_k<<<dim3(DI_ / BN_, ROWS2 / BM_), 256, 0, stream>>>(
            XDB, nullptr, XPR_, L_dtw, L_dtb, DELTA, DI_, ROWS2, DI_, DTR_, 2);
        // scan: chunked parallel (3 phases)
        scan_partial_k<<<SCAN_BLOCKS, 256, 0, stream>>>(
            DELTA, XCONV, XDB, L_Al, L_Abl, HFIN, SDELT);
        scan_combine_k<<<(2 * B_ * DI_ * NS_) / 256, 256, 0, stream>>>(
            HFIN, SDELT, L_Al, L_Abl, HINIT);
        scan_final_k<<<SCAN_BLOCKS, 256, 0, stream>>>(
            DELTA, XCONV, XDB, XZ, L_Al, L_Abl, L_dsk, HINIT, YOUT);
        // out_proj + residual, A = YOUT_fwd + YOUT_bwd fused at load
        gemm_k<<<dim3(DM_ / BN_, ROWS / BM_), 256, 0, stream>>>(
            YOUT, YOUT + (size_t)B_ * KEEP_ * DI_, DI_, L_ow, nullptr,
            X, DM_, ROWS, DM_, DI_, 4);
        // LN2
        layernorm_k<<<(ROWS + 3) / 4, 256, 0, stream>>>(
            X, n2w + layer * DM_, n2b + layer * DM_, H, ROWS);
        // fc1 + bias + gelu: (1728x384) x (768x384)^T -> G
        gemm_k<<<dim3((2 * DM_) / BN_, ROWS / BM_), 256, 0, stream>>>(
            H, nullptr, DM_, L_f1w, L_f1b, G, 2 * DM_, ROWS, 2 * DM_, DM_, 3);
        // fc2 + bias + residual: X += G (1728x768) x (384x768)^T + f2b
        gemm_k<<<dim3(DM_ / BN_, ROWS / BM_), 256, 0, stream>>>(
            G, nullptr, 2 * DM_, L_f2w, L_f2b, X, DM_, ROWS, DM_, 2 * DM_, 5);
    }

    final_scatter_k<<<(B_ * DM_ * L_ + 255) / 256, 256, 0, stream>>>(
        X, mask_tok, RANK, out);
}

// Round 4
// 1818.714 us; speedup vs baseline: 3.5733x; 2.0610x over previous
//
#include <hip/hip_runtime.h>
#include <hip/hip_bf16.h>
#include <math.h>

#define B_    4
#define GRID_ 12
#define DM_   384
#define DEPTH_ 8
#define L_    1728      // 12^3
#define DI_   768
#define NS_   16
#define DC_   4
#define DTR_  24
#define KEEP_ 432
#define XPR_  56        // DTR + 2*NS
#define NC_   16        // scan chunks
#define CL_   27        // steps per chunk (16*27 = 432)

typedef __attribute__((ext_vector_type(8))) short short8;
typedef __attribute__((ext_vector_type(4))) float floatx4;

// ---------------------------------------------------------------- utilities
__device__ __forceinline__ float silu_f(float x) {
    return x / (1.0f + __expf(-x));
}
__device__ __forceinline__ float softplus_f(float x) {
    return (x > 20.0f) ? x : log1pf(expf(x));
}
__device__ __forceinline__ float gelu_exact_f(float x) {
    return 0.5f * x * (1.0f + erff(x * 0.7071067811865476f));
}
__device__ __forceinline__ unsigned short f2bf(float x) {
    union { float f; unsigned int u; } c; c.f = x;
    unsigned int u = c.u;
    unsigned int r = (u + 0x7fffu + ((u >> 16) & 1u)) >> 16;
    return (unsigned short)r;
}

// ---------------------------------------------------------------- weight cast
// All six weight tensors fp32 -> bf16 into workspace (runs every call).
#define S0_ (DEPTH_ * 2 * DI_ * DM_)   // inW  4718592
#define S1_ (DEPTH_ * XPR_ * DI_)      // xpw   344064
#define S2_ (DEPTH_ * DI_ * DTR_)      // dtw   147456
#define S3_ (DEPTH_ * DM_ * DI_)       // ow   2359296
#define S4_ (DEPTH_ * 2 * DM_ * DM_)   // f1w  2359296
#define S5_ (DEPTH_ * DM_ * 2 * DM_)   // f2w  2359296
#define WTOT_ (S0_ + S1_ + S2_ + S3_ + S4_ + S5_)

__global__ void cast_weights_k(const float* __restrict__ w0,
                               const float* __restrict__ w1,
                               const float* __restrict__ w2,
                               const float* __restrict__ w3,
                               const float* __restrict__ w4,
                               const float* __restrict__ w5,
                               unsigned short* __restrict__ out) {
    int i = blockIdx.x * 256 + threadIdx.x;
    if (i >= WTOT_) return;
    float v;
    if (i < S0_) v = w0[i];
    else if (i < S0_ + S1_) v = w1[i - S0_];
    else if (i < S0_ + S1_ + S2_) v = w2[i - S0_ - S1_];
    else if (i < S0_ + S1_ + S2_ + S3_) v = w3[i - S0_ - S1_ - S2_];
    else if (i < S0_ + S1_ + S2_ + S3_ + S4_) v = w4[i - S0_ - S1_ - S2_ - S3_];
    else v = w5[i - S0_ - S1_ - S2_ - S3_ - S4_];
    out[i] = f2bf(v);
}

// ---------------------------------------------------------------- ids / rank
__global__ __launch_bounds__(256) void compute_ids_k(
        const int* __restrict__ active,
        int* __restrict__ RANK, int* __restrict__ IDS) {
    __shared__ int cnt[256];
    int b = blockIdx.x;
    int t = threadIdx.x;
    const int PER = (L_ + 255) / 256;   // 7
    int base = t * PER;
    int c = 0;
    for (int j = 0; j < PER; ++j) {
        int l = base + j;
        if (l < L_ && active[b * L_ + l]) ++c;
    }
    cnt[t] = c;
    __syncthreads();
    for (int off = 1; off < 256; off <<= 1) {
        int v = (t >= off) ? cnt[t - off] : 0;
        __syncthreads();
        cnt[t] += v;
        __syncthreads();
    }
    int r = cnt[t] - c;   // exclusive prefix
    for (int j = 0; j < PER; ++j) {
        int l = base + j;
        if (l >= L_) break;
        if (active[b * L_ + l]) {
            RANK[b * L_ + l] = r;
            IDS[b * KEEP_ + r] = l;
            ++r;
        } else {
            RANK[b * L_ + l] = -1;
        }
    }
}

// X[b,i,c] = imgs[b,c,ids[b,i]] + pos[ids[b,i], c]
__global__ void gather_embed_k(const float* __restrict__ imgs,
                               const float* __restrict__ pos,
                               const int* __restrict__ IDS,
                               float* __restrict__ X) {
    int tid = blockIdx.x * 256 + threadIdx.x;
    if (tid >= B_ * KEEP_ * DM_) return;
    int c = tid % DM_;
    int i = (tid / DM_) % KEEP_;
    int b = tid / (DM_ * KEEP_);
    int l = IDS[b * KEEP_ + i];
    X[tid] = imgs[((size_t)b * DM_ + c) * L_ + l] + pos[(size_t)l * DM_ + c];
}

// out[b,c,l] = active ? X[b, rank, c] : mask_token[c]
__global__ void final_scatter_k(const float* __restrict__ X,
                                const float* __restrict__ mask_token,
                                const int* __restrict__ RANK,
                                float* __restrict__ out) {
    int tid = blockIdx.x * 256 + threadIdx.x;
    if (tid >= B_ * DM_ * L_) return;
    int l = tid % L_;
    int c = (tid / L_) % DM_;
    int b = tid / (L_ * DM_);
    int r = RANK[b * L_ + l];
    out[tid] = (r >= 0) ? X[((size_t)b * KEEP_ + r) * DM_ + c] : mask_token[c];
}

// ---------------------------------------------------------------- layernorm
__global__ void layernorm_k(const float* __restrict__ X,
                            const float* __restrict__ w,
                            const float* __restrict__ bia,
                            float* __restrict__ H, int rows) {
    int row = blockIdx.x * 4 + (threadIdx.x >> 6);
    int lane = threadIdx.x & 63;
    if (row >= rows) return;
    const float* x = X + (size_t)row * DM_;
    float v[6];
    float s = 0.0f;
#pragma unroll
    for (int j = 0; j < 6; ++j) { v[j] = x[lane + 64 * j]; s += v[j]; }
#pragma unroll
    for (int m = 1; m < 64; m <<= 1) s += __shfl_xor(s, m);
    float mu = s * (1.0f / DM_);
    float s2 = 0.0f;
#pragma unroll
    for (int j = 0; j < 6; ++j) { float d = v[j] - mu; s2 += d * d; }
#pragma unroll
    for (int m = 1; m < 64; m <<= 1) s2 += __shfl_xor(s2, m);
    float rs = rsqrtf(s2 * (1.0f / DM_) + 1e-5f);
    float* h = H + (size_t)row * DM_;
#pragma unroll
    for (int j = 0; j < 6; ++j) {
        int c = lane + 64 * j;
        h[c] = (v[j] - mu) * rs * w[c] + bia[c];
    }
}

// ---------------------------------------------------------------- MFMA GEMM
// C[m,n] = sum_k (A[m,k] (+ A2[m,k])) * W[n,k]
// A fp32 (rounded to bf16 at staging), W pre-cast bf16 [N][K] row-major.
// Tile 64x64, BK=32, 4 waves; wave w computes rows [w*16,w*16+16) x 64 cols.
// mfma_f32_16x16x32_bf16: A-frag lane holds A[m=lane&15][k=quad*8+j];
// identical load from the N x K weight tile gives the B operand; C/D:
// col=lane&15, row=quad*4+reg  [verified m89/m91].
// modes: 0 none, 2 bias+softplus, 3 bias+gelu, 4 residual, 5 bias+residual
__global__ __launch_bounds__(256) void gemm_mfma_k(
    const float* __restrict__ A, const float* __restrict__ A2, int lda,
    const unsigned short* __restrict__ Wb,
    const float* __restrict__ bias,
    float* __restrict__ C, int ldc,
    int M, int N, int K, int mode) {
    __shared__ unsigned short As[64][32];   // 4 KB
    __shared__ unsigned short Bs[64][32];   // 4 KB
    int t = threadIdx.x;
    int wave = t >> 6;
    int lane = t & 63;
    int q = lane >> 4;
    int ml = lane & 15;
    int m0 = blockIdx.y * 64;
    int n0 = blockIdx.x * 64;

    int srow = t >> 2;          // staging row 0..63
    int scol = (t & 3) * 8;     // staging col 0,8,16,24

    floatx4 acc[4];
#pragma unroll
    for (int i = 0; i < 4; ++i) acc[i] = (floatx4){0.f, 0.f, 0.f, 0.f};

    const bool nfull = (N - n0) >= 64;

    for (int k0 = 0; k0 < K; k0 += 32) {
        // ---- stage A (fp32 -> bf16)
        if (K - k0 >= 32) {
            const floatx4* ap =
                (const floatx4*)(A + (size_t)(m0 + srow) * lda + k0 + scol);
            floatx4 v0 = ap[0], v1 = ap[1];
            if (A2) {
                const floatx4* ap2 =
                    (const floatx4*)(A2 + (size_t)(m0 + srow) * lda + k0 + scol);
                floatx4 w0 = ap2[0], w1 = ap2[1];
                v0 += w0; v1 += w1;
            }
#pragma unroll
            for (int j = 0; j < 4; ++j) As[srow][scol + j] = f2bf(v0[j]);
#pragma unroll
            for (int j = 0; j < 4; ++j) As[srow][scol + 4 + j] = f2bf(v1[j]);
        } else {
#pragma unroll
            for (int j = 0; j < 8; ++j) {
                int kk = k0 + scol + j;
                float v = 0.0f;
                if (kk < K) {
                    size_t ai = (size_t)(m0 + srow) * lda + kk;
                    v = A[ai];
                    if (A2) v += A2[ai];
                }
                As[srow][scol + j] = f2bf(v);
            }
        }
        // ---- stage B (bf16 weights)
        if (nfull && (K - k0 >= 32)) {
            const uint4* bp =
                (const uint4*)(Wb + (size_t)(n0 + srow) * K + k0 + scol);
            *(uint4*)&Bs[srow][scol] = bp[0];
        } else {
#pragma unroll
            for (int j = 0; j < 8; ++j) {
                int kk = k0 + scol + j;
                unsigned short v = 0;
                if ((n0 + srow) < N && kk < K)
                    v = Wb[(size_t)(n0 + srow) * K + kk];
                Bs[srow][scol + j] = v;
            }
        }
        __syncthreads();
        short8 a = *(const short8*)&As[wave * 16 + ml][q * 8];
#pragma unroll
        for (int ns = 0; ns < 4; ++ns) {
            short8 b = *(const short8*)&Bs[ns * 16 + ml][q * 8];
            acc[ns] = __builtin_amdgcn_mfma_f32_16x16x32_bf16(a, b, acc[ns], 0, 0, 0);
        }
        __syncthreads();
    }

    // ---- epilogue
#pragma unroll
    for (int ns = 0; ns < 4; ++ns) {
        int n = n0 + ns * 16 + ml;
        if (n >= N) continue;
#pragma unroll
        for (int r = 0; r < 4; ++r) {
            int m = m0 + wave * 16 + q * 4 + r;
            float v = acc[ns][r];
            size_t ci = (size_t)m * ldc + n;
            if (mode == 2) {
                v = softplus_f(v + bias[n]);
            } else if (mode == 3) {
                v = gelu_exact_f(v + bias[n]);
            } else if (mode == 4) {
                v += C[ci];
            } else if (mode == 5) {
                v += C[ci] + bias[n];
            }
            C[ci] = v;
        }
    }
}

// ---------------------------------------------------------------- conv+silu
__global__ void conv_silu_k(const float* __restrict__ XZ,
                            const float* __restrict__ cw,
                            const float* __restrict__ cb,
                            float* __restrict__ XCONV) {
    int tid = blockIdx.x * 256 + threadIdx.x;
    if (tid >= 2 * B_ * KEEP_ * DI_) return;
    int d = tid % DI_;
    int s = (tid / DI_) % KEEP_;
    int b = (tid / (DI_ * KEEP_)) % B_;
    int dir = tid / (DI_ * KEEP_ * B_);
    float v = cb[d];
#pragma unroll
    for (int k = 0; k < DC_; ++k) {
        int j = s - (DC_ - 1) + k;
        if (j >= 0) {
            int la = dir ? (KEEP_ - 1 - j) : j;
            v += cw[d * DC_ + k] * XZ[((size_t)b * KEEP_ + la) * (2 * DI_) + d];
        }
    }
    XCONV[tid] = silu_f(v);
}

// ---------------------------------------------------------------- SSM scan
// Chunked parallel scan (3 phases), h[16] in registers, no cross-lane ops.

// Phase A: thread = (dir,b,d,chunk).
__global__ __launch_bounds__(256) void scan_partial_k(
        const float* __restrict__ DELTA,
        const float* __restrict__ XCONV,
        const float* __restrict__ XDB,
        const float* __restrict__ Alog,
        const float* __restrict__ Ablog,
        float* __restrict__ HFIN,
        float* __restrict__ SDELT) {
    __shared__ float sB[CL_][NS_];
    int blk = blockIdx.x;
    int g   = blk % 3;
    int c   = (blk / 3) % NC_;
    int b   = (blk / (3 * NC_)) % B_;
    int dir = blk / (3 * NC_ * B_);
    int t = threadIdx.x;
    int d = g * 256 + t;
    size_t base = (size_t)(dir * B_ + b) * KEEP_ + c * CL_;

    for (int i = t; i < CL_ * NS_; i += 256) {
        int s = i >> 4, n = i & 15;
        sB[s][n] = XDB[(base + s) * XPR_ + DTR_ + n];
    }
    __syncthreads();

    const float* alog = dir ? Ablog : Alog;
    float Av[NS_];
#pragma unroll
    for (int n = 0; n < NS_; ++n) Av[n] = -__expf(alog[d * NS_ + n]);
    float h[NS_];
#pragma unroll
    for (int n = 0; n < NS_; ++n) h[n] = 0.0f;
    float sdel = 0.0f;

    float nd = DELTA[base * DI_ + d];
    float nx = XCONV[base * DI_ + d];
    for (int s = 0; s < CL_; ++s) {
        float delta = nd, xv = nx;
        if (s + 1 < CL_) {
            nd = DELTA[(base + s + 1) * DI_ + d];
            nx = XCONV[(base + s + 1) * DI_ + d];
        }
        sdel += delta;
        float dx = delta * xv;
#pragma unroll
        for (int n = 0; n < NS_; ++n)
            h[n] = __expf(delta * Av[n]) * h[n] + dx * sB[s][n];
    }
    size_t o = ((size_t)(dir * B_ + b) * NC_ + c) * DI_ + d;
    SDELT[o] = sdel;
#pragma unroll
    for (int n = 0; n < NS_; ++n) HFIN[o * NS_ + n] = h[n];
}

// Phase B: thread = (dir,b,d,n); serial combine across chunks.
__global__ __launch_bounds__(256) void scan_combine_k(
        const float* __restrict__ HFIN,
        const float* __restrict__ SDELT,
        const float* __restrict__ Alog,
        const float* __restrict__ Ablog,
        float* __restrict__ HINIT) {
    int gid = blockIdx.x * 256 + threadIdx.x;
    int n = gid & 15;
    int d = (gid >> 4) % DI_;
    int b = (gid / (16 * DI_)) % B_;
    int dir = gid / (16 * DI_ * B_);
    const float* alog = dir ? Ablog : Alog;
    float Av = -__expf(alog[d * NS_ + n]);
    float hi = 0.0f;
#pragma unroll
    for (int c = 0; c < NC_; ++c) {
        size_t o = ((size_t)(dir * B_ + b) * NC_ + c) * DI_ + d;
        HINIT[o * NS_ + n] = hi;
        hi = __expf(Av * SDELT[o]) * hi + HFIN[o * NS_ + n];
    }
}

// Phase C: replay chunk with h_init; y = sum_n h*C in-register; gate; write.
__global__ __launch_bounds__(256) void scan_final_k(
        const float* __restrict__ DELTA,
        const float* __restrict__ XCONV,
        const float* __restrict__ XDB,
        const float* __restrict__ XZ,
        const float* __restrict__ Alog,
        const float* __restrict__ Ablog,
        const float* __restrict__ dskip,
        const float* __restrict__ HINIT,
        float* __restrict__ YOUT) {
    __shared__ float sB[CL_][NS_];
    __shared__ float sC[CL_][NS_];
    int blk = blockIdx.x;
    int g   = blk % 3;
    int c   = (blk / 3) % NC_;
    int b   = (blk / (3 * NC_)) % B_;
    int dir = blk / (3 * NC_ * B_);
    int t = threadIdx.x;
    int d = g * 256 + t;
    size_t base = (size_t)(dir * B_ + b) * KEEP_ + c * CL_;

    for (int i = t; i < CL_ * NS_; i += 256) {
        int s = i >> 4, n = i & 15;
        sB[s][n] = XDB[(base + s) * XPR_ + DTR_ + n];
        sC[s][n] = XDB[(base + s) * XPR_ + DTR_ + NS_ + n];
    }
    __syncthreads();

    const float* alog = dir ? Ablog : Alog;
    float Av[NS_];
#pragma unroll
    for (int n = 0; n < NS_; ++n) Av[n] = -__expf(alog[d * NS_ + n]);
    float dsk = dskip[d];
    size_t o = ((size_t)(dir * B_ + b) * NC_ + c) * DI_ + d;
    float h[NS_];
#pragma unroll
    for (int n = 0; n < NS_; ++n) h[n] = HINIT[o * NS_ + n];

    float nd = DELTA[base * DI_ + d];
    float nx = XCONV[base * DI_ + d];
    for (int s = 0; s < CL_; ++s) {
        float delta = nd, xv = nx;
        if (s + 1 < CL_) {
            nd = DELTA[(base + s + 1) * DI_ + d];
            nx = XCONV[(base + s + 1) * DI_ + d];
        }
        float dx = delta * xv;
        float y = 0.0f;
#pragma unroll
        for (int n = 0; n < NS_; ++n) {
            h[n] = __expf(delta * Av[n]) * h[n] + dx * sB[s][n];
            y += h[n] * sC[s][n];
        }
        int pos = c * CL_ + s;
        int la = dir ? (KEEP_ - 1 - pos) : pos;
        float z = XZ[((size_t)b * KEEP_ + la) * (2 * DI_) + DI_ + d];
        YOUT[((size_t)(dir * B_ + b) * KEEP_ + la) * DI_ + d] =
            (y + dsk * xv) * silu_f(z);
    }
}

// ---------------------------------------------------------------- launcher
extern "C" void kernel_launch(void* const* d_in, const int* in_sizes, int n_in,
                              void* d_out, int out_size, void* d_ws, size_t ws_size,
                              hipStream_t stream) {
    const float* imgs      = (const float*)d_in[0];
    const float* pos       = (const float*)d_in[1];
    const float* mask_tok  = (const float*)d_in[2];
    const float* n1w       = (const float*)d_in[3];
    const float* n1b       = (const float*)d_in[4];
    const float* inW       = (const float*)d_in[5];
    const float* cw        = (const float*)d_in[6];
    const float* cb        = (const float*)d_in[7];
    const float* xpw       = (const float*)d_in[8];
    const float* dtw       = (const float*)d_in[9];
    const float* dtb       = (const float*)d_in[10];
    const float* Alog      = (const float*)d_in[11];
    const float* Ablog     = (const float*)d_in[12];
    const float* dskip     = (const float*)d_in[13];
    const float* ow        = (const float*)d_in[14];
    const float* n2w       = (const float*)d_in[15];
    const float* n2b       = (const float*)d_in[16];
    const float* f1w       = (const float*)d_in[17];
    const float* f1b       = (const float*)d_in[18];
    const float* f2w       = (const float*)d_in[19];
    const float* f2b       = (const float*)d_in[20];
    const int*   active    = (const int*)d_in[21];
    float* out = (float*)d_out;

    // workspace carve
    char* w = (char*)d_ws;
    auto alloc = [&](size_t bytes) {
        void* p = (void*)w;
        w += (bytes + 255) & ~(size_t)255;
        return p;
    };
    int*   RANK  = (int*)  alloc((size_t)B_ * L_ * 4);
    int*   IDS   = (int*)  alloc((size_t)B_ * KEEP_ * 4);
    float* X     = (float*)alloc((size_t)B_ * KEEP_ * DM_ * 4);
    float* H     = (float*)alloc((size_t)B_ * KEEP_ * DM_ * 4);
    float* XZ    = (float*)alloc((size_t)B_ * KEEP_ * 2 * DI_ * 4);
    float* XCONV = (float*)alloc((size_t)2 * B_ * KEEP_ * DI_ * 4);
    float* XDB   = (float*)alloc((size_t)2 * B_ * KEEP_ * XPR_ * 4);
    float* DELTA = (float*)alloc((size_t)2 * B_ * KEEP_ * DI_ * 4);
    float* YOUT  = (float*)alloc((size_t)2 * B_ * KEEP_ * DI_ * 4);
    float* G     = (float*)alloc((size_t)B_ * KEEP_ * DI_ * 4);
    float* HFIN  = (float*)alloc((size_t)2 * B_ * NC_ * DI_ * NS_ * 4);
    float* HINIT = (float*)alloc((size_t)2 * B_ * NC_ * DI_ * NS_ * 4);
    float* SDELT = (float*)alloc((size_t)2 * B_ * NC_ * DI_ * 4);
    unsigned short* WB = (unsigned short*)alloc((size_t)WTOT_ * 2);

    const unsigned short* wInB = WB;
    const unsigned short* wXpB = WB + S0_;
    const unsigned short* wDtB = WB + S0_ + S1_;
    const unsigned short* wOwB = WB + S0_ + S1_ + S2_;
    const unsigned short* wF1B = WB + S0_ + S1_ + S2_ + S3_;
    const unsigned short* wF2B = WB + S0_ + S1_ + S2_ + S3_ + S4_;

    const int ROWS = B_ * KEEP_;       // 1728
    const int ROWS2 = 2 * B_ * KEEP_;  // 3456
    const int SCAN_BLOCKS = 2 * B_ * NC_ * 3;   // 384

    cast_weights_k<<<(WTOT_ + 255) / 256, 256, 0, stream>>>(
        inW, xpw, dtw, ow, f1w, f2w, (unsigned short*)WB);
    compute_ids_k<<<B_, 256, 0, stream>>>(active, RANK, IDS);
    gather_embed_k<<<(B_ * KEEP_ * DM_ + 255) / 256, 256, 0, stream>>>(imgs, pos, IDS, X);

    for (int layer = 0; layer < DEPTH_; ++layer) {
        const unsigned short* L_inW = wInB + (size_t)layer * 2 * DI_ * DM_;
        const float* L_cw  = cw  + (size_t)layer * DI_ * DC_;
        const float* L_cb  = cb  + (size_t)layer * DI_;
        const unsigned short* L_xpw = wXpB + (size_t)layer * XPR_ * DI_;
        const unsigned short* L_dtw = wDtB + (size_t)layer * DI_ * DTR_;
        const float* L_dtb = dtb + (size_t)layer * DI_;
        const float* L_Al  = Alog  + (size_t)layer * DI_ * NS_;
        const float* L_Abl = Ablog + (size_t)layer * DI_ * NS_;
        const float* L_dsk = dskip + (size_t)layer * DI_;
        const unsigned short* L_ow  = wOwB + (size_t)layer * DM_ * DI_;
        const unsigned short* L_f1w = wF1B + (size_t)layer * 2 * DM_ * DM_;
        const float* L_f1b = f1b + (size_t)layer * 2 * DM_;
        const unsigned short* L_f2w = wF2B + (size_t)layer * DM_ * 2 * DM_;
        const float* L_f2b = f2b + (size_t)layer * DM_;

        // LN1
        layernorm_k<<<(ROWS + 3) / 4, 256, 0, stream>>>(
            X, n1w + layer * DM_, n1b + layer * DM_, H, ROWS);
        // in_proj: (1728 x 384) x (1536 x 384)^T -> XZ
        gemm_mfma_k<<<dim3((2 * DI_) / 64, ROWS / 64), 256, 0, stream>>>(
            H, nullptr, DM_, L_inW, nullptr, XZ, 2 * DI_, ROWS, 2 * DI_, DM_, 0);
        // conv + silu (both directions)
        conv_silu_k<<<(2 * B_ * KEEP_ * DI_ + 255) / 256, 256, 0, stream>>>(
            XZ, L_cw, L_cb, XCONV);
        // x_proj: (3456 x 768) x (56 x 768)^T -> XDB
        gemm_mfma_k<<<dim3((XPR_ + 63) / 64, ROWS2 / 64), 256, 0, stream>>>(
            XCONV, nullptr, DI_, L_xpw, nullptr, XDB, XPR_, ROWS2, XPR_, DI_, 0);
        // dt: (3456 x 24 view of XDB) x (768 x 24)^T + dtb, softplus -> DELTA
        gemm_mfma_k<<<dim3(DI_ / 64, ROWS2 / 64), 256, 0, stream>>>(
            XDB, nullptr, XPR_, L_dtw, L_dtb, DELTA, DI_, ROWS2, DI_, DTR_, 2);
        // scan: chunked parallel (3 phases)
        scan_partial_k<<<SCAN_BLOCKS, 256, 0, stream>>>(
            DELTA, XCONV, XDB, L_Al, L_Abl, HFIN, SDELT);
        scan_combine_k<<<(2 * B_ * DI_ * NS_) / 256, 256, 0, stream>>>(
            HFIN, SDELT, L_Al, L_Abl, HINIT);
        scan_final_k<<<SCAN_BLOCKS, 256, 0, stream>>>(
            DELTA, XCONV, XDB, XZ, L_Al, L_Abl, L_dsk, HINIT, YOUT);
        // out_proj + residual, A = YOUT_fwd + YOUT_bwd fused at load
        gemm_mfma_k<<<dim3(DM_ / 64, ROWS / 64), 256, 0, stream>>>(
            YOUT, YOUT + (size_t)B_ * KEEP_ * DI_, DI_, L_ow, nullptr,
            X, DM_, ROWS, DM_, DI_, 4);
        // LN2
        layernorm_k<<<(ROWS + 3) / 4, 256, 0, stream>>>(
            X, n2w + layer * DM_, n2b + layer * DM_, H, ROWS);
        // fc1 + bias + gelu
        gemm_mfma_k<<<dim3((2 * DM_) / 64, ROWS / 64), 256, 0, stream>>>(
            H, nullptr, DM_, L_f1w, L_f1b, G, 2 * DM_, ROWS, 2 * DM_, DM_, 3);
        // fc2 + bias + residual
        gemm_mfma_k<<<dim3(DM_ / 64, ROWS / 64), 256, 0, stream>>>(
            G, nullptr, 2 * DM_, L_f2w, L_f2b, X, DM_, ROWS, DM_, 2 * DM_, 5);
    }

    final_scatter_k<<<(B_ * DM_ * L_ + 255) / 256, 256, 0, stream>>>(
        X, mask_tok, RANK, out);
}

// Round 5
// 1521.621 us; speedup vs baseline: 4.2709x; 1.1952x over previous
//
#include <hip/hip_runtime.h>
#include <hip/hip_bf16.h>
#include <math.h>

#define B_    4
#define GRID_ 12
#define DM_   384
#define DEPTH_ 8
#define L_    1728      // 12^3
#define DI_   768
#define NS_   16
#define DC_   4
#define DTR_  24
#define KEEP_ 432
#define XPR_  56        // DTR + 2*NS
#define NC_   16        // scan chunks
#define CL_   27        // steps per chunk (16*27 = 432)
#define XSPLIT_ 4       // x_proj split-K slabs

typedef __attribute__((ext_vector_type(8))) short short8;
typedef __attribute__((ext_vector_type(4))) float floatx4;

// ---------------------------------------------------------------- utilities
__device__ __forceinline__ float silu_f(float x) {
    return x / (1.0f + __expf(-x));
}
__device__ __forceinline__ float softplus_f(float x) {
    return (x > 20.0f) ? x : log1pf(expf(x));
}
__device__ __forceinline__ float gelu_exact_f(float x) {
    return 0.5f * x * (1.0f + erff(x * 0.7071067811865476f));
}
__device__ __forceinline__ unsigned short f2bf(float x) {
    union { float f; unsigned int u; } c; c.f = x;
    unsigned int u = c.u;
    unsigned int r = (u + 0x7fffu + ((u >> 16) & 1u)) >> 16;
    return (unsigned short)r;
}

// ---------------------------------------------------------------- weight cast
#define S0_ (DEPTH_ * 2 * DI_ * DM_)   // inW  4718592
#define S1_ (DEPTH_ * XPR_ * DI_)      // xpw   344064
#define S2_ (DEPTH_ * DI_ * DTR_)      // dtw   147456
#define S3_ (DEPTH_ * DM_ * DI_)       // ow   2359296
#define S4_ (DEPTH_ * 2 * DM_ * DM_)   // f1w  2359296
#define S5_ (DEPTH_ * DM_ * 2 * DM_)   // f2w  2359296
#define WTOT_ (S0_ + S1_ + S2_ + S3_ + S4_ + S5_)

__global__ void cast_weights_k(const float* __restrict__ w0,
                               const float* __restrict__ w1,
                               const float* __restrict__ w2,
                               const float* __restrict__ w3,
                               const float* __restrict__ w4,
                               const float* __restrict__ w5,
                               unsigned short* __restrict__ out) {
    int i = blockIdx.x * 256 + threadIdx.x;
    if (i >= WTOT_) return;
    float v;
    if (i < S0_) v = w0[i];
    else if (i < S0_ + S1_) v = w1[i - S0_];
    else if (i < S0_ + S1_ + S2_) v = w2[i - S0_ - S1_];
    else if (i < S0_ + S1_ + S2_ + S3_) v = w3[i - S0_ - S1_ - S2_];
    else if (i < S0_ + S1_ + S2_ + S3_ + S4_) v = w4[i - S0_ - S1_ - S2_ - S3_];
    else v = w5[i - S0_ - S1_ - S2_ - S3_ - S4_];
    out[i] = f2bf(v);
}

// ---------------------------------------------------------------- ids / rank
__global__ __launch_bounds__(256) void compute_ids_k(
        const int* __restrict__ active,
        int* __restrict__ RANK, int* __restrict__ IDS) {
    __shared__ int cnt[256];
    int b = blockIdx.x;
    int t = threadIdx.x;
    const int PER = (L_ + 255) / 256;   // 7
    int base = t * PER;
    int c = 0;
    for (int j = 0; j < PER; ++j) {
        int l = base + j;
        if (l < L_ && active[b * L_ + l]) ++c;
    }
    cnt[t] = c;
    __syncthreads();
    for (int off = 1; off < 256; off <<= 1) {
        int v = (t >= off) ? cnt[t - off] : 0;
        __syncthreads();
        cnt[t] += v;
        __syncthreads();
    }
    int r = cnt[t] - c;   // exclusive prefix
    for (int j = 0; j < PER; ++j) {
        int l = base + j;
        if (l >= L_) break;
        if (active[b * L_ + l]) {
            RANK[b * L_ + l] = r;
            IDS[b * KEEP_ + r] = l;
            ++r;
        } else {
            RANK[b * L_ + l] = -1;
        }
    }
}

// X[b,i,c] = imgs[b,c,ids[b,i]] + pos[ids[b,i], c]
__global__ void gather_embed_k(const float* __restrict__ imgs,
                               const float* __restrict__ pos,
                               const int* __restrict__ IDS,
                               float* __restrict__ X) {
    int tid = blockIdx.x * 256 + threadIdx.x;
    if (tid >= B_ * KEEP_ * DM_) return;
    int c = tid % DM_;
    int i = (tid / DM_) % KEEP_;
    int b = tid / (DM_ * KEEP_);
    int l = IDS[b * KEEP_ + i];
    X[tid] = imgs[((size_t)b * DM_ + c) * L_ + l] + pos[(size_t)l * DM_ + c];
}

// out[b,c,l] = active ? X[b, rank, c] : mask_token[c]
__global__ void final_scatter_k(const float* __restrict__ X,
                                const float* __restrict__ mask_token,
                                const int* __restrict__ RANK,
                                float* __restrict__ out) {
    int tid = blockIdx.x * 256 + threadIdx.x;
    if (tid >= B_ * DM_ * L_) return;
    int l = tid % L_;
    int c = (tid / L_) % DM_;
    int b = tid / (L_ * DM_);
    int r = RANK[b * L_ + l];
    out[tid] = (r >= 0) ? X[((size_t)b * KEEP_ + r) * DM_ + c] : mask_token[c];
}

// ---------------------------------------------------------------- layernorm
__global__ void layernorm_k(const float* __restrict__ X,
                            const float* __restrict__ w,
                            const float* __restrict__ bia,
                            float* __restrict__ H, int rows) {
    int row = blockIdx.x * 4 + (threadIdx.x >> 6);
    int lane = threadIdx.x & 63;
    if (row >= rows) return;
    const float* x = X + (size_t)row * DM_;
    float v[6];
    float s = 0.0f;
#pragma unroll
    for (int j = 0; j < 6; ++j) { v[j] = x[lane + 64 * j]; s += v[j]; }
#pragma unroll
    for (int m = 1; m < 64; m <<= 1) s += __shfl_xor(s, m);
    float mu = s * (1.0f / DM_);
    float s2 = 0.0f;
#pragma unroll
    for (int j = 0; j < 6; ++j) { float d = v[j] - mu; s2 += d * d; }
#pragma unroll
    for (int m = 1; m < 64; m <<= 1) s2 += __shfl_xor(s2, m);
    float rs = rsqrtf(s2 * (1.0f / DM_) + 1e-5f);
    float* h = H + (size_t)row * DM_;
#pragma unroll
    for (int j = 0; j < 6; ++j) {
        int c = lane + 64 * j;
        h[c] = (v[j] - mu) * rs * w[c] + bia[c];
    }
}

// ---------------------------------------------------------------- MFMA GEMM
// C[m,n] = sum_k (sum_slab A[m,k,slab] (+ A2[m,k])) * W[n,k]
// Double-buffered LDS + register prefetch; optional split-K over blockIdx.z.
// modes: 0 write, 2 bias+softplus, 3 bias+gelu, 4 residual RMW,
//        5 bias+residual RMW, 6 atomicAdd (split-K residual),
//        7 atomicAdd + bias on z==0 (split-K bias+residual),
//        8 slab write: C + z*M*ldc
__global__ __launch_bounds__(256) void gemm_mfma_k(
    const float* __restrict__ A, const float* __restrict__ A2, int lda,
    int aslabs, size_t aslabstride,
    const unsigned short* __restrict__ Wb,
    const float* __restrict__ bias,
    float* __restrict__ C, int ldc,
    int M, int N, int K, int kslices, int mode) {
    __shared__ unsigned short As[2][64][32];   // 8 KB
    __shared__ unsigned short Bs[2][64][32];   // 8 KB
    int t = threadIdx.x;
    int wave = t >> 6;
    int lane = t & 63;
    int q = lane >> 4;
    int ml = lane & 15;
    int m0 = blockIdx.y * 64;
    int n0 = blockIdx.x * 64;
    int z  = blockIdx.z;
    int Kper = K / kslices;            // kslices>1 only when divisible
    int kbeg = z * Kper;
    int kend = kbeg + Kper;
    if (mode == 8) C += (size_t)z * M * ldc;

    int srow = t >> 2;          // staging row 0..63
    int scol = (t & 3) * 8;     // staging col 0,8,16,24

    const bool nfull = (N - n0) >= 64;

    floatx4 acc[4];
#pragma unroll
    for (int i = 0; i < 4; ++i) acc[i] = (floatx4){0.f, 0.f, 0.f, 0.f};

    float ra[8];
    uint4 rb;

    auto loadA = [&](int k0) {
        if (k0 + 32 <= kend) {
            const float* ap = A + (size_t)(m0 + srow) * lda + k0 + scol;
            floatx4 v0 = *(const floatx4*)ap;
            floatx4 v1 = *(const floatx4*)(ap + 4);
            for (int sl = 1; sl < aslabs; ++sl) {
                const float* ap2 = ap + sl * aslabstride;
                v0 += *(const floatx4*)ap2;
                v1 += *(const floatx4*)(ap2 + 4);
            }
            if (A2) {
                const float* ap2 = A2 + (size_t)(m0 + srow) * lda + k0 + scol;
                v0 += *(const floatx4*)ap2;
                v1 += *(const floatx4*)(ap2 + 4);
            }
#pragma unroll
            for (int j = 0; j < 4; ++j) { ra[j] = v0[j]; ra[4 + j] = v1[j]; }
        } else {
#pragma unroll
            for (int j = 0; j < 8; ++j) {
                int kk = k0 + scol + j;
                float v = 0.0f;
                if (kk < kend) {
                    size_t ai = (size_t)(m0 + srow) * lda + kk;
                    v = A[ai];
                    for (int sl = 1; sl < aslabs; ++sl) v += A[ai + sl * aslabstride];
                    if (A2) v += A2[ai];
                }
                ra[j] = v;
            }
        }
    };
    auto loadB = [&](int k0) {
        if (nfull && (k0 + 32 <= kend)) {
            rb = *(const uint4*)(Wb + (size_t)(n0 + srow) * K + k0 + scol);
        } else {
            unsigned short tmp[8];
#pragma unroll
            for (int j = 0; j < 8; ++j) {
                int kk = k0 + scol + j;
                unsigned short v = 0;
                if ((n0 + srow) < N && kk < kend)
                    v = Wb[(size_t)(n0 + srow) * K + kk];
                tmp[j] = v;
            }
            rb = *(const uint4*)tmp;
        }
    };
    auto storeT = [&](int buf) {
#pragma unroll
        for (int j = 0; j < 8; ++j) As[buf][srow][scol + j] = f2bf(ra[j]);
        *(uint4*)&Bs[buf][srow][scol] = rb;
    };

    int nk = (Kper + 31) >> 5;
    loadA(kbeg);
    loadB(kbeg);
    storeT(0);
    __syncthreads();
    int buf = 0;
    for (int it = 0; it < nk; ++it) {
        if (it + 1 < nk) {
            int kn = kbeg + (it + 1) * 32;
            loadA(kn);
            loadB(kn);
        }
        short8 a = *(const short8*)&As[buf][wave * 16 + ml][q * 8];
#pragma unroll
        for (int ns = 0; ns < 4; ++ns) {
            short8 b = *(const short8*)&Bs[buf][ns * 16 + ml][q * 8];
            acc[ns] = __builtin_amdgcn_mfma_f32_16x16x32_bf16(a, b, acc[ns], 0, 0, 0);
        }
        if (it + 1 < nk) {
            storeT(buf ^ 1);
            __syncthreads();
            buf ^= 1;
        }
    }

    // ---- epilogue
#pragma unroll
    for (int ns = 0; ns < 4; ++ns) {
        int n = n0 + ns * 16 + ml;
        if (n >= N) continue;
#pragma unroll
        for (int r = 0; r < 4; ++r) {
            int m = m0 + wave * 16 + q * 4 + r;
            float v = acc[ns][r];
            size_t ci = (size_t)m * ldc + n;
            if (mode == 2) {
                C[ci] = softplus_f(v + bias[n]);
            } else if (mode == 3) {
                C[ci] = gelu_exact_f(v + bias[n]);
            } else if (mode == 4) {
                C[ci] = v + C[ci];
            } else if (mode == 5) {
                C[ci] = v + C[ci] + bias[n];
            } else if (mode == 6) {
                atomicAdd(&C[ci], v);
            } else if (mode == 7) {
                if (z == 0) v += bias[n];
                atomicAdd(&C[ci], v);
            } else {
                C[ci] = v;
            }
        }
    }
}

// ---------------------------------------------------------------- conv+silu
__global__ void conv_silu_k(const float* __restrict__ XZ,
                            const float* __restrict__ cw,
                            const float* __restrict__ cb,
                            float* __restrict__ XCONV) {
    int tid = blockIdx.x * 256 + threadIdx.x;
    if (tid >= 2 * B_ * KEEP_ * DI_) return;
    int d = tid % DI_;
    int s = (tid / DI_) % KEEP_;
    int b = (tid / (DI_ * KEEP_)) % B_;
    int dir = tid / (DI_ * KEEP_ * B_);
    float v = cb[d];
#pragma unroll
    for (int k = 0; k < DC_; ++k) {
        int j = s - (DC_ - 1) + k;
        if (j >= 0) {
            int la = dir ? (KEEP_ - 1 - j) : j;
            v += cw[d * DC_ + k] * XZ[((size_t)b * KEEP_ + la) * (2 * DI_) + d];
        }
    }
    XCONV[tid] = silu_f(v);
}

// ---------------------------------------------------------------- SSM scan
// Chunked parallel scan (3 phases). x_proj output lives in XSPLIT_ partial
// slabs (PART); staging sums them.
#define PSL_ ((size_t)(2 * B_ * KEEP_) * XPR_)   // slab stride

// Phase A: thread = (dir,b,d,chunk).
__global__ __launch_bounds__(256) void scan_partial_k(
        const float* __restrict__ DELTA,
        const float* __restrict__ XCONV,
        const float* __restrict__ PART,
        const float* __restrict__ Alog,
        const float* __restrict__ Ablog,
        float* __restrict__ HFIN,
        float* __restrict__ SDELT) {
    __shared__ float sB[CL_][NS_];
    int blk = blockIdx.x;
    int g   = blk % 3;
    int c   = (blk / 3) % NC_;
    int b   = (blk / (3 * NC_)) % B_;
    int dir = blk / (3 * NC_ * B_);
    int t = threadIdx.x;
    int d = g * 256 + t;
    size_t base = (size_t)(dir * B_ + b) * KEEP_ + c * CL_;

    for (int i = t; i < CL_ * NS_; i += 256) {
        int s = i >> 4, n = i & 15;
        size_t idx = (base + s) * XPR_ + DTR_ + n;
        float v = PART[idx];
#pragma unroll
        for (int sl = 1; sl < XSPLIT_; ++sl) v += PART[idx + sl * PSL_];
        sB[s][n] = v;
    }
    __syncthreads();

    const float* alog = dir ? Ablog : Alog;
    float Av[NS_];
#pragma unroll
    for (int n = 0; n < NS_; ++n) Av[n] = -__expf(alog[d * NS_ + n]);
    float h[NS_];
#pragma unroll
    for (int n = 0; n < NS_; ++n) h[n] = 0.0f;
    float sdel = 0.0f;

    float nd = DELTA[base * DI_ + d];
    float nx = XCONV[base * DI_ + d];
    for (int s = 0; s < CL_; ++s) {
        float delta = nd, xv = nx;
        if (s + 1 < CL_) {
            nd = DELTA[(base + s + 1) * DI_ + d];
            nx = XCONV[(base + s + 1) * DI_ + d];
        }
        sdel += delta;
        float dx = delta * xv;
#pragma unroll
        for (int n = 0; n < NS_; ++n)
            h[n] = __expf(delta * Av[n]) * h[n] + dx * sB[s][n];
    }
    size_t o = ((size_t)(dir * B_ + b) * NC_ + c) * DI_ + d;
    SDELT[o] = sdel;
#pragma unroll
    for (int n = 0; n < NS_; ++n) HFIN[o * NS_ + n] = h[n];
}

// Phase B: thread = (dir,b,d,n); serial combine across chunks.
__global__ __launch_bounds__(256) void scan_combine_k(
        const float* __restrict__ HFIN,
        const float* __restrict__ SDELT,
        const float* __restrict__ Alog,
        const float* __restrict__ Ablog,
        float* __restrict__ HINIT) {
    int gid = blockIdx.x * 256 + threadIdx.x;
    int n = gid & 15;
    int d = (gid >> 4) % DI_;
    int b = (gid / (16 * DI_)) % B_;
    int dir = gid / (16 * DI_ * B_);
    const float* alog = dir ? Ablog : Alog;
    float Av = -__expf(alog[d * NS_ + n]);
    float hi = 0.0f;
#pragma unroll
    for (int c = 0; c < NC_; ++c) {
        size_t o = ((size_t)(dir * B_ + b) * NC_ + c) * DI_ + d;
        HINIT[o * NS_ + n] = hi;
        hi = __expf(Av * SDELT[o]) * hi + HFIN[o * NS_ + n];
    }
}

// Phase C: replay chunk with h_init; y = sum_n h*C in-register; gate; write.
__global__ __launch_bounds__(256) void scan_final_k(
        const float* __restrict__ DELTA,
        const float* __restrict__ XCONV,
        const float* __restrict__ PART,
        const float* __restrict__ XZ,
        const float* __restrict__ Alog,
        const float* __restrict__ Ablog,
        const float* __restrict__ dskip,
        const float* __restrict__ HINIT,
        float* __restrict__ YOUT) {
    __shared__ float sB[CL_][NS_];
    __shared__ float sC[CL_][NS_];
    int blk = blockIdx.x;
    int g   = blk % 3;
    int c   = (blk / 3) % NC_;
    int b   = (blk / (3 * NC_)) % B_;
    int dir = blk / (3 * NC_ * B_);
    int t = threadIdx.x;
    int d = g * 256 + t;
    size_t base = (size_t)(dir * B_ + b) * KEEP_ + c * CL_;

    for (int i = t; i < CL_ * NS_; i += 256) {
        int s = i >> 4, n = i & 15;
        size_t ib = (base + s) * XPR_ + DTR_ + n;
        size_t ic = ib + NS_;
        float vb = PART[ib], vc = PART[ic];
#pragma unroll
        for (int sl = 1; sl < XSPLIT_; ++sl) {
            vb += PART[ib + sl * PSL_];
            vc += PART[ic + sl * PSL_];
        }
        sB[s][n] = vb;
        sC[s][n] = vc;
    }
    __syncthreads();

    const float* alog = dir ? Ablog : Alog;
    float Av[NS_];
#pragma unroll
    for (int n = 0; n < NS_; ++n) Av[n] = -__expf(alog[d * NS_ + n]);
    float dsk = dskip[d];
    size_t o = ((size_t)(dir * B_ + b) * NC_ + c) * DI_ + d;
    float h[NS_];
#pragma unroll
    for (int n = 0; n < NS_; ++n) h[n] = HINIT[o * NS_ + n];

    float nd = DELTA[base * DI_ + d];
    float nx = XCONV[base * DI_ + d];
    for (int s = 0; s < CL_; ++s) {
        float delta = nd, xv = nx;
        if (s + 1 < CL_) {
            nd = DELTA[(base + s + 1) * DI_ + d];
            nx = XCONV[(base + s + 1) * DI_ + d];
        }
        float dx = delta * xv;
        float y = 0.0f;
#pragma unroll
        for (int n = 0; n < NS_; ++n) {
            h[n] = __expf(delta * Av[n]) * h[n] + dx * sB[s][n];
            y += h[n] * sC[s][n];
        }
        int pos = c * CL_ + s;
        int la = dir ? (KEEP_ - 1 - pos) : pos;
        float z = XZ[((size_t)b * KEEP_ + la) * (2 * DI_) + DI_ + d];
        YOUT[((size_t)(dir * B_ + b) * KEEP_ + la) * DI_ + d] =
            (y + dsk * xv) * silu_f(z);
    }
}

// ---------------------------------------------------------------- launcher
extern "C" void kernel_launch(void* const* d_in, const int* in_sizes, int n_in,
                              void* d_out, int out_size, void* d_ws, size_t ws_size,
                              hipStream_t stream) {
    const float* imgs      = (const float*)d_in[0];
    const float* pos       = (const float*)d_in[1];
    const float* mask_tok  = (const float*)d_in[2];
    const float* n1w       = (const float*)d_in[3];
    const float* n1b       = (const float*)d_in[4];
    const float* inW       = (const float*)d_in[5];
    const float* cw        = (const float*)d_in[6];
    const float* cb        = (const float*)d_in[7];
    const float* xpw       = (const float*)d_in[8];
    const float* dtw       = (const float*)d_in[9];
    const float* dtb       = (const float*)d_in[10];
    const float* Alog      = (const float*)d_in[11];
    const float* Ablog     = (const float*)d_in[12];
    const float* dskip     = (const float*)d_in[13];
    const float* ow        = (const float*)d_in[14];
    const float* n2w       = (const float*)d_in[15];
    const float* n2b       = (const float*)d_in[16];
    const float* f1w       = (const float*)d_in[17];
    const float* f1b       = (const float*)d_in[18];
    const float* f2w       = (const float*)d_in[19];
    const float* f2b       = (const float*)d_in[20];
    const int*   active    = (const int*)d_in[21];
    float* out = (float*)d_out;

    // workspace carve
    char* w = (char*)d_ws;
    auto alloc = [&](size_t bytes) {
        void* p = (void*)w;
        w += (bytes + 255) & ~(size_t)255;
        return p;
    };
    int*   RANK  = (int*)  alloc((size_t)B_ * L_ * 4);
    int*   IDS   = (int*)  alloc((size_t)B_ * KEEP_ * 4);
    float* X     = (float*)alloc((size_t)B_ * KEEP_ * DM_ * 4);
    float* H     = (float*)alloc((size_t)B_ * KEEP_ * DM_ * 4);
    float* XZ    = (float*)alloc((size_t)B_ * KEEP_ * 2 * DI_ * 4);
    float* XCONV = (float*)alloc((size_t)2 * B_ * KEEP_ * DI_ * 4);
    float* PART  = (float*)alloc((size_t)XSPLIT_ * 2 * B_ * KEEP_ * XPR_ * 4);
    float* DELTA = (float*)alloc((size_t)2 * B_ * KEEP_ * DI_ * 4);
    float* YOUT  = (float*)alloc((size_t)2 * B_ * KEEP_ * DI_ * 4);
    float* G     = (float*)alloc((size_t)B_ * KEEP_ * DI_ * 4);
    float* HFIN  = (float*)alloc((size_t)2 * B_ * NC_ * DI_ * NS_ * 4);
    float* HINIT = (float*)alloc((size_t)2 * B_ * NC_ * DI_ * NS_ * 4);
    float* SDELT = (float*)alloc((size_t)2 * B_ * NC_ * DI_ * 4);
    unsigned short* WB = (unsigned short*)alloc((size_t)WTOT_ * 2);

    const unsigned short* wInB = WB;
    const unsigned short* wXpB = WB + S0_;
    const unsigned short* wDtB = WB + S0_ + S1_;
    const unsigned short* wOwB = WB + S0_ + S1_ + S2_;
    const unsigned short* wF1B = WB + S0_ + S1_ + S2_ + S3_;
    const unsigned short* wF2B = WB + S0_ + S1_ + S2_ + S3_ + S4_;

    const int ROWS = B_ * KEEP_;       // 1728
    const int ROWS2 = 2 * B_ * KEEP_;  // 3456
    const int SCAN_BLOCKS = 2 * B_ * NC_ * 3;   // 384
    const size_t PSLAB = (size_t)ROWS2 * XPR_;

    cast_weights_k<<<(WTOT_ + 255) / 256, 256, 0, stream>>>(
        inW, xpw, dtw, ow, f1w, f2w, (unsigned short*)WB);
    compute_ids_k<<<B_, 256, 0, stream>>>(active, RANK, IDS);
    gather_embed_k<<<(B_ * KEEP_ * DM_ + 255) / 256, 256, 0, stream>>>(imgs, pos, IDS, X);

    for (int layer = 0; layer < DEPTH_; ++layer) {
        const unsigned short* L_inW = wInB + (size_t)layer * 2 * DI_ * DM_;
        const float* L_cw  = cw  + (size_t)layer * DI_ * DC_;
        const float* L_cb  = cb  + (size_t)layer * DI_;
        const unsigned short* L_xpw = wXpB + (size_t)layer * XPR_ * DI_;
        const unsigned short* L_dtw = wDtB + (size_t)layer * DI_ * DTR_;
        const float* L_dtb = dtb + (size_t)layer * DI_;
        const float* L_Al  = Alog  + (size_t)layer * DI_ * NS_;
        const float* L_Abl = Ablog + (size_t)layer * DI_ * NS_;
        const float* L_dsk = dskip + (size_t)layer * DI_;
        const unsigned short* L_ow  = wOwB + (size_t)layer * DM_ * DI_;
        const unsigned short* L_f1w = wF1B + (size_t)layer * 2 * DM_ * DM_;
        const float* L_f1b = f1b + (size_t)layer * 2 * DM_;
        const unsigned short* L_f2w = wF2B + (size_t)layer * DM_ * 2 * DM_;
        const float* L_f2b = f2b + (size_t)layer * DM_;

        // LN1
        layernorm_k<<<(ROWS + 3) / 4, 256, 0, stream>>>(
            X, n1w + layer * DM_, n1b + layer * DM_, H, ROWS);
        // in_proj: (1728 x 384) x (1536 x 384)^T -> XZ
        gemm_mfma_k<<<dim3((2 * DI_) / 64, ROWS / 64), 256, 0, stream>>>(
            H, nullptr, DM_, 1, 0, L_inW, nullptr, XZ, 2 * DI_,
            ROWS, 2 * DI_, DM_, 1, 0);
        // conv + silu (both directions)
        conv_silu_k<<<(2 * B_ * KEEP_ * DI_ + 255) / 256, 256, 0, stream>>>(
            XZ, L_cw, L_cb, XCONV);
        // x_proj split-K=4 -> PART slabs
        gemm_mfma_k<<<dim3(1, ROWS2 / 64, XSPLIT_), 256, 0, stream>>>(
            XCONV, nullptr, DI_, 1, 0, L_xpw, nullptr, PART, XPR_,
            ROWS2, XPR_, DI_, XSPLIT_, 8);
        // dt: A = sum of PART slabs (cols 0..24), softplus -> DELTA
        gemm_mfma_k<<<dim3(DI_ / 64, ROWS2 / 64), 256, 0, stream>>>(
            PART, nullptr, XPR_, XSPLIT_, PSLAB, L_dtw, L_dtb, DELTA, DI_,
            ROWS2, DI_, DTR_, 1, 2);
        // scan: chunked parallel (3 phases)
        scan_partial_k<<<SCAN_BLOCKS, 256, 0, stream>>>(
            DELTA, XCONV, PART, L_Al, L_Abl, HFIN, SDELT);
        scan_combine_k<<<(2 * B_ * DI_ * NS_) / 256, 256, 0, stream>>>(
            HFIN, SDELT, L_Al, L_Abl, HINIT);
        scan_final_k<<<SCAN_BLOCKS, 256, 0, stream>>>(
            DELTA, XCONV, PART, XZ, L_Al, L_Abl, L_dsk, HINIT, YOUT);
        // out_proj split-K=2, atomic residual into X (X holds residual base)
        gemm_mfma_k<<<dim3(DM_ / 64, ROWS / 64, 2), 256, 0, stream>>>(
            YOUT, YOUT + (size_t)B_ * KEEP_ * DI_, DI_, 1, 0, L_ow, nullptr,
            X, DM_, ROWS, DM_, DI_, 2, 6);
        // LN2
        layernorm_k<<<(ROWS + 3) / 4, 256, 0, stream>>>(
            X, n2w + layer * DM_, n2b + layer * DM_, H, ROWS);
        // fc1 + bias + gelu
        gemm_mfma_k<<<dim3((2 * DM_) / 64, ROWS / 64), 256, 0, stream>>>(
            H, nullptr, DM_, 1, 0, L_f1w, L_f1b, G, 2 * DM_,
            ROWS, 2 * DM_, DM_, 1, 3);
        // fc2 split-K=2, atomic + bias(z0) + residual into X
        gemm_mfma_k<<<dim3(DM_ / 64, ROWS / 64, 2), 256, 0, stream>>>(
            G, nullptr, 2 * DM_, 1, 0, L_f2w, L_f2b, X, DM_,
            ROWS, DM_, 2 * DM_, 2, 7);
    }

    final_scatter_k<<<(B_ * DM_ * L_ + 255) / 256, 256, 0, stream>>>(
        X, mask_tok, RANK, out);
}

// Round 6
// 1488.073 us; speedup vs baseline: 4.3672x; 1.0225x over previous
//
#include <hip/hip_runtime.h>
#include <hip/hip_bf16.h>
#include <math.h>

#define B_    4
#define GRID_ 12
#define DM_   384
#define DEPTH_ 8
#define L_    1728      // 12^3
#define DI_   768
#define NS_   16
#define DC_   4
#define DTR_  24
#define KEEP_ 432
#define XPR_  56        // DTR + 2*NS
#define NC_   16        // scan chunks
#define CL_   27        // steps per chunk (16*27 = 432)
#define XSPLIT_ 4       // x_proj split-K slabs

typedef __attribute__((ext_vector_type(8))) short short8;
typedef __attribute__((ext_vector_type(4))) float floatx4;

// ---------------------------------------------------------------- utilities
__device__ __forceinline__ float silu_f(float x) {
    return x / (1.0f + __expf(-x));
}
__device__ __forceinline__ float softplus_f(float x) {
    return (x > 20.0f) ? x : log1pf(expf(x));
}
__device__ __forceinline__ float gelu_exact_f(float x) {
    return 0.5f * x * (1.0f + erff(x * 0.7071067811865476f));
}
__device__ __forceinline__ unsigned short f2bf(float x) {
    union { float f; unsigned int u; } c; c.f = x;
    unsigned int u = c.u;
    unsigned int r = (u + 0x7fffu + ((u >> 16) & 1u)) >> 16;
    return (unsigned short)r;
}

// ---------------------------------------------------------------- weight cast
#define S0_ (DEPTH_ * 2 * DI_ * DM_)   // inW
#define S1_ (DEPTH_ * XPR_ * DI_)      // xpw
#define S3_ (DEPTH_ * DM_ * DI_)       // ow
#define S4_ (DEPTH_ * 2 * DM_ * DM_)   // f1w
#define S5_ (DEPTH_ * DM_ * 2 * DM_)   // f2w
#define WTOT_ (S0_ + S1_ + S3_ + S4_ + S5_)

__global__ void cast_weights_k(const float* __restrict__ w0,
                               const float* __restrict__ w1,
                               const float* __restrict__ w3,
                               const float* __restrict__ w4,
                               const float* __restrict__ w5,
                               unsigned short* __restrict__ out) {
    int i = blockIdx.x * 256 + threadIdx.x;
    if (i >= WTOT_) return;
    float v;
    if (i < S0_) v = w0[i];
    else if (i < S0_ + S1_) v = w1[i - S0_];
    else if (i < S0_ + S1_ + S3_) v = w3[i - S0_ - S1_];
    else if (i < S0_ + S1_ + S3_ + S4_) v = w4[i - S0_ - S1_ - S3_];
    else v = w5[i - S0_ - S1_ - S3_ - S4_];
    out[i] = f2bf(v);
}

// ---------------------------------------------------------------- ids / rank
__global__ __launch_bounds__(256) void compute_ids_k(
        const int* __restrict__ active,
        int* __restrict__ RANK, int* __restrict__ IDS) {
    __shared__ int cnt[256];
    int b = blockIdx.x;
    int t = threadIdx.x;
    const int PER = (L_ + 255) / 256;   // 7
    int base = t * PER;
    int c = 0;
    for (int j = 0; j < PER; ++j) {
        int l = base + j;
        if (l < L_ && active[b * L_ + l]) ++c;
    }
    cnt[t] = c;
    __syncthreads();
    for (int off = 1; off < 256; off <<= 1) {
        int v = (t >= off) ? cnt[t - off] : 0;
        __syncthreads();
        cnt[t] += v;
        __syncthreads();
    }
    int r = cnt[t] - c;   // exclusive prefix
    for (int j = 0; j < PER; ++j) {
        int l = base + j;
        if (l >= L_) break;
        if (active[b * L_ + l]) {
            RANK[b * L_ + l] = r;
            IDS[b * KEEP_ + r] = l;
            ++r;
        } else {
            RANK[b * L_ + l] = -1;
        }
    }
}

// X[b,i,c] = imgs[b,c,ids[b,i]] + pos[ids[b,i], c]
__global__ void gather_embed_k(const float* __restrict__ imgs,
                               const float* __restrict__ pos,
                               const int* __restrict__ IDS,
                               float* __restrict__ X) {
    int tid = blockIdx.x * 256 + threadIdx.x;
    if (tid >= B_ * KEEP_ * DM_) return;
    int c = tid % DM_;
    int i = (tid / DM_) % KEEP_;
    int b = tid / (DM_ * KEEP_);
    int l = IDS[b * KEEP_ + i];
    X[tid] = imgs[((size_t)b * DM_ + c) * L_ + l] + pos[(size_t)l * DM_ + c];
}

// out[b,c,l] = active ? X[b, rank, c] : mask_token[c]
__global__ void final_scatter_k(const float* __restrict__ X,
                                const float* __restrict__ mask_token,
                                const int* __restrict__ RANK,
                                float* __restrict__ out) {
    int tid = blockIdx.x * 256 + threadIdx.x;
    if (tid >= B_ * DM_ * L_) return;
    int l = tid % L_;
    int c = (tid / L_) % DM_;
    int b = tid / (L_ * DM_);
    int r = RANK[b * L_ + l];
    out[tid] = (r >= 0) ? X[((size_t)b * KEEP_ + r) * DM_ + c] : mask_token[c];
}

// ---------------------------------------------------------------- layernorm
// fp32 in -> bf16 out (GEMM A-input format)
__global__ void layernorm_k(const float* __restrict__ X,
                            const float* __restrict__ w,
                            const float* __restrict__ bia,
                            unsigned short* __restrict__ H, int rows) {
    int row = blockIdx.x * 4 + (threadIdx.x >> 6);
    int lane = threadIdx.x & 63;
    if (row >= rows) return;
    const float* x = X + (size_t)row * DM_;
    float v[6];
    float s = 0.0f;
#pragma unroll
    for (int j = 0; j < 6; ++j) { v[j] = x[lane + 64 * j]; s += v[j]; }
#pragma unroll
    for (int m = 1; m < 64; m <<= 1) s += __shfl_xor(s, m);
    float mu = s * (1.0f / DM_);
    float s2 = 0.0f;
#pragma unroll
    for (int j = 0; j < 6; ++j) { float d = v[j] - mu; s2 += d * d; }
#pragma unroll
    for (int m = 1; m < 64; m <<= 1) s2 += __shfl_xor(s2, m);
    float rs = rsqrtf(s2 * (1.0f / DM_) + 1e-5f);
    unsigned short* h = H + (size_t)row * DM_;
#pragma unroll
    for (int j = 0; j < 6; ++j) {
        int c = lane + 64 * j;
        h[c] = f2bf((v[j] - mu) * rs * w[c] + bia[c]);
    }
}

// ---------------------------------------------------------------- MFMA GEMM
// C[m,n] = sum_k (A[m,k] (+ A2[m,k])) * W[n,k]. All tiles full (dims are
// multiples of 64/32). abf16: A is bf16 (ushort). Split-K over blockIdx.z.
// modes: 0 write fp32, 6 atomicAdd, 7 atomicAdd + bias on z==0,
//        9 bias+gelu -> bf16 write (C is ushort*)
#define APAD_ 40   // ushort row pad: 80B rows -> 2-way max on frag reads
__global__ __launch_bounds__(256) void gemm_mfma_k(
    const void* __restrict__ Ap, const float* __restrict__ A2, int lda,
    int abf16,
    const unsigned short* __restrict__ Wb,
    const float* __restrict__ bias,
    float* __restrict__ C, int ldc,
    int M, int N, int K, int kslices, int mode) {
    __shared__ unsigned short As[2][64][APAD_];
    __shared__ unsigned short Bs[2][64][APAD_];
    int t = threadIdx.x;
    int wave = t >> 6;
    int lane = t & 63;
    int q = lane >> 4;
    int ml = lane & 15;
    int m0 = blockIdx.y * 64;
    int n0 = blockIdx.x * 64;
    int z  = blockIdx.z;
    int Kper = K / kslices;
    int kbeg = z * Kper;

    int srow = t >> 2;          // staging row 0..63
    int scol = (t & 3) * 8;     // staging col 0,8,16,24

    floatx4 acc[4];
#pragma unroll
    for (int i = 0; i < 4; ++i) acc[i] = (floatx4){0.f, 0.f, 0.f, 0.f};

    float ra[8];
    uint4 rau, rb;

    auto loadA = [&](int k0) {
        if (abf16) {
            rau = *(const uint4*)((const unsigned short*)Ap +
                                  (size_t)(m0 + srow) * lda + k0 + scol);
        } else {
            const float* ap = (const float*)Ap + (size_t)(m0 + srow) * lda + k0 + scol;
            floatx4 v0 = *(const floatx4*)ap;
            floatx4 v1 = *(const floatx4*)(ap + 4);
            if (A2) {
                const float* ap2 = A2 + (size_t)(m0 + srow) * lda + k0 + scol;
                v0 += *(const floatx4*)ap2;
                v1 += *(const floatx4*)(ap2 + 4);
            }
#pragma unroll
            for (int j = 0; j < 4; ++j) { ra[j] = v0[j]; ra[4 + j] = v1[j]; }
        }
    };
    auto loadB = [&](int k0) {
        rb = *(const uint4*)(Wb + (size_t)(n0 + srow) * K + k0 + scol);
    };
    auto storeT = [&](int buf) {
        if (abf16) {
            *(uint4*)&As[buf][srow][scol] = rau;
        } else {
#pragma unroll
            for (int j = 0; j < 8; ++j) As[buf][srow][scol + j] = f2bf(ra[j]);
        }
        *(uint4*)&Bs[buf][srow][scol] = rb;
    };

    int nk = Kper >> 5;
    loadA(kbeg);
    loadB(kbeg);
    storeT(0);
    __syncthreads();
    int buf = 0;
    for (int it = 0; it < nk; ++it) {
        if (it + 1 < nk) {
            int kn = kbeg + (it + 1) * 32;
            loadA(kn);
            loadB(kn);
        }
        short8 a = *(const short8*)&As[buf][wave * 16 + ml][q * 8];
#pragma unroll
        for (int ns = 0; ns < 4; ++ns) {
            short8 b = *(const short8*)&Bs[buf][ns * 16 + ml][q * 8];
            acc[ns] = __builtin_amdgcn_mfma_f32_16x16x32_bf16(a, b, acc[ns], 0, 0, 0);
        }
        if (it + 1 < nk) {
            storeT(buf ^ 1);
            __syncthreads();
            buf ^= 1;
        }
    }

    // ---- epilogue
#pragma unroll
    for (int ns = 0; ns < 4; ++ns) {
        int n = n0 + ns * 16 + ml;
#pragma unroll
        for (int r = 0; r < 4; ++r) {
            int m = m0 + wave * 16 + q * 4 + r;
            float v = acc[ns][r];
            size_t ci = (size_t)m * ldc + n;
            if (mode == 6) {
                atomicAdd(&C[ci], v);
            } else if (mode == 7) {
                if (z == 0) v += bias[n];
                atomicAdd(&C[ci], v);
            } else if (mode == 9) {
                ((unsigned short*)C)[ci] = f2bf(gelu_exact_f(v + bias[n]));
            } else {
                C[ci] = v;
            }
        }
    }
}

// ---------------------------------------------------------------- x_proj
// XDB_slab[z][m][n] = sum_{k in slab z} silu(conv(XZ))[m,k] * xpw[n,k]
// conv fused into A staging: A[m=(dir,b,s)][d] =
//   silu(cb[d] + sum_j cw[d*4+j] * xr[pos=s-3+j, d]), zero-padded pos<0;
//   dir=1 reads reversed sequence via la = KEEP-1-pos. M=3456,N=56,K=768.
__global__ __launch_bounds__(256) void xproj_conv_k(
        const float* __restrict__ XZ,
        const float* __restrict__ cw,
        const float* __restrict__ cb,
        const unsigned short* __restrict__ Wb,   // xpw bf16 [56][768]
        float* __restrict__ Cout) {
    __shared__ unsigned short As[2][64][APAD_];
    __shared__ unsigned short Bs[2][64][APAD_];
    int t = threadIdx.x;
    int wave = t >> 6;
    int lane = t & 63;
    int q = lane >> 4;
    int ml = lane & 15;
    int m0 = blockIdx.y * 64;
    int z  = blockIdx.z;
    const int Kper = DI_ / XSPLIT_;   // 192
    int kbeg = z * Kper;
    float* C = Cout + (size_t)z * (2 * B_ * KEEP_) * XPR_;

    int srow = t >> 2;
    int scol = (t & 3) * 8;
    // decode A row -> (dir,b,s)
    int m = m0 + srow;
    int dir = m / (B_ * KEEP_);
    int rem = m - dir * (B_ * KEEP_);
    int b = rem / KEEP_;
    int s = rem - b * KEEP_;

    floatx4 acc[4];
#pragma unroll
    for (int i = 0; i < 4; ++i) acc[i] = (floatx4){0.f, 0.f, 0.f, 0.f};

    float ra[8];
    uint4 rb;

    auto loadA = [&](int k0) {
        int d0 = k0 + scol;
        float v[8];
        {
            floatx4 c0v = *(const floatx4*)(cb + d0);
            floatx4 c1v = *(const floatx4*)(cb + d0 + 4);
#pragma unroll
            for (int j = 0; j < 4; ++j) { v[j] = c0v[j]; v[4 + j] = c1v[j]; }
        }
        float cwv[8][4];
#pragma unroll
        for (int jj = 0; jj < 8; ++jj) {
            floatx4 cv = *(const floatx4*)(cw + (size_t)(d0 + jj) * 4);
#pragma unroll
            for (int j = 0; j < 4; ++j) cwv[jj][j] = cv[j];
        }
#pragma unroll
        for (int j = 0; j < DC_; ++j) {
            int pos = s - (DC_ - 1) + j;
            if (pos >= 0) {
                int la = dir ? (KEEP_ - 1 - pos) : pos;
                const float* xp = XZ + ((size_t)b * KEEP_ + la) * (2 * DI_) + d0;
                floatx4 x0 = *(const floatx4*)xp;
                floatx4 x1 = *(const floatx4*)(xp + 4);
#pragma unroll
                for (int jj = 0; jj < 4; ++jj) v[jj] += cwv[jj][j] * x0[jj];
#pragma unroll
                for (int jj = 0; jj < 4; ++jj) v[4 + jj] += cwv[4 + jj][j] * x1[jj];
            }
        }
#pragma unroll
        for (int jj = 0; jj < 8; ++jj) ra[jj] = silu_f(v[jj]);
    };
    auto loadB = [&](int k0) {
        if (srow < XPR_) {
            rb = *(const uint4*)(Wb + (size_t)srow * DI_ + k0 + scol);
        } else {
            rb = (uint4){0u, 0u, 0u, 0u};
        }
    };
    auto storeT = [&](int buf) {
#pragma unroll
        for (int j = 0; j < 8; ++j) As[buf][srow][scol + j] = f2bf(ra[j]);
        *(uint4*)&Bs[buf][srow][scol] = rb;
    };

    const int nk = Kper >> 5;   // 6
    loadA(kbeg);
    loadB(kbeg);
    storeT(0);
    __syncthreads();
    int buf = 0;
    for (int it = 0; it < nk; ++it) {
        if (it + 1 < nk) {
            int kn = kbeg + (it + 1) * 32;
            loadA(kn);
            loadB(kn);
        }
        short8 a = *(const short8*)&As[buf][wave * 16 + ml][q * 8];
#pragma unroll
        for (int ns = 0; ns < 4; ++ns) {
            short8 b2 = *(const short8*)&Bs[buf][ns * 16 + ml][q * 8];
            acc[ns] = __builtin_amdgcn_mfma_f32_16x16x32_bf16(a, b2, acc[ns], 0, 0, 0);
        }
        if (it + 1 < nk) {
            storeT(buf ^ 1);
            __syncthreads();
            buf ^= 1;
        }
    }
#pragma unroll
    for (int ns = 0; ns < 4; ++ns) {
        int n = ns * 16 + ml;
        if (n >= XPR_) continue;
#pragma unroll
        for (int r = 0; r < 4; ++r) {
            int mm = m0 + wave * 16 + q * 4 + r;
            C[(size_t)mm * XPR_ + n] = acc[ns][r];
        }
    }
}

// ---------------------------------------------------------------- SSM scan
// Fully fused chunked parallel scan: conv+silu and the dt projection
// (softplus(dtr @ dtw^T + dtb)) are computed in-kernel from LDS-staged
// XZ windows and XDB rows. No DELTA/XCONV tensors exist.
#define PSL_ ((size_t)(2 * B_ * KEEP_) * XPR_)   // slab stride

// Phase A: block = (dgroup of 256, chunk, b, dir). h[16] in registers.
__global__ __launch_bounds__(256) void scan_partial_k(
        const float* __restrict__ XZ,
        const float* __restrict__ PART,
        const float* __restrict__ cw,
        const float* __restrict__ cb,
        const float* __restrict__ dtw,
        const float* __restrict__ dtb,
        const float* __restrict__ Alog,
        const float* __restrict__ Ablog,
        float* __restrict__ HFIN,
        float* __restrict__ SDELT) {
    __shared__ float sXR[CL_ + 3][256];
    __shared__ float sXDB[CL_][XPR_];
    int blk = blockIdx.x;
    int g   = blk % 3;
    int c   = (blk / 3) % NC_;
    int b   = (blk / (3 * NC_)) % B_;
    int dir = blk / (3 * NC_ * B_);
    int t = threadIdx.x;
    int d = g * 256 + t;
    int c0 = c * CL_;

    // stage xr window (pos c0-3 .. c0+CL-1), zero-pad pos<0
    for (int r = 0; r < CL_ + 3; ++r) {
        int pos = c0 - 3 + r;
        float v = 0.0f;
        if (pos >= 0) {
            int la = dir ? (KEEP_ - 1 - pos) : pos;
            v = XZ[((size_t)b * KEEP_ + la) * (2 * DI_) + d];
        }
        sXR[r][t] = v;
    }
    // stage xdb rows (sum split-K slabs)
    size_t rbase = ((size_t)(dir * B_ + b) * KEEP_ + c0) * XPR_;
    for (int i = t; i < CL_ * XPR_; i += 256) {
        size_t idx = rbase + i;
        float v = PART[idx];
#pragma unroll
        for (int sl = 1; sl < XSPLIT_; ++sl) v += PART[idx + sl * PSL_];
        sXDB[i / XPR_][i % XPR_] = v;
    }
    __syncthreads();

    float cwv[DC_];
    {
        floatx4 cv = *(const floatx4*)(cw + (size_t)d * 4);
#pragma unroll
        for (int j = 0; j < DC_; ++j) cwv[j] = cv[j];
    }
    float cbv = cb[d];
    float dtwv[DTR_];
#pragma unroll
    for (int r = 0; r < DTR_ / 4; ++r) {
        floatx4 v = *(const floatx4*)(dtw + (size_t)d * DTR_ + r * 4);
#pragma unroll
        for (int j = 0; j < 4; ++j) dtwv[r * 4 + j] = v[j];
    }
    float dtbv = dtb[d];
    const float* alog = dir ? Ablog : Alog;
    float Av[NS_];
#pragma unroll
    for (int n = 0; n < NS_; ++n) Av[n] = -__expf(alog[(size_t)d * NS_ + n]);

    float h[NS_];
#pragma unroll
    for (int n = 0; n < NS_; ++n) h[n] = 0.0f;
    float sdel = 0.0f;

    for (int s = 0; s < CL_; ++s) {
        float xv = cbv;
#pragma unroll
        for (int j = 0; j < DC_; ++j) xv += cwv[j] * sXR[s + j][t];
        xv = silu_f(xv);
        float dt = dtbv;
#pragma unroll
        for (int r = 0; r < DTR_; ++r) dt += dtwv[r] * sXDB[s][r];
        dt = softplus_f(dt);
        sdel += dt;
        float dx = dt * xv;
#pragma unroll
        for (int n = 0; n < NS_; ++n)
            h[n] = __expf(dt * Av[n]) * h[n] + dx * sXDB[s][DTR_ + n];
    }
    size_t o = ((size_t)(dir * B_ + b) * NC_ + c) * DI_ + d;
    SDELT[o] = sdel;
#pragma unroll
    for (int n = 0; n < NS_; ++n) HFIN[o * NS_ + n] = h[n];
}

// Phase B: thread = (dir,b,d,n); serial combine across chunks.
__global__ __launch_bounds__(256) void scan_combine_k(
        const float* __restrict__ HFIN,
        const float* __restrict__ SDELT,
        const float* __restrict__ Alog,
        const float* __restrict__ Ablog,
        float* __restrict__ HINIT) {
    int gid = blockIdx.x * 256 + threadIdx.x;
    int n = gid & 15;
    int d = (gid >> 4) % DI_;
    int b = (gid / (16 * DI_)) % B_;
    int dir = gid / (16 * DI_ * B_);
    const float* alog = dir ? Ablog : Alog;
    float Av = -__expf(alog[(size_t)d * NS_ + n]);
    float hi = 0.0f;
#pragma unroll
    for (int c = 0; c < NC_; ++c) {
        size_t o = ((size_t)(dir * B_ + b) * NC_ + c) * DI_ + d;
        HINIT[o * NS_ + n] = hi;
        hi = __expf(Av * SDELT[o]) * hi + HFIN[o * NS_ + n];
    }
}

// Phase C: replay with h_init; y = sum_n h*C; gate with silu(z); write YOUT.
__global__ __launch_bounds__(256) void scan_final_k(
        const float* __restrict__ XZ,
        const float* __restrict__ PART,
        const float* __restrict__ cw,
        const float* __restrict__ cb,
        const float* __restrict__ dtw,
        const float* __restrict__ dtb,
        const float* __restrict__ Alog,
        const float* __restrict__ Ablog,
        const float* __restrict__ dskip,
        const float* __restrict__ HINIT,
        float* __restrict__ YOUT) {
    __shared__ float sXR[CL_ + 3][256];
    __shared__ float sZ[CL_][256];
    __shared__ float sXDB[CL_][XPR_];
    int blk = blockIdx.x;
    int g   = blk % 3;
    int c   = (blk / 3) % NC_;
    int b   = (blk / (3 * NC_)) % B_;
    int dir = blk / (3 * NC_ * B_);
    int t = threadIdx.x;
    int d = g * 256 + t;
    int c0 = c * CL_;

    for (int r = 0; r < CL_ + 3; ++r) {
        int pos = c0 - 3 + r;
        float v = 0.0f;
        if (pos >= 0) {
            int la = dir ? (KEEP_ - 1 - pos) : pos;
            v = XZ[((size_t)b * KEEP_ + la) * (2 * DI_) + d];
        }
        sXR[r][t] = v;
    }
    for (int s = 0; s < CL_; ++s) {
        int pos = c0 + s;
        int la = dir ? (KEEP_ - 1 - pos) : pos;
        sZ[s][t] = XZ[((size_t)b * KEEP_ + la) * (2 * DI_) + DI_ + d];
    }
    size_t rbase = ((size_t)(dir * B_ + b) * KEEP_ + c0) * XPR_;
    for (int i = t; i < CL_ * XPR_; i += 256) {
        size_t idx = rbase + i;
        float v = PART[idx];
#pragma unroll
        for (int sl = 1; sl < XSPLIT_; ++sl) v += PART[idx + sl * PSL_];
        sXDB[i / XPR_][i % XPR_] = v;
    }
    __syncthreads();

    float cwv[DC_];
    {
        floatx4 cv = *(const floatx4*)(cw + (size_t)d * 4);
#pragma unroll
        for (int j = 0; j < DC_; ++j) cwv[j] = cv[j];
    }
    float cbv = cb[d];
    float dtwv[DTR_];
#pragma unroll
    for (int r = 0; r < DTR_ / 4; ++r) {
        floatx4 v = *(const floatx4*)(dtw + (size_t)d * DTR_ + r * 4);
#pragma unroll
        for (int j = 0; j < 4; ++j) dtwv[r * 4 + j] = v[j];
    }
    float dtbv = dtb[d];
    const float* alog = dir ? Ablog : Alog;
    float Av[NS_];
#pragma unroll
    for (int n = 0; n < NS_; ++n) Av[n] = -__expf(alog[(size_t)d * NS_ + n]);
    float dsk = dskip[d];

    size_t o = ((size_t)(dir * B_ + b) * NC_ + c) * DI_ + d;
    float h[NS_];
#pragma unroll
    for (int n = 0; n < NS_; ++n) h[n] = HINIT[o * NS_ + n];

    for (int s = 0; s < CL_; ++s) {
        float xv = cbv;
#pragma unroll
        for (int j = 0; j < DC_; ++j) xv += cwv[j] * sXR[s + j][t];
        xv = silu_f(xv);
        float dt = dtbv;
#pragma unroll
        for (int r = 0; r < DTR_; ++r) dt += dtwv[r] * sXDB[s][r];
        dt = softplus_f(dt);
        float dx = dt * xv;
        float y = 0.0f;
#pragma unroll
        for (int n = 0; n < NS_; ++n) {
            h[n] = __expf(dt * Av[n]) * h[n] + dx * sXDB[s][DTR_ + n];
            y += h[n] * sXDB[s][DTR_ + NS_ + n];
        }
        int pos = c0 + s;
        int la = dir ? (KEEP_ - 1 - pos) : pos;
        YOUT[((size_t)(dir * B_ + b) * KEEP_ + la) * DI_ + d] =
            (y + dsk * xv) * silu_f(sZ[s][t]);
    }
}

// ---------------------------------------------------------------- launcher
extern "C" void kernel_launch(void* const* d_in, const int* in_sizes, int n_in,
                              void* d_out, int out_size, void* d_ws, size_t ws_size,
                              hipStream_t stream) {
    const float* imgs      = (const float*)d_in[0];
    const float* pos       = (const float*)d_in[1];
    const float* mask_tok  = (const float*)d_in[2];
    const float* n1w       = (const float*)d_in[3];
    const float* n1b       = (const float*)d_in[4];
    const float* inW       = (const float*)d_in[5];
    const float* cw        = (const float*)d_in[6];
    const float* cb        = (const float*)d_in[7];
    const float* xpw       = (const float*)d_in[8];
    const float* dtw       = (const float*)d_in[9];
    const float* dtb       = (const float*)d_in[10];
    const float* Alog      = (const float*)d_in[11];
    const float* Ablog     = (const float*)d_in[12];
    const float* dskip     = (const float*)d_in[13];
    const float* ow        = (const float*)d_in[14];
    const float* n2w       = (const float*)d_in[15];
    const float* n2b       = (const float*)d_in[16];
    const float* f1w       = (const float*)d_in[17];
    const float* f1b       = (const float*)d_in[18];
    const float* f2w       = (const float*)d_in[19];
    const float* f2b       = (const float*)d_in[20];
    const int*   active    = (const int*)d_in[21];
    float* out = (float*)d_out;

    // workspace carve
    char* w = (char*)d_ws;
    auto alloc = [&](size_t bytes) {
        void* p = (void*)w;
        w += (bytes + 255) & ~(size_t)255;
        return p;
    };
    int*   RANK  = (int*)  alloc((size_t)B_ * L_ * 4);
    int*   IDS   = (int*)  alloc((size_t)B_ * KEEP_ * 4);
    float* X     = (float*)alloc((size_t)B_ * KEEP_ * DM_ * 4);
    unsigned short* Hb = (unsigned short*)alloc((size_t)B_ * KEEP_ * DM_ * 2);
    float* XZ    = (float*)alloc((size_t)B_ * KEEP_ * 2 * DI_ * 4);
    float* PART  = (float*)alloc((size_t)XSPLIT_ * 2 * B_ * KEEP_ * XPR_ * 4);
    float* YOUT  = (float*)alloc((size_t)2 * B_ * KEEP_ * DI_ * 4);
    unsigned short* Gb = (unsigned short*)alloc((size_t)B_ * KEEP_ * DI_ * 2);
    float* HFIN  = (float*)alloc((size_t)2 * B_ * NC_ * DI_ * NS_ * 4);
    float* HINIT = (float*)alloc((size_t)2 * B_ * NC_ * DI_ * NS_ * 4);
    float* SDELT = (float*)alloc((size_t)2 * B_ * NC_ * DI_ * 4);
    unsigned short* WB = (unsigned short*)alloc((size_t)WTOT_ * 2);

    const unsigned short* wInB = WB;
    const unsigned short* wXpB = WB + S0_;
    const unsigned short* wOwB = WB + S0_ + S1_;
    const unsigned short* wF1B = WB + S0_ + S1_ + S3_;
    const unsigned short* wF2B = WB + S0_ + S1_ + S3_ + S4_;

    const int ROWS = B_ * KEEP_;       // 1728
    const int ROWS2 = 2 * B_ * KEEP_;  // 3456
    const int SCAN_BLOCKS = 2 * B_ * NC_ * 3;   // 384

    cast_weights_k<<<(WTOT_ + 255) / 256, 256, 0, stream>>>(
        inW, xpw, ow, f1w, f2w, (unsigned short*)WB);
    compute_ids_k<<<B_, 256, 0, stream>>>(active, RANK, IDS);
    gather_embed_k<<<(B_ * KEEP_ * DM_ + 255) / 256, 256, 0, stream>>>(imgs, pos, IDS, X);

    for (int layer = 0; layer < DEPTH_; ++layer) {
        const unsigned short* L_inW = wInB + (size_t)layer * 2 * DI_ * DM_;
        const float* L_cw  = cw  + (size_t)layer * DI_ * DC_;
        const float* L_cb  = cb  + (size_t)layer * DI_;
        const unsigned short* L_xpw = wXpB + (size_t)layer * XPR_ * DI_;
        const float* L_dtw = dtw + (size_t)layer * DI_ * DTR_;
        const float* L_dtb = dtb + (size_t)layer * DI_;
        const float* L_Al  = Alog  + (size_t)layer * DI_ * NS_;
        const float* L_Abl = Ablog + (size_t)layer * DI_ * NS_;
        const float* L_dsk = dskip + (size_t)layer * DI_;
        const unsigned short* L_ow  = wOwB + (size_t)layer * DM_ * DI_;
        const unsigned short* L_f1w = wF1B + (size_t)layer * 2 * DM_ * DM_;
        const float* L_f1b = f1b + (size_t)layer * 2 * DM_;
        const unsigned short* L_f2w = wF2B + (size_t)layer * DM_ * 2 * DM_;
        const float* L_f2b = f2b + (size_t)layer * DM_;

        // LN1 -> bf16 H
        layernorm_k<<<(ROWS + 3) / 4, 256, 0, stream>>>(
            X, n1w + layer * DM_, n1b + layer * DM_, Hb, ROWS);
        // in_proj: (1728x384)bf16 x (1536x384)^T -> XZ fp32
        gemm_mfma_k<<<dim3((2 * DI_) / 64, ROWS / 64), 256, 0, stream>>>(
            Hb, nullptr, DM_, 1, L_inW, nullptr, XZ, 2 * DI_,
            ROWS, 2 * DI_, DM_, 1, 0);
        // x_proj with fused conv+silu, split-K=4 -> PART slabs
        xproj_conv_k<<<dim3(1, ROWS2 / 64, XSPLIT_), 256, 0, stream>>>(
            XZ, L_cw, L_cb, L_xpw, PART);
        // fused scan (conv + dt-proj in-kernel), 3 phases
        scan_partial_k<<<SCAN_BLOCKS, 256, 0, stream>>>(
            XZ, PART, L_cw, L_cb, L_dtw, L_dtb, L_Al, L_Abl, HFIN, SDELT);
        scan_combine_k<<<(2 * B_ * DI_ * NS_) / 256, 256, 0, stream>>>(
            HFIN, SDELT, L_Al, L_Abl, HINIT);
        scan_final_k<<<SCAN_BLOCKS, 256, 0, stream>>>(
            XZ, PART, L_cw, L_cb, L_dtw, L_dtb, L_Al, L_Abl, L_dsk, HINIT, YOUT);
        // out_proj split-K=2, atomic residual into X
        gemm_mfma_k<<<dim3(DM_ / 64, ROWS / 64, 2), 256, 0, stream>>>(
            YOUT, YOUT + (size_t)B_ * KEEP_ * DI_, DI_, 0, L_ow, nullptr,
            X, DM_, ROWS, DM_, DI_, 2, 6);
        // LN2 -> bf16 H
        layernorm_k<<<(ROWS + 3) / 4, 256, 0, stream>>>(
            X, n2w + layer * DM_, n2b + layer * DM_, Hb, ROWS);
        // fc1 + bias + gelu -> bf16 G
        gemm_mfma_k<<<dim3((2 * DM_) / 64, ROWS / 64), 256, 0, stream>>>(
            Hb, nullptr, DM_, 1, L_f1w, L_f1b, (float*)Gb, 2 * DM_,
            ROWS, 2 * DM_, DM_, 1, 9);
        // fc2 split-K=2, atomic + bias(z0) + residual into X
        gemm_mfma_k<<<dim3(DM_ / 64, ROWS / 64, 2), 256, 0, stream>>>(
            Gb, nullptr, 2 * DM_, 1, L_f2w, L_f2b, X, DM_,
            ROWS, DM_, 2 * DM_, 2, 7);
    }

    final_scatter_k<<<(B_ * DM_ * L_ + 255) / 256, 256, 0, stream>>>(
        X, mask_tok, RANK, out);
}

// Round 7
// 1275.759 us; speedup vs baseline: 5.0940x; 1.1664x over previous
//
#include <hip/hip_runtime.h>
#include <hip/hip_bf16.h>
#include <math.h>

#define B_    4
#define GRID_ 12
#define DM_   384
#define DEPTH_ 8
#define L_    1728      // 12^3
#define DI_   768
#define NS_   16
#define DC_   4
#define DTR_  24
#define KEEP_ 432
#define XPR_  56        // DTR + 2*NS
#define NC_   48        // scan chunks (48*9 = 432)
#define CL_   9         // steps per chunk
#define XSPLIT_ 4       // x_proj split-K slabs

typedef __attribute__((ext_vector_type(8))) short short8;
typedef __attribute__((ext_vector_type(4))) float floatx4;

// ---------------------------------------------------------------- utilities
__device__ __forceinline__ float silu_f(float x) {
    return x / (1.0f + __expf(-x));
}
__device__ __forceinline__ float softplus_f(float x) {
    return (x > 20.0f) ? x : __logf(1.0f + __expf(x));
}
__device__ __forceinline__ float gelu_exact_f(float x) {
    return 0.5f * x * (1.0f + erff(x * 0.7071067811865476f));
}
__device__ __forceinline__ unsigned short f2bf(float x) {
    union { float f; unsigned int u; } c; c.f = x;
    unsigned int u = c.u;
    unsigned int r = (u + 0x7fffu + ((u >> 16) & 1u)) >> 16;
    return (unsigned short)r;
}

// ---------------------------------------------------------------- weight cast
#define S0_ (DEPTH_ * 2 * DI_ * DM_)   // inW
#define S1_ (DEPTH_ * XPR_ * DI_)      // xpw
#define S3_ (DEPTH_ * DM_ * DI_)       // ow
#define S4_ (DEPTH_ * 2 * DM_ * DM_)   // f1w
#define S5_ (DEPTH_ * DM_ * 2 * DM_)   // f2w
#define WTOT_ (S0_ + S1_ + S3_ + S4_ + S5_)

__global__ void cast_weights_k(const float* __restrict__ w0,
                               const float* __restrict__ w1,
                               const float* __restrict__ w3,
                               const float* __restrict__ w4,
                               const float* __restrict__ w5,
                               unsigned short* __restrict__ out) {
    int i = blockIdx.x * 256 + threadIdx.x;
    if (i >= WTOT_) return;
    float v;
    if (i < S0_) v = w0[i];
    else if (i < S0_ + S1_) v = w1[i - S0_];
    else if (i < S0_ + S1_ + S3_) v = w3[i - S0_ - S1_];
    else if (i < S0_ + S1_ + S3_ + S4_) v = w4[i - S0_ - S1_ - S3_];
    else v = w5[i - S0_ - S1_ - S3_ - S4_];
    out[i] = f2bf(v);
}

// ---------------------------------------------------------------- ids / rank
__global__ __launch_bounds__(256) void compute_ids_k(
        const int* __restrict__ active,
        int* __restrict__ RANK, int* __restrict__ IDS) {
    __shared__ int cnt[256];
    int b = blockIdx.x;
    int t = threadIdx.x;
    const int PER = (L_ + 255) / 256;   // 7
    int base = t * PER;
    int c = 0;
    for (int j = 0; j < PER; ++j) {
        int l = base + j;
        if (l < L_ && active[b * L_ + l]) ++c;
    }
    cnt[t] = c;
    __syncthreads();
    for (int off = 1; off < 256; off <<= 1) {
        int v = (t >= off) ? cnt[t - off] : 0;
        __syncthreads();
        cnt[t] += v;
        __syncthreads();
    }
    int r = cnt[t] - c;   // exclusive prefix
    for (int j = 0; j < PER; ++j) {
        int l = base + j;
        if (l >= L_) break;
        if (active[b * L_ + l]) {
            RANK[b * L_ + l] = r;
            IDS[b * KEEP_ + r] = l;
            ++r;
        } else {
            RANK[b * L_ + l] = -1;
        }
    }
}

// X[b,i,c] = imgs[b,c,ids[b,i]] + pos[ids[b,i], c]
__global__ void gather_embed_k(const float* __restrict__ imgs,
                               const float* __restrict__ pos,
                               const int* __restrict__ IDS,
                               float* __restrict__ X) {
    int tid = blockIdx.x * 256 + threadIdx.x;
    if (tid >= B_ * KEEP_ * DM_) return;
    int c = tid % DM_;
    int i = (tid / DM_) % KEEP_;
    int b = tid / (DM_ * KEEP_);
    int l = IDS[b * KEEP_ + i];
    X[tid] = imgs[((size_t)b * DM_ + c) * L_ + l] + pos[(size_t)l * DM_ + c];
}

// out[b,c,l] = active ? X[b, rank, c] : mask_token[c]
__global__ void final_scatter_k(const float* __restrict__ X,
                                const float* __restrict__ mask_token,
                                const int* __restrict__ RANK,
                                float* __restrict__ out) {
    int tid = blockIdx.x * 256 + threadIdx.x;
    if (tid >= B_ * DM_ * L_) return;
    int l = tid % L_;
    int c = (tid / L_) % DM_;
    int b = tid / (L_ * DM_);
    int r = RANK[b * L_ + l];
    out[tid] = (r >= 0) ? X[((size_t)b * KEEP_ + r) * DM_ + c] : mask_token[c];
}

// ---------------------------------------------------------------- layernorm
// fp32 in -> bf16 out (GEMM A-input format)
__global__ void layernorm_k(const float* __restrict__ X,
                            const float* __restrict__ w,
                            const float* __restrict__ bia,
                            unsigned short* __restrict__ H, int rows) {
    int row = blockIdx.x * 4 + (threadIdx.x >> 6);
    int lane = threadIdx.x & 63;
    if (row >= rows) return;
    const float* x = X + (size_t)row * DM_;
    float v[6];
    float s = 0.0f;
#pragma unroll
    for (int j = 0; j < 6; ++j) { v[j] = x[lane + 64 * j]; s += v[j]; }
#pragma unroll
    for (int m = 1; m < 64; m <<= 1) s += __shfl_xor(s, m);
    float mu = s * (1.0f / DM_);
    float s2 = 0.0f;
#pragma unroll
    for (int j = 0; j < 6; ++j) { float d = v[j] - mu; s2 += d * d; }
#pragma unroll
    for (int m = 1; m < 64; m <<= 1) s2 += __shfl_xor(s2, m);
    float rs = rsqrtf(s2 * (1.0f / DM_) + 1e-5f);
    unsigned short* h = H + (size_t)row * DM_;
#pragma unroll
    for (int j = 0; j < 6; ++j) {
        int c = lane + 64 * j;
        h[c] = f2bf((v[j] - mu) * rs * w[c] + bia[c]);
    }
}

// ---------------------------------------------------------------- MFMA GEMM
// C[m,n] = sum_k (A[m,k] (+ A2[m,k])) * W[n,k]. abf16: A is bf16 (ushort).
// Split-K over blockIdx.z.
// modes: 0 write fp32, 6 atomicAdd, 7 atomicAdd + bias on z==0,
//        9 bias+gelu -> bf16 write (C is ushort*)
#define APAD_ 40
__global__ __launch_bounds__(256) void gemm_mfma_k(
    const void* __restrict__ Ap, const float* __restrict__ A2, int lda,
    int abf16,
    const unsigned short* __restrict__ Wb,
    const float* __restrict__ bias,
    float* __restrict__ C, int ldc,
    int M, int N, int K, int kslices, int mode) {
    __shared__ unsigned short As[2][64][APAD_];
    __shared__ unsigned short Bs[2][64][APAD_];
    int t = threadIdx.x;
    int wave = t >> 6;
    int lane = t & 63;
    int q = lane >> 4;
    int ml = lane & 15;
    int m0 = blockIdx.y * 64;
    int n0 = blockIdx.x * 64;
    int z  = blockIdx.z;
    int Kper = K / kslices;
    int kbeg = z * Kper;

    int srow = t >> 2;          // staging row 0..63
    int scol = (t & 3) * 8;     // staging col 0,8,16,24

    floatx4 acc[4];
#pragma unroll
    for (int i = 0; i < 4; ++i) acc[i] = (floatx4){0.f, 0.f, 0.f, 0.f};

    float ra[8];
    uint4 rau, rb;

    auto loadA = [&](int k0) {
        if (abf16) {
            rau = *(const uint4*)((const unsigned short*)Ap +
                                  (size_t)(m0 + srow) * lda + k0 + scol);
        } else {
            const float* ap = (const float*)Ap + (size_t)(m0 + srow) * lda + k0 + scol;
            floatx4 v0 = *(const floatx4*)ap;
            floatx4 v1 = *(const floatx4*)(ap + 4);
            if (A2) {
                const float* ap2 = A2 + (size_t)(m0 + srow) * lda + k0 + scol;
                v0 += *(const floatx4*)ap2;
                v1 += *(const floatx4*)(ap2 + 4);
            }
#pragma unroll
            for (int j = 0; j < 4; ++j) { ra[j] = v0[j]; ra[4 + j] = v1[j]; }
        }
    };
    auto loadB = [&](int k0) {
        rb = *(const uint4*)(Wb + (size_t)(n0 + srow) * K + k0 + scol);
    };
    auto storeT = [&](int buf) {
        if (abf16) {
            *(uint4*)&As[buf][srow][scol] = rau;
        } else {
#pragma unroll
            for (int j = 0; j < 8; ++j) As[buf][srow][scol + j] = f2bf(ra[j]);
        }
        *(uint4*)&Bs[buf][srow][scol] = rb;
    };

    int nk = Kper >> 5;
    loadA(kbeg);
    loadB(kbeg);
    storeT(0);
    __syncthreads();
    int buf = 0;
    for (int it = 0; it < nk; ++it) {
        if (it + 1 < nk) {
            int kn = kbeg + (it + 1) * 32;
            loadA(kn);
            loadB(kn);
        }
        short8 a = *(const short8*)&As[buf][wave * 16 + ml][q * 8];
#pragma unroll
        for (int ns = 0; ns < 4; ++ns) {
            short8 b = *(const short8*)&Bs[buf][ns * 16 + ml][q * 8];
            acc[ns] = __builtin_amdgcn_mfma_f32_16x16x32_bf16(a, b, acc[ns], 0, 0, 0);
        }
        if (it + 1 < nk) {
            storeT(buf ^ 1);
            __syncthreads();
            buf ^= 1;
        }
    }

    // ---- epilogue
#pragma unroll
    for (int ns = 0; ns < 4; ++ns) {
        int n = n0 + ns * 16 + ml;
#pragma unroll
        for (int r = 0; r < 4; ++r) {
            int m = m0 + wave * 16 + q * 4 + r;
            float v = acc[ns][r];
            size_t ci = (size_t)m * ldc + n;
            if (mode == 6) {
                atomicAdd(&C[ci], v);
            } else if (mode == 7) {
                if (z == 0) v += bias[n];
                atomicAdd(&C[ci], v);
            } else if (mode == 9) {
                ((unsigned short*)C)[ci] = f2bf(gelu_exact_f(v + bias[n]));
            } else {
                C[ci] = v;
            }
        }
    }
}

// ---------------------------------------------------------------- x_proj
// conv+silu fused into A staging. M=3456, N=56, K=768, split-K=4 slabs.
__global__ __launch_bounds__(256) void xproj_conv_k(
        const float* __restrict__ XZ,
        const float* __restrict__ cw,
        const float* __restrict__ cb,
        const unsigned short* __restrict__ Wb,   // xpw bf16 [56][768]
        float* __restrict__ Cout) {
    __shared__ unsigned short As[2][64][APAD_];
    __shared__ unsigned short Bs[2][64][APAD_];
    int t = threadIdx.x;
    int wave = t >> 6;
    int lane = t & 63;
    int q = lane >> 4;
    int ml = lane & 15;
    int m0 = blockIdx.y * 64;
    int z  = blockIdx.z;
    const int Kper = DI_ / XSPLIT_;   // 192
    int kbeg = z * Kper;
    float* C = Cout + (size_t)z * (2 * B_ * KEEP_) * XPR_;

    int srow = t >> 2;
    int scol = (t & 3) * 8;
    int m = m0 + srow;
    int dir = m / (B_ * KEEP_);
    int rem = m - dir * (B_ * KEEP_);
    int b = rem / KEEP_;
    int s = rem - b * KEEP_;

    floatx4 acc[4];
#pragma unroll
    for (int i = 0; i < 4; ++i) acc[i] = (floatx4){0.f, 0.f, 0.f, 0.f};

    float ra[8];
    uint4 rb;

    auto loadA = [&](int k0) {
        int d0 = k0 + scol;
        float v[8];
        {
            floatx4 c0v = *(const floatx4*)(cb + d0);
            floatx4 c1v = *(const floatx4*)(cb + d0 + 4);
#pragma unroll
            for (int j = 0; j < 4; ++j) { v[j] = c0v[j]; v[4 + j] = c1v[j]; }
        }
        float cwv[8][4];
#pragma unroll
        for (int jj = 0; jj < 8; ++jj) {
            floatx4 cv = *(const floatx4*)(cw + (size_t)(d0 + jj) * 4);
#pragma unroll
            for (int j = 0; j < 4; ++j) cwv[jj][j] = cv[j];
        }
#pragma unroll
        for (int j = 0; j < DC_; ++j) {
            int pos = s - (DC_ - 1) + j;
            if (pos >= 0) {
                int la = dir ? (KEEP_ - 1 - pos) : pos;
                const float* xp = XZ + ((size_t)b * KEEP_ + la) * (2 * DI_) + d0;
                floatx4 x0 = *(const floatx4*)xp;
                floatx4 x1 = *(const floatx4*)(xp + 4);
#pragma unroll
                for (int jj = 0; jj < 4; ++jj) v[jj] += cwv[jj][j] * x0[jj];
#pragma unroll
                for (int jj = 0; jj < 4; ++jj) v[4 + jj] += cwv[4 + jj][j] * x1[jj];
            }
        }
#pragma unroll
        for (int jj = 0; jj < 8; ++jj) ra[jj] = silu_f(v[jj]);
    };
    auto loadB = [&](int k0) {
        if (srow < XPR_) {
            rb = *(const uint4*)(Wb + (size_t)srow * DI_ + k0 + scol);
        } else {
            rb = (uint4){0u, 0u, 0u, 0u};
        }
    };
    auto storeT = [&](int buf) {
#pragma unroll
        for (int j = 0; j < 8; ++j) As[buf][srow][scol + j] = f2bf(ra[j]);
        *(uint4*)&Bs[buf][srow][scol] = rb;
    };

    const int nk = Kper >> 5;   // 6
    loadA(kbeg);
    loadB(kbeg);
    storeT(0);
    __syncthreads();
    int buf = 0;
    for (int it = 0; it < nk; ++it) {
        if (it + 1 < nk) {
            int kn = kbeg + (it + 1) * 32;
            loadA(kn);
            loadB(kn);
        }
        short8 a = *(const short8*)&As[buf][wave * 16 + ml][q * 8];
#pragma unroll
        for (int ns = 0; ns < 4; ++ns) {
            short8 b2 = *(const short8*)&Bs[buf][ns * 16 + ml][q * 8];
            acc[ns] = __builtin_amdgcn_mfma_f32_16x16x32_bf16(a, b2, acc[ns], 0, 0, 0);
        }
        if (it + 1 < nk) {
            storeT(buf ^ 1);
            __syncthreads();
            buf ^= 1;
        }
    }
#pragma unroll
    for (int ns = 0; ns < 4; ++ns) {
        int n = ns * 16 + ml;
        if (n >= XPR_) continue;
#pragma unroll
        for (int r = 0; r < 4; ++r) {
            int mm = m0 + wave * 16 + q * 4 + r;
            C[(size_t)mm * XPR_ + n] = acc[ns][r];
        }
    }
}

// ---------------------------------------------------------------- SSM scan
// Fully fused chunked parallel scan. conv via rolling register window
// (direct coalesced loads, no big LDS); only XDB rows staged (2 KB, broadcast).
// dA = exp(dt*Av[n]) computed as powers of exp(dt*Av0) when Av[n]=(n+1)Av0
// (true for this model: A = -arange(1..16)); exact-exp fallback otherwise.
// HS layout: HS[((dirb*NC + c)*NS + n)*DI + d]  (d-coalesced).
#define PSL_ ((size_t)(2 * B_ * KEEP_) * XPR_)   // x_proj slab stride

__device__ __forceinline__ bool a_geometric(const float* alog, int d, float& Av0) {
    Av0 = -__expf(alog[(size_t)d * NS_]);
    bool fast = true;
#pragma unroll
    for (int n = 1; n < NS_; ++n) {
        float av = -__expf(alog[(size_t)d * NS_ + n]);
        float ref = (float)(n + 1) * Av0;
        fast = fast && (fabsf(av - ref) <= 1e-4f * fabsf(ref));
    }
    return fast;
}

// Phase A: block = (dgroup of 256, chunk, b, dir). h[16] in registers.
__global__ __launch_bounds__(256) void scan_partial_k(
        const float* __restrict__ XZ,
        const float* __restrict__ PART,
        const float* __restrict__ cw,
        const float* __restrict__ cb,
        const float* __restrict__ dtw,
        const float* __restrict__ dtb,
        const float* __restrict__ Alog,
        const float* __restrict__ Ablog,
        float* __restrict__ HS,
        float* __restrict__ SDELT) {
    __shared__ float sXDB[CL_][XPR_];
    int blk = blockIdx.x;
    int g   = blk % 3;
    int c   = (blk / 3) % NC_;
    int b   = (blk / (3 * NC_)) % B_;
    int dir = blk / (3 * NC_ * B_);
    int t = threadIdx.x;
    int d = g * 256 + t;
    int c0 = c * CL_;
    int dirb = dir * B_ + b;

    size_t rbase = ((size_t)dirb * KEEP_ + c0) * XPR_;
    for (int i = t; i < CL_ * XPR_; i += 256) {
        size_t idx = rbase + i;
        float v = PART[idx];
#pragma unroll
        for (int sl = 1; sl < XSPLIT_; ++sl) v += PART[idx + sl * PSL_];
        sXDB[i / XPR_][i % XPR_] = v;
    }
    __syncthreads();

    floatx4 cwv = *(const floatx4*)(cw + (size_t)d * 4);
    float cbv = cb[d];
    float dtwv[DTR_];
#pragma unroll
    for (int r = 0; r < DTR_ / 4; ++r) {
        floatx4 v = *(const floatx4*)(dtw + (size_t)d * DTR_ + r * 4);
#pragma unroll
        for (int j = 0; j < 4; ++j) dtwv[r * 4 + j] = v[j];
    }
    float dtbv = dtb[d];
    const float* alog = dir ? Ablog : Alog;
    float Av0;
    bool fast = a_geometric(alog, d, Av0);

    auto xr_at = [&](int pos) -> float {
        if (pos < 0) return 0.0f;
        int la = dir ? (KEEP_ - 1 - pos) : pos;
        return XZ[((size_t)b * KEEP_ + la) * (2 * DI_) + d];
    };
    float w0 = xr_at(c0 - 3), w1 = xr_at(c0 - 2), w2 = xr_at(c0 - 1);

    float h[NS_];
#pragma unroll
    for (int n = 0; n < NS_; ++n) h[n] = 0.0f;
    float sdel = 0.0f;

    if (fast) {
#pragma unroll
        for (int s = 0; s < CL_; ++s) {
            float w3 = xr_at(c0 + s);
            float xv = silu_f(cbv + cwv[0] * w0 + cwv[1] * w1 + cwv[2] * w2 + cwv[3] * w3);
            w0 = w1; w1 = w2; w2 = w3;
            float dt = dtbv;
#pragma unroll
            for (int r = 0; r < DTR_; ++r) dt += dtwv[r] * sXDB[s][r];
            dt = softplus_f(dt);
            sdel += dt;
            float dx = dt * xv;
            float e1 = __expf(dt * Av0);
            float e = e1;
#pragma unroll
            for (int n = 0; n < NS_; ++n) {
                h[n] = e * h[n] + dx * sXDB[s][DTR_ + n];
                e *= e1;
            }
        }
    } else {
        for (int s = 0; s < CL_; ++s) {
            float w3 = xr_at(c0 + s);
            float xv = silu_f(cbv + cwv[0] * w0 + cwv[1] * w1 + cwv[2] * w2 + cwv[3] * w3);
            w0 = w1; w1 = w2; w2 = w3;
            float dt = dtbv;
            for (int r = 0; r < DTR_; ++r) dt += dtwv[r] * sXDB[s][r];
            dt = softplus_f(dt);
            sdel += dt;
            float dx = dt * xv;
            for (int n = 0; n < NS_; ++n) {
                float av = -__expf(alog[(size_t)d * NS_ + n]);
                h[n] = __expf(dt * av) * h[n] + dx * sXDB[s][DTR_ + n];
            }
        }
    }
    size_t ob = ((size_t)dirb * NC_ + c) * NS_;
    SDELT[((size_t)dirb * NC_ + c) * DI_ + d] = sdel;
#pragma unroll
    for (int n = 0; n < NS_; ++n) HS[(ob + n) * DI_ + d] = h[n];
}

// Phase B: thread = (dir,b,d,n); serial combine across chunks, in-place on HS.
__global__ __launch_bounds__(256) void scan_combine_k(
        float* __restrict__ HS,
        const float* __restrict__ SDELT,
        const float* __restrict__ Alog,
        const float* __restrict__ Ablog) {
    int gid = blockIdx.x * 256 + threadIdx.x;
    int d = gid % DI_;
    int n = (gid / DI_) % NS_;
    int b = (gid / (DI_ * NS_)) % B_;
    int dir = gid / (DI_ * NS_ * B_);
    int dirb = dir * B_ + b;
    const float* alog = dir ? Ablog : Alog;
    float Av = -__expf(alog[(size_t)d * NS_ + n]);
    float hi = 0.0f;
    size_t sbase = (size_t)dirb * NC_ * DI_ + d;
    size_t hbase = ((size_t)dirb * NC_ * NS_ + n) * DI_ + d;
    float sd_n = SDELT[sbase];
    float hf_n = HS[hbase];
    for (int c = 0; c < NC_; ++c) {
        float sd = sd_n, hf = hf_n;
        if (c + 1 < NC_) {
            sd_n = SDELT[sbase + (size_t)(c + 1) * DI_];
            hf_n = HS[hbase + (size_t)(c + 1) * NS_ * DI_];
        }
        HS[hbase + (size_t)c * NS_ * DI_] = hi;
        hi = __expf(Av * sd) * hi + hf;
    }
}

// Phase C: replay with h_init; y = sum_n h*C; gate with silu(z); write YOUT.
__global__ __launch_bounds__(256) void scan_final_k(
        const float* __restrict__ XZ,
        const float* __restrict__ PART,
        const float* __restrict__ cw,
        const float* __restrict__ cb,
        const float* __restrict__ dtw,
        const float* __restrict__ dtb,
        const float* __restrict__ Alog,
        const float* __restrict__ Ablog,
        const float* __restrict__ dskip,
        const float* __restrict__ HS,
        float* __restrict__ YOUT) {
    __shared__ float sXDB[CL_][XPR_];
    int blk = blockIdx.x;
    int g   = blk % 3;
    int c   = (blk / 3) % NC_;
    int b   = (blk / (3 * NC_)) % B_;
    int dir = blk / (3 * NC_ * B_);
    int t = threadIdx.x;
    int d = g * 256 + t;
    int c0 = c * CL_;
    int dirb = dir * B_ + b;

    size_t rbase = ((size_t)dirb * KEEP_ + c0) * XPR_;
    for (int i = t; i < CL_ * XPR_; i += 256) {
        size_t idx = rbase + i;
        float v = PART[idx];
#pragma unroll
        for (int sl = 1; sl < XSPLIT_; ++sl) v += PART[idx + sl * PSL_];
        sXDB[i / XPR_][i % XPR_] = v;
    }
    __syncthreads();

    floatx4 cwv = *(const floatx4*)(cw + (size_t)d * 4);
    float cbv = cb[d];
    float dtwv[DTR_];
#pragma unroll
    for (int r = 0; r < DTR_ / 4; ++r) {
        floatx4 v = *(const floatx4*)(dtw + (size_t)d * DTR_ + r * 4);
#pragma unroll
        for (int j = 0; j < 4; ++j) dtwv[r * 4 + j] = v[j];
    }
    float dtbv = dtb[d];
    const float* alog = dir ? Ablog : Alog;
    float Av0;
    bool fast = a_geometric(alog, d, Av0);
    float dsk = dskip[d];

    float h[NS_];
    size_t hbase = ((size_t)dirb * NC_ + c) * NS_;
#pragma unroll
    for (int n = 0; n < NS_; ++n) h[n] = HS[(hbase + n) * DI_ + d];

    auto xr_at = [&](int pos) -> float {
        if (pos < 0) return 0.0f;
        int la = dir ? (KEEP_ - 1 - pos) : pos;
        return XZ[((size_t)b * KEEP_ + la) * (2 * DI_) + d];
    };
    float w0 = xr_at(c0 - 3), w1 = xr_at(c0 - 2), w2 = xr_at(c0 - 1);

    if (fast) {
#pragma unroll
        for (int s = 0; s < CL_; ++s) {
            int pos = c0 + s;
            int la = dir ? (KEEP_ - 1 - pos) : pos;
            float w3 = XZ[((size_t)b * KEEP_ + la) * (2 * DI_) + d];
            float zg = XZ[((size_t)b * KEEP_ + la) * (2 * DI_) + DI_ + d];
            float xv = silu_f(cbv + cwv[0] * w0 + cwv[1] * w1 + cwv[2] * w2 + cwv[3] * w3);
            w0 = w1; w1 = w2; w2 = w3;
            float dt = dtbv;
#pragma unroll
            for (int r = 0; r < DTR_; ++r) dt += dtwv[r] * sXDB[s][r];
            dt = softplus_f(dt);
            float dx = dt * xv;
            float e1 = __expf(dt * Av0);
            float e = e1;
            float y = 0.0f;
#pragma unroll
            for (int n = 0; n < NS_; ++n) {
                h[n] = e * h[n] + dx * sXDB[s][DTR_ + n];
                y += h[n] * sXDB[s][DTR_ + NS_ + n];
                e *= e1;
            }
            YOUT[((size_t)dirb * KEEP_ + la) * DI_ + d] =
                (y + dsk * xv) * silu_f(zg);
        }
    } else {
        for (int s = 0; s < CL_; ++s) {
            int pos = c0 + s;
            int la = dir ? (KEEP_ - 1 - pos) : pos;
            float w3 = XZ[((size_t)b * KEEP_ + la) * (2 * DI_) + d];
            float zg = XZ[((size_t)b * KEEP_ + la) * (2 * DI_) + DI_ + d];
            float xv = silu_f(cbv + cwv[0] * w0 + cwv[1] * w1 + cwv[2] * w2 + cwv[3] * w3);
            w0 = w1; w1 = w2; w2 = w3;
            float dt = dtbv;
            for (int r = 0; r < DTR_; ++r) dt += dtwv[r] * sXDB[s][r];
            dt = softplus_f(dt);
            float dx = dt * xv;
            float y = 0.0f;
            for (int n = 0; n < NS_; ++n) {
                float av = -__expf(alog[(size_t)d * NS_ + n]);
                h[n] = __expf(dt * av) * h[n] + dx * sXDB[s][DTR_ + n];
                y += h[n] * sXDB[s][DTR_ + NS_ + n];
            }
            YOUT[((size_t)dirb * KEEP_ + la) * DI_ + d] =
                (y + dsk * xv) * silu_f(zg);
        }
    }
}

// ---------------------------------------------------------------- launcher
extern "C" void kernel_launch(void* const* d_in, const int* in_sizes, int n_in,
                              void* d_out, int out_size, void* d_ws, size_t ws_size,
                              hipStream_t stream) {
    const float* imgs      = (const float*)d_in[0];
    const float* pos       = (const float*)d_in[1];
    const float* mask_tok  = (const float*)d_in[2];
    const float* n1w       = (const float*)d_in[3];
    const float* n1b       = (const float*)d_in[4];
    const float* inW       = (const float*)d_in[5];
    const float* cw        = (const float*)d_in[6];
    const float* cb        = (const float*)d_in[7];
    const float* xpw       = (const float*)d_in[8];
    const float* dtw       = (const float*)d_in[9];
    const float* dtb       = (const float*)d_in[10];
    const float* Alog      = (const float*)d_in[11];
    const float* Ablog     = (const float*)d_in[12];
    const float* dskip     = (const float*)d_in[13];
    const float* ow        = (const float*)d_in[14];
    const float* n2w       = (const float*)d_in[15];
    const float* n2b       = (const float*)d_in[16];
    const float* f1w       = (const float*)d_in[17];
    const float* f1b       = (const float*)d_in[18];
    const float* f2w       = (const float*)d_in[19];
    const float* f2b       = (const float*)d_in[20];
    const int*   active    = (const int*)d_in[21];
    float* out = (float*)d_out;

    // workspace carve
    char* w = (char*)d_ws;
    auto alloc = [&](size_t bytes) {
        void* p = (void*)w;
        w += (bytes + 255) & ~(size_t)255;
        return p;
    };
    int*   RANK  = (int*)  alloc((size_t)B_ * L_ * 4);
    int*   IDS   = (int*)  alloc((size_t)B_ * KEEP_ * 4);
    float* X     = (float*)alloc((size_t)B_ * KEEP_ * DM_ * 4);
    unsigned short* Hb = (unsigned short*)alloc((size_t)B_ * KEEP_ * DM_ * 2);
    float* XZ    = (float*)alloc((size_t)B_ * KEEP_ * 2 * DI_ * 4);
    float* PART  = (float*)alloc((size_t)XSPLIT_ * 2 * B_ * KEEP_ * XPR_ * 4);
    float* YOUT  = (float*)alloc((size_t)2 * B_ * KEEP_ * DI_ * 4);
    unsigned short* Gb = (unsigned short*)alloc((size_t)B_ * KEEP_ * DI_ * 2);
    float* HS    = (float*)alloc((size_t)2 * B_ * NC_ * NS_ * DI_ * 4);
    float* SDELT = (float*)alloc((size_t)2 * B_ * NC_ * DI_ * 4);
    unsigned short* WB = (unsigned short*)alloc((size_t)WTOT_ * 2);

    const unsigned short* wInB = WB;
    const unsigned short* wXpB = WB + S0_;
    const unsigned short* wOwB = WB + S0_ + S1_;
    const unsigned short* wF1B = WB + S0_ + S1_ + S3_;
    const unsigned short* wF2B = WB + S0_ + S1_ + S3_ + S4_;

    const int ROWS = B_ * KEEP_;       // 1728
    const int ROWS2 = 2 * B_ * KEEP_;  // 3456
    const int SCAN_BLOCKS = 2 * B_ * NC_ * 3;   // 1152

    cast_weights_k<<<(WTOT_ + 255) / 256, 256, 0, stream>>>(
        inW, xpw, ow, f1w, f2w, (unsigned short*)WB);
    compute_ids_k<<<B_, 256, 0, stream>>>(active, RANK, IDS);
    gather_embed_k<<<(B_ * KEEP_ * DM_ + 255) / 256, 256, 0, stream>>>(imgs, pos, IDS, X);

    for (int layer = 0; layer < DEPTH_; ++layer) {
        const unsigned short* L_inW = wInB + (size_t)layer * 2 * DI_ * DM_;
        const float* L_cw  = cw  + (size_t)layer * DI_ * DC_;
        const float* L_cb  = cb  + (size_t)layer * DI_;
        const unsigned short* L_xpw = wXpB + (size_t)layer * XPR_ * DI_;
        const float* L_dtw = dtw + (size_t)layer * DI_ * DTR_;
        const float* L_dtb = dtb + (size_t)layer * DI_;
        const float* L_Al  = Alog  + (size_t)layer * DI_ * NS_;
        const float* L_Abl = Ablog + (size_t)layer * DI_ * NS_;
        const float* L_dsk = dskip + (size_t)layer * DI_;
        const unsigned short* L_ow  = wOwB + (size_t)layer * DM_ * DI_;
        const unsigned short* L_f1w = wF1B + (size_t)layer * 2 * DM_ * DM_;
        const float* L_f1b = f1b + (size_t)layer * 2 * DM_;
        const unsigned short* L_f2w = wF2B + (size_t)layer * DM_ * 2 * DM_;
        const float* L_f2b = f2b + (size_t)layer * DM_;

        // LN1 -> bf16 H
        layernorm_k<<<(ROWS + 3) / 4, 256, 0, stream>>>(
            X, n1w + layer * DM_, n1b + layer * DM_, Hb, ROWS);
        // in_proj: (1728x384)bf16 x (1536x384)^T -> XZ fp32
        gemm_mfma_k<<<dim3((2 * DI_) / 64, ROWS / 64), 256, 0, stream>>>(
            Hb, nullptr, DM_, 1, L_inW, nullptr, XZ, 2 * DI_,
            ROWS, 2 * DI_, DM_, 1, 0);
        // x_proj with fused conv+silu, split-K=4 -> PART slabs
        xproj_conv_k<<<dim3(1, ROWS2 / 64, XSPLIT_), 256, 0, stream>>>(
            XZ, L_cw, L_cb, L_xpw, PART);
        // fused scan (conv + dt-proj in-kernel), 3 phases
        scan_partial_k<<<SCAN_BLOCKS, 256, 0, stream>>>(
            XZ, PART, L_cw, L_cb, L_dtw, L_dtb, L_Al, L_Abl, HS, SDELT);
        scan_combine_k<<<(2 * B_ * NS_ * DI_) / 256, 256, 0, stream>>>(
            HS, SDELT, L_Al, L_Abl);
        scan_final_k<<<SCAN_BLOCKS, 256, 0, stream>>>(
            XZ, PART, L_cw, L_cb, L_dtw, L_dtb, L_Al, L_Abl, L_dsk, HS, YOUT);
        // out_proj split-K=2, atomic residual into X
        gemm_mfma_k<<<dim3(DM_ / 64, ROWS / 64, 2), 256, 0, stream>>>(
            YOUT, YOUT + (size_t)B_ * KEEP_ * DI_, DI_, 0, L_ow, nullptr,
            X, DM_, ROWS, DM_, DI_, 2, 6);
        // LN2 -> bf16 H
        layernorm_k<<<(ROWS + 3) / 4, 256, 0, stream>>>(
            X, n2w + layer * DM_, n2b + layer * DM_, Hb, ROWS);
        // fc1 + bias + gelu -> bf16 G
        gemm_mfma_k<<<dim3((2 * DM_) / 64, ROWS / 64), 256, 0, stream>>>(
            Hb, nullptr, DM_, 1, L_f1w, L_f1b, (float*)Gb, 2 * DM_,
            ROWS, 2 * DM_, DM_, 1, 9);
        // fc2 split-K=2, atomic + bias(z0) + residual into X
        gemm_mfma_k<<<dim3(DM_ / 64, ROWS / 64, 2), 256, 0, stream>>>(
            Gb, nullptr, 2 * DM_, 1, L_f2w, L_f2b, X, DM_,
            ROWS, DM_, 2 * DM_, 2, 7);
    }

    final_scatter_k<<<(B_ * DM_ * L_ + 255) / 256, 256, 0, stream>>>(
        X, mask_tok, RANK, out);
}

// Round 10
// 1250.057 us; speedup vs baseline: 5.1988x; 1.0206x over previous
//
#include <hip/hip_runtime.h>
#include <hip/hip_bf16.h>
#include <math.h>

#define B_    4
#define GRID_ 12
#define DM_   384
#define DEPTH_ 8
#define L_    1728      // 12^3
#define DI_   768
#define NS_   16
#define DC_   4
#define DTR_  24
#define KEEP_ 432
#define XPR_  56        // DTR + 2*NS
#define NC_   48        // scan chunks (48*9 = 432) — R7-proven numerics
#define CL_   9         // steps per chunk
#define XSPLIT_ 4       // x_proj split-K slabs

typedef __attribute__((ext_vector_type(8))) short short8;
typedef __attribute__((ext_vector_type(4))) float floatx4;

// ---------------------------------------------------------------- utilities
__device__ __forceinline__ float silu_f(float x) {
    return x / (1.0f + __expf(-x));
}
__device__ __forceinline__ float softplus_f(float x) {
    return (x > 20.0f) ? x : __logf(1.0f + __expf(x));
}
__device__ __forceinline__ float gelu_exact_f(float x) {
    return 0.5f * x * (1.0f + erff(x * 0.7071067811865476f));
}
__device__ __forceinline__ unsigned short f2bf(float x) {
    union { float f; unsigned int u; } c; c.f = x;
    unsigned int u = c.u;
    unsigned int r = (u + 0x7fffu + ((u >> 16) & 1u)) >> 16;
    return (unsigned short)r;
}
// async global->LDS, 16B per lane; LDS dest is wave-uniform base, HW writes
// lane i at base + i*16 — lane-linear layout required.
__device__ __forceinline__ void gld_lds16(const unsigned short* g, unsigned short* l) {
    __builtin_amdgcn_global_load_lds(
        (const __attribute__((address_space(1))) void*)g,
        (__attribute__((address_space(3))) void*)l, 16, 0, 0);
}

// ---------------------------------------------------------------- weight cast
#define S0_ (DEPTH_ * 2 * DI_ * DM_)   // inW
#define S1_ (DEPTH_ * XPR_ * DI_)      // xpw
#define S3_ (DEPTH_ * DM_ * DI_)       // ow
#define S4_ (DEPTH_ * 2 * DM_ * DM_)   // f1w
#define S5_ (DEPTH_ * DM_ * 2 * DM_)   // f2w
#define WTOT_ (S0_ + S1_ + S3_ + S4_ + S5_)

__global__ void cast_weights_k(const float* __restrict__ w0,
                               const float* __restrict__ w1,
                               const float* __restrict__ w3,
                               const float* __restrict__ w4,
                               const float* __restrict__ w5,
                               unsigned short* __restrict__ out) {
    int i = blockIdx.x * 256 + threadIdx.x;
    if (i >= WTOT_) return;
    float v;
    if (i < S0_) v = w0[i];
    else if (i < S0_ + S1_) v = w1[i - S0_];
    else if (i < S0_ + S1_ + S3_) v = w3[i - S0_ - S1_];
    else if (i < S0_ + S1_ + S3_ + S4_) v = w4[i - S0_ - S1_ - S3_];
    else v = w5[i - S0_ - S1_ - S3_ - S4_];
    out[i] = f2bf(v);
}

// ---------------------------------------------------------------- ids / rank
__global__ __launch_bounds__(256) void compute_ids_k(
        const int* __restrict__ active,
        int* __restrict__ RANK, int* __restrict__ IDS) {
    __shared__ int cnt[256];
    int b = blockIdx.x;
    int t = threadIdx.x;
    const int PER = (L_ + 255) / 256;   // 7
    int base = t * PER;
    int c = 0;
    for (int j = 0; j < PER; ++j) {
        int l = base + j;
        if (l < L_ && active[b * L_ + l]) ++c;
    }
    cnt[t] = c;
    __syncthreads();
    for (int off = 1; off < 256; off <<= 1) {
        int v = (t >= off) ? cnt[t - off] : 0;
        __syncthreads();
        cnt[t] += v;
        __syncthreads();
    }
    int r = cnt[t] - c;   // exclusive prefix
    for (int j = 0; j < PER; ++j) {
        int l = base + j;
        if (l >= L_) break;
        if (active[b * L_ + l]) {
            RANK[b * L_ + l] = r;
            IDS[b * KEEP_ + r] = l;
            ++r;
        } else {
            RANK[b * L_ + l] = -1;
        }
    }
}

// X[b,i,c] = imgs[b,c,ids[b,i]] + pos[ids[b,i], c]
__global__ void gather_embed_k(const float* __restrict__ imgs,
                               const float* __restrict__ pos,
                               const int* __restrict__ IDS,
                               float* __restrict__ X) {
    int tid = blockIdx.x * 256 + threadIdx.x;
    if (tid >= B_ * KEEP_ * DM_) return;
    int c = tid % DM_;
    int i = (tid / DM_) % KEEP_;
    int b = tid / (DM_ * KEEP_);
    int l = IDS[b * KEEP_ + i];
    X[tid] = imgs[((size_t)b * DM_ + c) * L_ + l] + pos[(size_t)l * DM_ + c];
}

// out[b,c,l] = active ? X[b, rank, c] : mask_token[c]
__global__ void final_scatter_k(const float* __restrict__ X,
                                const float* __restrict__ mask_token,
                                const int* __restrict__ RANK,
                                float* __restrict__ out) {
    int tid = blockIdx.x * 256 + threadIdx.x;
    if (tid >= B_ * DM_ * L_) return;
    int l = tid % L_;
    int c = (tid / L_) % DM_;
    int b = tid / (L_ * DM_);
    int r = RANK[b * L_ + l];
    out[tid] = (r >= 0) ? X[((size_t)b * KEEP_ + r) * DM_ + c] : mask_token[c];
}

// ---------------------------------------------------------------- layernorm
// fp32 in -> bf16 out (GEMM A-input format)
__global__ void layernorm_k(const float* __restrict__ X,
                            const float* __restrict__ w,
                            const float* __restrict__ bia,
                            unsigned short* __restrict__ H, int rows) {
    int row = blockIdx.x * 4 + (threadIdx.x >> 6);
    int lane = threadIdx.x & 63;
    if (row >= rows) return;
    const float* x = X + (size_t)row * DM_;
    float v[6];
    float s = 0.0f;
#pragma unroll
    for (int j = 0; j < 6; ++j) { v[j] = x[lane + 64 * j]; s += v[j]; }
#pragma unroll
    for (int m = 1; m < 64; m <<= 1) s += __shfl_xor(s, m);
    float mu = s * (1.0f / DM_);
    float s2 = 0.0f;
#pragma unroll
    for (int j = 0; j < 6; ++j) { float d = v[j] - mu; s2 += d * d; }
#pragma unroll
    for (int m = 1; m < 64; m <<= 1) s2 += __shfl_xor(s2, m);
    float rs = rsqrtf(s2 * (1.0f / DM_) + 1e-5f);
    unsigned short* h = H + (size_t)row * DM_;
#pragma unroll
    for (int j = 0; j < 6; ++j) {
        int c = lane + 64 * j;
        h[c] = f2bf((v[j] - mu) * rs * w[c] + bia[c]);
    }
}

// ---------------------------------------------------------------- MFMA GEMM
// C[m,n] = sum_k (A[m,k] (+ A2[m,k])) * W[n,k]. abf16: A is bf16 and staged
// via global_load_lds; B always staged via global_load_lds (lane-linear
// [64][32] LDS tiles). fp32 A (out_proj sum) staged via registers.
// modes: 0 write fp32, 6 atomicAdd, 7 atomicAdd + bias on z==0,
//        9 bias+gelu -> bf16 write (C is ushort*)
#define APAD_ 32
__global__ __launch_bounds__(256) void gemm_mfma_k(
    const void* __restrict__ Ap, const float* __restrict__ A2, int lda,
    int abf16,
    const unsigned short* __restrict__ Wb,
    const float* __restrict__ bias,
    float* __restrict__ C, int ldc,
    int M, int N, int K, int kslices, int mode) {
    __shared__ unsigned short As[2][64][APAD_];
    __shared__ unsigned short Bs[2][64][APAD_];
    int t = threadIdx.x;
    int wave = t >> 6;
    int lane = t & 63;
    int q = lane >> 4;
    int ml = lane & 15;
    int m0 = blockIdx.y * 64;
    int n0 = blockIdx.x * 64;
    int z  = blockIdx.z;
    int Kper = K / kslices;
    int kbeg = z * Kper;

    int srow = t >> 2;          // staging row 0..63 == wave*16 + (lane>>2)
    int scol = (t & 3) * 8;     // staging col 0,8,16,24

    floatx4 acc[4];
#pragma unroll
    for (int i = 0; i < 4; ++i) acc[i] = (floatx4){0.f, 0.f, 0.f, 0.f};

    float ra[8];

    auto asyncB = [&](int k0, int buf) {
        gld_lds16(Wb + (size_t)(n0 + srow) * K + k0 + scol,
                  &Bs[buf][wave * 16][0]);
    };
    auto asyncA = [&](int k0, int buf) {
        gld_lds16((const unsigned short*)Ap + (size_t)(m0 + srow) * lda + k0 + scol,
                  &As[buf][wave * 16][0]);
    };
    auto loadA = [&](int k0) {   // fp32 (+A2) path
        const float* ap = (const float*)Ap + (size_t)(m0 + srow) * lda + k0 + scol;
        floatx4 v0 = *(const floatx4*)ap;
        floatx4 v1 = *(const floatx4*)(ap + 4);
        if (A2) {
            const float* ap2 = A2 + (size_t)(m0 + srow) * lda + k0 + scol;
            v0 += *(const floatx4*)ap2;
            v1 += *(const floatx4*)(ap2 + 4);
        }
#pragma unroll
        for (int j = 0; j < 4; ++j) { ra[j] = v0[j]; ra[4 + j] = v1[j]; }
    };
    auto storeA = [&](int buf) {
#pragma unroll
        for (int j = 0; j < 8; ++j) As[buf][srow][scol + j] = f2bf(ra[j]);
    };

    int nk = Kper >> 5;
    asyncB(kbeg, 0);
    if (abf16) { asyncA(kbeg, 0); }
    else       { loadA(kbeg); storeA(0); }
    __syncthreads();
    int buf = 0;
    for (int it = 0; it < nk; ++it) {
        if (it + 1 < nk) {
            int kn = kbeg + (it + 1) * 32;
            asyncB(kn, buf ^ 1);
            if (abf16) asyncA(kn, buf ^ 1);
            else       loadA(kn);
        }
        short8 a = *(const short8*)&As[buf][wave * 16 + ml][q * 8];
#pragma unroll
        for (int ns = 0; ns < 4; ++ns) {
            short8 b = *(const short8*)&Bs[buf][ns * 16 + ml][q * 8];
            acc[ns] = __builtin_amdgcn_mfma_f32_16x16x32_bf16(a, b, acc[ns], 0, 0, 0);
        }
        if (it + 1 < nk) {
            if (!abf16) storeA(buf ^ 1);
            __syncthreads();
            buf ^= 1;
        }
    }

    // ---- epilogue
#pragma unroll
    for (int ns = 0; ns < 4; ++ns) {
        int n = n0 + ns * 16 + ml;
#pragma unroll
        for (int r = 0; r < 4; ++r) {
            int m = m0 + wave * 16 + q * 4 + r;
            float v = acc[ns][r];
            size_t ci = (size_t)m * ldc + n;
            if (mode == 6) {
                atomicAdd(&C[ci], v);
            } else if (mode == 7) {
                if (z == 0) v += bias[n];
                atomicAdd(&C[ci], v);
            } else if (mode == 9) {
                ((unsigned short*)C)[ci] = f2bf(gelu_exact_f(v + bias[n]));
            } else {
                C[ci] = v;
            }
        }
    }
}

// ---------------------------------------------------------------- x_proj
// conv+silu fused into A staging (registers). B via global_load_lds
// (rows >= 56 read in-bounds garbage from WB; those columns are discarded
// in the epilogue so they never contaminate kept outputs).
// M=3456, N=56, K=768, split-K=4 slabs.
__global__ __launch_bounds__(256) void xproj_conv_k(
        const float* __restrict__ XZ,
        const float* __restrict__ cw,
        const float* __restrict__ cb,
        const unsigned short* __restrict__ Wb,   // xpw bf16 [56][768]
        float* __restrict__ Cout) {
    __shared__ unsigned short As[2][64][APAD_];
    __shared__ unsigned short Bs[2][64][APAD_];
    int t = threadIdx.x;
    int wave = t >> 6;
    int lane = t & 63;
    int q = lane >> 4;
    int ml = lane & 15;
    int m0 = blockIdx.y * 64;
    int z  = blockIdx.z;
    const int Kper = DI_ / XSPLIT_;   // 192
    int kbeg = z * Kper;
    float* C = Cout + (size_t)z * (2 * B_ * KEEP_) * XPR_;

    int srow = t >> 2;
    int scol = (t & 3) * 8;
    int m = m0 + srow;
    int dir = m / (B_ * KEEP_);
    int rem = m - dir * (B_ * KEEP_);
    int b = rem / KEEP_;
    int s = rem - b * KEEP_;

    floatx4 acc[4];
#pragma unroll
    for (int i = 0; i < 4; ++i) acc[i] = (floatx4){0.f, 0.f, 0.f, 0.f};

    float ra[8];

    auto asyncB = [&](int k0, int buf) {
        gld_lds16(Wb + (size_t)srow * DI_ + k0 + scol,
                  &Bs[buf][wave * 16][0]);
    };
    auto loadA = [&](int k0) {
        int d0 = k0 + scol;
        float v[8];
        {
            floatx4 c0v = *(const floatx4*)(cb + d0);
            floatx4 c1v = *(const floatx4*)(cb + d0 + 4);
#pragma unroll
            for (int j = 0; j < 4; ++j) { v[j] = c0v[j]; v[4 + j] = c1v[j]; }
        }
        float cwv[8][4];
#pragma unroll
        for (int jj = 0; jj < 8; ++jj) {
            floatx4 cv = *(const floatx4*)(cw + (size_t)(d0 + jj) * 4);
#pragma unroll
            for (int j = 0; j < 4; ++j) cwv[jj][j] = cv[j];
        }
#pragma unroll
        for (int j = 0; j < DC_; ++j) {
            int pos = s - (DC_ - 1) + j;
            if (pos >= 0) {
                int la = dir ? (KEEP_ - 1 - pos) : pos;
                const float* xp = XZ + ((size_t)b * KEEP_ + la) * (2 * DI_) + d0;
                floatx4 x0 = *(const floatx4*)xp;
                floatx4 x1 = *(const floatx4*)(xp + 4);
#pragma unroll
                for (int jj = 0; jj < 4; ++jj) v[jj] += cwv[jj][j] * x0[jj];
#pragma unroll
                for (int jj = 0; jj < 4; ++jj) v[4 + jj] += cwv[4 + jj][j] * x1[jj];
            }
        }
#pragma unroll
        for (int jj = 0; jj < 8; ++jj) ra[jj] = silu_f(v[jj]);
    };
    auto storeA = [&](int buf) {
#pragma unroll
        for (int j = 0; j < 8; ++j) As[buf][srow][scol + j] = f2bf(ra[j]);
    };

    const int nk = Kper >> 5;   // 6
    asyncB(kbeg, 0);
    loadA(kbeg);
    storeA(0);
    __syncthreads();
    int buf = 0;
    for (int it = 0; it < nk; ++it) {
        if (it + 1 < nk) {
            int kn = kbeg + (it + 1) * 32;
            asyncB(kn, buf ^ 1);
            loadA(kn);
        }
        short8 a = *(const short8*)&As[buf][wave * 16 + ml][q * 8];
#pragma unroll
        for (int ns = 0; ns < 4; ++ns) {
            short8 b2 = *(const short8*)&Bs[buf][ns * 16 + ml][q * 8];
            acc[ns] = __builtin_amdgcn_mfma_f32_16x16x32_bf16(a, b2, acc[ns], 0, 0, 0);
        }
        if (it + 1 < nk) {
            storeA(buf ^ 1);
            __syncthreads();
            buf ^= 1;
        }
    }
#pragma unroll
    for (int ns = 0; ns < 4; ++ns) {
        int n = ns * 16 + ml;
        if (n >= XPR_) continue;
#pragma unroll
        for (int r = 0; r < 4; ++r) {
            int mm = m0 + wave * 16 + q * 4 + r;
            C[(size_t)mm * XPR_ + n] = acc[ns][r];
        }
    }
}

// ---------------------------------------------------------------- SSM scan
// R7-verbatim configuration (NC=48, CL=9, 3 separate kernels, geometric
// trick) — measured absmax 0.03125. The CL=18 variants (R8/R9) failed at
// 0.1133: chunk-decay exp(Av*sumdelta) amplifies rounding by |Av*sumdelta|
// which doubles with CL; do NOT grow CL without switching to exact exps.
#define PSL_ ((size_t)(2 * B_ * KEEP_) * XPR_)   // x_proj slab stride

__device__ __forceinline__ bool a_geometric(const float* alog, int d, float& Av0) {
    Av0 = -__expf(alog[(size_t)d * NS_]);
    bool fast = true;
#pragma unroll
    for (int n = 1; n < NS_; ++n) {
        float av = -__expf(alog[(size_t)d * NS_ + n]);
        float ref = (float)(n + 1) * Av0;
        fast = fast && (fabsf(av - ref) <= 1e-4f * fabsf(ref));
    }
    return fast;
}

// Phase A: block = (dgroup of 256, chunk, b, dir). h[16] in registers.
__global__ __launch_bounds__(256) void scan_partial_k(
        const float* __restrict__ XZ,
        const float* __restrict__ PART,
        const float* __restrict__ cw,
        const float* __restrict__ cb,
        const float* __restrict__ dtw,
        const float* __restrict__ dtb,
        const float* __restrict__ Alog,
        const float* __restrict__ Ablog,
        float* __restrict__ HS,
        float* __restrict__ SDELT) {
    __shared__ float sXDB[CL_][XPR_];
    int blk = blockIdx.x;
    int g   = blk % 3;
    int c   = (blk / 3) % NC_;
    int b   = (blk / (3 * NC_)) % B_;
    int dir = blk / (3 * NC_ * B_);
    int t = threadIdx.x;
    int d = g * 256 + t;
    int c0 = c * CL_;
    int dirb = dir * B_ + b;

    size_t rbase = ((size_t)dirb * KEEP_ + c0) * XPR_;
    for (int i = t; i < CL_ * XPR_; i += 256) {
        size_t idx = rbase + i;
        float v = PART[idx];
#pragma unroll
        for (int sl = 1; sl < XSPLIT_; ++sl) v += PART[idx + sl * PSL_];
        sXDB[i / XPR_][i % XPR_] = v;
    }
    __syncthreads();

    floatx4 cwv = *(const floatx4*)(cw + (size_t)d * 4);
    float cbv = cb[d];
    float dtwv[DTR_];
#pragma unroll
    for (int r = 0; r < DTR_ / 4; ++r) {
        floatx4 v = *(const floatx4*)(dtw + (size_t)d * DTR_ + r * 4);
#pragma unroll
        for (int j = 0; j < 4; ++j) dtwv[r * 4 + j] = v[j];
    }
    float dtbv = dtb[d];
    const float* alog = dir ? Ablog : Alog;
    float Av0;
    bool fast = a_geometric(alog, d, Av0);

    auto xr_at = [&](int pos) -> float {
        if (pos < 0) return 0.0f;
        int la = dir ? (KEEP_ - 1 - pos) : pos;
        return XZ[((size_t)b * KEEP_ + la) * (2 * DI_) + d];
    };
    float w0 = xr_at(c0 - 3), w1 = xr_at(c0 - 2), w2 = xr_at(c0 - 1);

    float h[NS_];
#pragma unroll
    for (int n = 0; n < NS_; ++n) h[n] = 0.0f;
    float sdel = 0.0f;

    if (fast) {
#pragma unroll
        for (int s = 0; s < CL_; ++s) {
            float w3 = xr_at(c0 + s);
            float xv = silu_f(cbv + cwv[0] * w0 + cwv[1] * w1 + cwv[2] * w2 + cwv[3] * w3);
            w0 = w1; w1 = w2; w2 = w3;
            float dt = dtbv;
#pragma unroll
            for (int r = 0; r < DTR_; ++r) dt += dtwv[r] * sXDB[s][r];
            dt = softplus_f(dt);
            sdel += dt;
            float dx = dt * xv;
            float e1 = __expf(dt * Av0);
            float e = e1;
#pragma unroll
            for (int n = 0; n < NS_; ++n) {
                h[n] = e * h[n] + dx * sXDB[s][DTR_ + n];
                e *= e1;
            }
        }
    } else {
        for (int s = 0; s < CL_; ++s) {
            float w3 = xr_at(c0 + s);
            float xv = silu_f(cbv + cwv[0] * w0 + cwv[1] * w1 + cwv[2] * w2 + cwv[3] * w3);
            w0 = w1; w1 = w2; w2 = w3;
            float dt = dtbv;
            for (int r = 0; r < DTR_; ++r) dt += dtwv[r] * sXDB[s][r];
            dt = softplus_f(dt);
            sdel += dt;
            float dx = dt * xv;
            for (int n = 0; n < NS_; ++n) {
                float av = -__expf(alog[(size_t)d * NS_ + n]);
                h[n] = __expf(dt * av) * h[n] + dx * sXDB[s][DTR_ + n];
            }
        }
    }
    size_t ob = ((size_t)dirb * NC_ + c) * NS_;
    SDELT[((size_t)dirb * NC_ + c) * DI_ + d] = sdel;
#pragma unroll
    for (int n = 0; n < NS_; ++n) HS[(ob + n) * DI_ + d] = h[n];
}

// Phase B: thread = (dir,b,d,n); serial combine across chunks, in-place on HS.
__global__ __launch_bounds__(256) void scan_combine_k(
        float* __restrict__ HS,
        const float* __restrict__ SDELT,
        const float* __restrict__ Alog,
        const float* __restrict__ Ablog) {
    int gid = blockIdx.x * 256 + threadIdx.x;
    int d = gid % DI_;
    int n = (gid / DI_) % NS_;
    int b = (gid / (DI_ * NS_)) % B_;
    int dir = gid / (DI_ * NS_ * B_);
    int dirb = dir * B_ + b;
    const float* alog = dir ? Ablog : Alog;
    float Av = -__expf(alog[(size_t)d * NS_ + n]);
    float hi = 0.0f;
    size_t sbase = (size_t)dirb * NC_ * DI_ + d;
    size_t hbase = ((size_t)dirb * NC_ * NS_ + n) * DI_ + d;
    float sd_n = SDELT[sbase];
    float hf_n = HS[hbase];
    for (int c = 0; c < NC_; ++c) {
        float sd = sd_n, hf = hf_n;
        if (c + 1 < NC_) {
            sd_n = SDELT[sbase + (size_t)(c + 1) * DI_];
            hf_n = HS[hbase + (size_t)(c + 1) * NS_ * DI_];
        }
        HS[hbase + (size_t)c * NS_ * DI_] = hi;
        hi = __expf(Av * sd) * hi + hf;
    }
}

// Phase C: replay with h_init; y = sum_n h*C; gate with silu(z); write YOUT.
__global__ __launch_bounds__(256) void scan_final_k(
        const float* __restrict__ XZ,
        const float* __restrict__ PART,
        const float* __restrict__ cw,
        const float* __restrict__ cb,
        const float* __restrict__ dtw,
        const float* __restrict__ dtb,
        const float* __restrict__ Alog,
        const float* __restrict__ Ablog,
        const float* __restrict__ dskip,
        const float* __restrict__ HS,
        float* __restrict__ YOUT) {
    __shared__ float sXDB[CL_][XPR_];
    int blk = blockIdx.x;
    int g   = blk % 3;
    int c   = (blk / 3) % NC_;
    int b   = (blk / (3 * NC_)) % B_;
    int dir = blk / (3 * NC_ * B_);
    int t = threadIdx.x;
    int d = g * 256 + t;
    int c0 = c * CL_;
    int dirb = dir * B_ + b;

    size_t rbase = ((size_t)dirb * KEEP_ + c0) * XPR_;
    for (int i = t; i < CL_ * XPR_; i += 256) {
        size_t idx = rbase + i;
        float v = PART[idx];
#pragma unroll
        for (int sl = 1; sl < XSPLIT_; ++sl) v += PART[idx + sl * PSL_];
        sXDB[i / XPR_][i % XPR_] = v;
    }
    __syncthreads();

    floatx4 cwv = *(const floatx4*)(cw + (size_t)d * 4);
    float cbv = cb[d];
    float dtwv[DTR_];
#pragma unroll
    for (int r = 0; r < DTR_ / 4; ++r) {
        floatx4 v = *(const floatx4*)(dtw + (size_t)d * DTR_ + r * 4);
#pragma unroll
        for (int j = 0; j < 4; ++j) dtwv[r * 4 + j] = v[j];
    }
    float dtbv = dtb[d];
    const float* alog = dir ? Ablog : Alog;
    float Av0;
    bool fast = a_geometric(alog, d, Av0);
    float dsk = dskip[d];

    float h[NS_];
    size_t hbase = ((size_t)dirb * NC_ + c) * NS_;
#pragma unroll
    for (int n = 0; n < NS_; ++n) h[n] = HS[(hbase + n) * DI_ + d];

    auto xr_at = [&](int pos) -> float {
        if (pos < 0) return 0.0f;
        int la = dir ? (KEEP_ - 1 - pos) : pos;
        return XZ[((size_t)b * KEEP_ + la) * (2 * DI_) + d];
    };
    float w0 = xr_at(c0 - 3), w1 = xr_at(c0 - 2), w2 = xr_at(c0 - 1);

    if (fast) {
#pragma unroll
        for (int s = 0; s < CL_; ++s) {
            int pos = c0 + s;
            int la = dir ? (KEEP_ - 1 - pos) : pos;
            float w3 = XZ[((size_t)b * KEEP_ + la) * (2 * DI_) + d];
            float zg = XZ[((size_t)b * KEEP_ + la) * (2 * DI_) + DI_ + d];
            float xv = silu_f(cbv + cwv[0] * w0 + cwv[1] * w1 + cwv[2] * w2 + cwv[3] * w3);
            w0 = w1; w1 = w2; w2 = w3;
            float dt = dtbv;
#pragma unroll
            for (int r = 0; r < DTR_; ++r) dt += dtwv[r] * sXDB[s][r];
            dt = softplus_f(dt);
            float dx = dt * xv;
            float e1 = __expf(dt * Av0);
            float e = e1;
            float y = 0.0f;
#pragma unroll
            for (int n = 0; n < NS_; ++n) {
                h[n] = e * h[n] + dx * sXDB[s][DTR_ + n];
                y += h[n] * sXDB[s][DTR_ + NS_ + n];
                e *= e1;
            }
            YOUT[((size_t)dirb * KEEP_ + la) * DI_ + d] =
                (y + dsk * xv) * silu_f(zg);
        }
    } else {
        for (int s = 0; s < CL_; ++s) {
            int pos = c0 + s;
            int la = dir ? (KEEP_ - 1 - pos) : pos;
            float w3 = XZ[((size_t)b * KEEP_ + la) * (2 * DI_) + d];
            float zg = XZ[((size_t)b * KEEP_ + la) * (2 * DI_) + DI_ + d];
            float xv = silu_f(cbv + cwv[0] * w0 + cwv[1] * w1 + cwv[2] * w2 + cwv[3] * w3);
            w0 = w1; w1 = w2; w2 = w3;
            float dt = dtbv;
            for (int r = 0; r < DTR_; ++r) dt += dtwv[r] * sXDB[s][r];
            dt = softplus_f(dt);
            float dx = dt * xv;
            float y = 0.0f;
            for (int n = 0; n < NS_; ++n) {
                float av = -__expf(alog[(size_t)d * NS_ + n]);
                h[n] = __expf(dt * av) * h[n] + dx * sXDB[s][DTR_ + n];
                y += h[n] * sXDB[s][DTR_ + NS_ + n];
            }
            YOUT[((size_t)dirb * KEEP_ + la) * DI_ + d] =
                (y + dsk * xv) * silu_f(zg);
        }
    }
}

// ---------------------------------------------------------------- launcher
extern "C" void kernel_launch(void* const* d_in, const int* in_sizes, int n_in,
                              void* d_out, int out_size, void* d_ws, size_t ws_size,
                              hipStream_t stream) {
    const float* imgs      = (const float*)d_in[0];
    const float* pos       = (const float*)d_in[1];
    const float* mask_tok  = (const float*)d_in[2];
    const float* n1w       = (const float*)d_in[3];
    const float* n1b       = (const float*)d_in[4];
    const float* inW       = (const float*)d_in[5];
    const float* cw        = (const float*)d_in[6];
    const float* cb        = (const float*)d_in[7];
    const float* xpw       = (const float*)d_in[8];
    const float* dtw       = (const float*)d_in[9];
    const float* dtb       = (const float*)d_in[10];
    const float* Alog      = (const float*)d_in[11];
    const float* Ablog     = (const float*)d_in[12];
    const float* dskip     = (const float*)d_in[13];
    const float* ow        = (const float*)d_in[14];
    const float* n2w       = (const float*)d_in[15];
    const float* n2b       = (const float*)d_in[16];
    const float* f1w       = (const float*)d_in[17];
    const float* f1b       = (const float*)d_in[18];
    const float* f2w       = (const float*)d_in[19];
    const float* f2b       = (const float*)d_in[20];
    const int*   active    = (const int*)d_in[21];
    float* out = (float*)d_out;

    // workspace carve
    char* w = (char*)d_ws;
    auto alloc = [&](size_t bytes) {
        void* p = (void*)w;
        w += (bytes + 255) & ~(size_t)255;
        return p;
    };
    int*   RANK  = (int*)  alloc((size_t)B_ * L_ * 4);
    int*   IDS   = (int*)  alloc((size_t)B_ * KEEP_ * 4);
    float* X     = (float*)alloc((size_t)B_ * KEEP_ * DM_ * 4);
    unsigned short* Hb = (unsigned short*)alloc((size_t)B_ * KEEP_ * DM_ * 2);
    float* XZ    = (float*)alloc((size_t)B_ * KEEP_ * 2 * DI_ * 4);
    float* PART  = (float*)alloc((size_t)XSPLIT_ * 2 * B_ * KEEP_ * XPR_ * 4);
    float* YOUT  = (float*)alloc((size_t)2 * B_ * KEEP_ * DI_ * 4);
    unsigned short* Gb = (unsigned short*)alloc((size_t)B_ * KEEP_ * DI_ * 2);
    float* HS    = (float*)alloc((size_t)2 * B_ * NC_ * NS_ * DI_ * 4);
    float* SDELT = (float*)alloc((size_t)2 * B_ * NC_ * DI_ * 4);
    unsigned short* WB = (unsigned short*)alloc((size_t)WTOT_ * 2);

    const unsigned short* wInB = WB;
    const unsigned short* wXpB = WB + S0_;
    const unsigned short* wOwB = WB + S0_ + S1_;
    const unsigned short* wF1B = WB + S0_ + S1_ + S3_;
    const unsigned short* wF2B = WB + S0_ + S1_ + S3_ + S4_;

    const int ROWS = B_ * KEEP_;       // 1728
    const int ROWS2 = 2 * B_ * KEEP_;  // 3456
    const int SCAN_BLOCKS = 2 * B_ * NC_ * 3;   // 1152

    cast_weights_k<<<(WTOT_ + 255) / 256, 256, 0, stream>>>(
        inW, xpw, ow, f1w, f2w, (unsigned short*)WB);
    compute_ids_k<<<B_, 256, 0, stream>>>(active, RANK, IDS);
    gather_embed_k<<<(B_ * KEEP_ * DM_ + 255) / 256, 256, 0, stream>>>(imgs, pos, IDS, X);

    for (int layer = 0; layer < DEPTH_; ++layer) {
        const unsigned short* L_inW = wInB + (size_t)layer * 2 * DI_ * DM_;
        const float* L_cw  = cw  + (size_t)layer * DI_ * DC_;
        const float* L_cb  = cb  + (size_t)layer * DI_;
        const unsigned short* L_xpw = wXpB + (size_t)layer * XPR_ * DI_;
        const float* L_dtw = dtw + (size_t)layer * DI_ * DTR_;
        const float* L_dtb = dtb + (size_t)layer * DI_;
        const float* L_Al  = Alog  + (size_t)layer * DI_ * NS_;
        const float* L_Abl = Ablog + (size_t)layer * DI_ * NS_;
        const float* L_dsk = dskip + (size_t)layer * DI_;
        const unsigned short* L_ow  = wOwB + (size_t)layer * DM_ * DI_;
        const unsigned short* L_f1w = wF1B + (size_t)layer * 2 * DM_ * DM_;
        const float* L_f1b = f1b + (size_t)layer * 2 * DM_;
        const unsigned short* L_f2w = wF2B + (size_t)layer * DM_ * 2 * DM_;
        const float* L_f2b = f2b + (size_t)layer * DM_;

        // LN1 -> bf16 H
        layernorm_k<<<(ROWS + 3) / 4, 256, 0, stream>>>(
            X, n1w + layer * DM_, n1b + layer * DM_, Hb, ROWS);
        // in_proj: (1728x384)bf16 x (1536x384)^T -> XZ fp32
        gemm_mfma_k<<<dim3((2 * DI_) / 64, ROWS / 64), 256, 0, stream>>>(
            Hb, nullptr, DM_, 1, L_inW, nullptr, XZ, 2 * DI_,
            ROWS, 2 * DI_, DM_, 1, 0);
        // x_proj with fused conv+silu, split-K=4 -> PART slabs
        xproj_conv_k<<<dim3(1, ROWS2 / 64, XSPLIT_), 256, 0, stream>>>(
            XZ, L_cw, L_cb, L_xpw, PART);
        // fused scan (conv + dt-proj in-kernel), 3 phases — R7 config
        scan_partial_k<<<SCAN_BLOCKS, 256, 0, stream>>>(
            XZ, PART, L_cw, L_cb, L_dtw, L_dtb, L_Al, L_Abl, HS, SDELT);
        scan_combine_k<<<(2 * B_ * NS_ * DI_) / 256, 256, 0, stream>>>(
            HS, SDELT, L_Al, L_Abl);
        scan_final_k<<<SCAN_BLOCKS, 256, 0, stream>>>(
            XZ, PART, L_cw, L_cb, L_dtw, L_dtb, L_Al, L_Abl, L_dsk, HS, YOUT);
        // out_proj split-K=2, atomic residual into X
        gemm_mfma_k<<<dim3(DM_ / 64, ROWS / 64, 2), 256, 0, stream>>>(
            YOUT, YOUT + (size_t)B_ * KEEP_ * DI_, DI_, 0, L_ow, nullptr,
            X, DM_, ROWS, DM_, DI_, 2, 6);
        // LN2 -> bf16 H
        layernorm_k<<<(ROWS + 3) / 4, 256, 0, stream>>>(
            X, n2w + layer * DM_, n2b + layer * DM_, Hb, ROWS);
        // fc1 + bias + gelu -> bf16 G
        gemm_mfma_k<<<dim3((2 * DM_) / 64, ROWS / 64), 256, 0, stream>>>(
            Hb, nullptr, DM_, 1, L_f1w, L_f1b, (float*)Gb, 2 * DM_,
            ROWS, 2 * DM_, DM_, 1, 9);
        // fc2 split-K=2, atomic + bias(z0) + residual into X
        gemm_mfma_k<<<dim3(DM_ / 64, ROWS / 64, 2), 256, 0, stream>>>(
            Gb, nullptr, 2 * DM_, 1, L_f2w, L_f2b, X, DM_,
            ROWS, DM_, 2 * DM_, 2, 7);
    }

    final_scatter_k<<<(B_ * DM_ * L_ + 255) / 256, 256, 0, stream>>>(
        X, mask_tok, RANK, out);
}